// Round 2
// baseline (2962.547 us; speedup 1.0000x reference)
//
#include <hip/hip_runtime.h>
#include <cstdint>

#define DEVI __device__ __forceinline__

typedef short short8 __attribute__((ext_vector_type(8)));
typedef float f32x4 __attribute__((ext_vector_type(4)));
typedef unsigned short u16;
typedef u16 u16x4 __attribute__((ext_vector_type(4)));

static constexpr int Bz = 8, Ss = 1024, Dd = 1024, Hh = 16, HD = 64, DFF = 4096, Ee = 16;
static constexpr int Tt = Bz * Ss;           // 8192 tokens
static constexpr int Cap = (2 * Tt) / Ee;    // 1024 capacity
static constexpr int D3 = 3 * Dd;            // 3072
static constexpr float EPSc = 1.1920929e-07f;

DEVI u16 f2b(float f) {
    union { float f; uint32_t u; } v; v.f = f;
    return (u16)((v.u + 0x7FFFu + ((v.u >> 16) & 1u)) >> 16);
}
DEVI float b2f(u16 h) {
    union { uint32_t u; float f; } v; v.u = ((uint32_t)h) << 16; return v.f;
}
DEVI f32x4 zf4() { f32x4 v; v[0] = 0.f; v[1] = 0.f; v[2] = 0.f; v[3] = 0.f; return v; }

// ---------------------------------------------------------------------------
// transpose + convert: in [Z][R][Cc] f32 -> out [Z][Cc][R] bf16
// ---------------------------------------------------------------------------
__global__ __launch_bounds__(256)
void tconv_kernel(const float* __restrict__ in, u16* __restrict__ out, int R, int Cc) {
    __shared__ float tile[32][33];
    const int z = blockIdx.z;
    const int r0 = blockIdx.y * 32, c0 = blockIdx.x * 32;
    const int tr = threadIdx.x >> 5, tc = threadIdx.x & 31;
    const float* ip = in + (size_t)z * R * Cc;
#pragma unroll
    for (int i = 0; i < 4; ++i)
        tile[tr + i * 8][tc] = ip[(size_t)(r0 + tr + i * 8) * Cc + c0 + tc];
    __syncthreads();
    u16* op = out + (size_t)z * R * Cc;
#pragma unroll
    for (int i = 0; i < 4; ++i)
        op[(size_t)(c0 + tr + i * 8) * R + r0 + tc] = f2b(tile[tc][tr + i * 8]);
}

// ---------------------------------------------------------------------------
// fp32 GEMM, fp64 accumulation: C[M,N] = A[M,K] * Bt[N,K]^T + bias
// tile 128x64, BK=16, 256 threads, micro 4x8. fp32 FMA within BK, double fold.
// ---------------------------------------------------------------------------
__global__ __launch_bounds__(256)
void gemm32(const float* __restrict__ A, const float* __restrict__ Bt,
            float* __restrict__ C, const float* __restrict__ bias,
            int M, int N, int K) {
    __shared__ float As[16][128];
    __shared__ float Bs[16][64];
    const int tid = threadIdx.x;
    const int m0 = blockIdx.y * 128, n0 = blockIdx.x * 64;
    const int rgp = tid >> 3, cgp = tid & 7;   // rows rgp*4+i, cols cgp*8+j

    double accd[4][8];
    float acc[4][8];
#pragma unroll
    for (int i = 0; i < 4; ++i)
#pragma unroll
        for (int j = 0; j < 8; ++j) { accd[i][j] = 0.0; acc[i][j] = 0.f; }

    const int arow = tid >> 1, akq = (tid & 1) * 8;
    const int brow = tid >> 2, bkq = (tid & 3) * 4;

    for (int kt = 0; kt < K; kt += 16) {
        const float4 a0 = *(const float4*)(A + (size_t)(m0 + arow) * K + kt + akq);
        const float4 a1 = *(const float4*)(A + (size_t)(m0 + arow) * K + kt + akq + 4);
        const float4 b0 = *(const float4*)(Bt + (size_t)(n0 + brow) * K + kt + bkq);
        __syncthreads();
        As[akq + 0][arow] = a0.x; As[akq + 1][arow] = a0.y;
        As[akq + 2][arow] = a0.z; As[akq + 3][arow] = a0.w;
        As[akq + 4][arow] = a1.x; As[akq + 5][arow] = a1.y;
        As[akq + 6][arow] = a1.z; As[akq + 7][arow] = a1.w;
        Bs[bkq + 0][brow] = b0.x; Bs[bkq + 1][brow] = b0.y;
        Bs[bkq + 2][brow] = b0.z; Bs[bkq + 3][brow] = b0.w;
        __syncthreads();
#pragma unroll
        for (int k = 0; k < 16; ++k) {
            const float4 av = *(const float4*)(&As[k][rgp * 4]);
            const float4 bv0 = *(const float4*)(&Bs[k][cgp * 8]);
            const float4 bv1 = *(const float4*)(&Bs[k][cgp * 8 + 4]);
            const float a4[4] = {av.x, av.y, av.z, av.w};
            const float b8[8] = {bv0.x, bv0.y, bv0.z, bv0.w, bv1.x, bv1.y, bv1.z, bv1.w};
#pragma unroll
            for (int i = 0; i < 4; ++i)
#pragma unroll
                for (int j = 0; j < 8; ++j) acc[i][j] = fmaf(a4[i], b8[j], acc[i][j]);
        }
#pragma unroll
        for (int i = 0; i < 4; ++i)
#pragma unroll
            for (int j = 0; j < 8; ++j) { accd[i][j] += (double)acc[i][j]; acc[i][j] = 0.f; }
    }

    float bj[8];
#pragma unroll
    for (int j = 0; j < 8; ++j) bj[j] = bias[n0 + cgp * 8 + j];
#pragma unroll
    for (int i = 0; i < 4; ++i) {
        const size_t row = (size_t)(m0 + rgp * 4 + i);
        float4 o0, o1;
        o0.x = (float)(accd[i][0] + (double)bj[0]);
        o0.y = (float)(accd[i][1] + (double)bj[1]);
        o0.z = (float)(accd[i][2] + (double)bj[2]);
        o0.w = (float)(accd[i][3] + (double)bj[3]);
        o1.x = (float)(accd[i][4] + (double)bj[4]);
        o1.y = (float)(accd[i][5] + (double)bj[5]);
        o1.z = (float)(accd[i][6] + (double)bj[6]);
        o1.w = (float)(accd[i][7] + (double)bj[7]);
        *(float4*)(C + row * N + n0 + cgp * 8) = o0;
        *(float4*)(C + row * N + n0 + cgp * 8 + 4) = o1;
    }
}

// ---------------------------------------------------------------------------
// fp32 flash attention, fp64 O/l accumulation. Block = (64 q-rows, b*h).
// 4 waves; wave owns 16 q-rows; lane = (rg,cg): rows rg*4+i, cols cg*4+j.
// ---------------------------------------------------------------------------
__global__ __launch_bounds__(256)
void attn32(const float* __restrict__ qkv, float* __restrict__ o) {
    __shared__ float Qs[64][68], Ks[64][68], Vs[64][68], Ps[64][68];
    const int qt = blockIdx.x, bh = blockIdx.y;
    const int bb = bh >> 4, hh = bh & 15;
    const int tid = threadIdx.x, lane = tid & 63, wid = tid >> 6;
    const int rg = lane >> 4, cg = lane & 15;
    const int srow = tid >> 2, sdq = (tid & 3) * 16;

    {
        const float* qp = qkv + ((size_t)(bb * Ss + qt * 64 + srow)) * D3 + hh * HD + sdq;
#pragma unroll
        for (int q = 0; q < 4; ++q)
            *(float4*)(&Qs[srow][sdq + q * 4]) = *(const float4*)(qp + q * 4);
    }

    double otd[4][4];
    double lr_d[4];
    float mr[4];
#pragma unroll
    for (int i = 0; i < 4; ++i) {
        lr_d[i] = 0.0; mr[i] = -1e30f;
#pragma unroll
        for (int j = 0; j < 4; ++j) otd[i][j] = 0.0;
    }
    const int qr = wid * 16 + rg * 4;
    __syncthreads();

    for (int kt = 0; kt < Ss / 64; ++kt) {
        const float* kp = qkv + ((size_t)(bb * Ss + kt * 64 + srow)) * D3 + hh * HD + sdq;
        float4 kv[4], vv[4];
#pragma unroll
        for (int q = 0; q < 4; ++q) {
            kv[q] = *(const float4*)(kp + Dd + q * 4);
            vv[q] = *(const float4*)(kp + 2 * Dd + q * 4);
        }
        __syncthreads();
#pragma unroll
        for (int q = 0; q < 4; ++q) {
            *(float4*)(&Ks[srow][sdq + q * 4]) = kv[q];
            *(float4*)(&Vs[srow][sdq + q * 4]) = vv[q];
        }
        __syncthreads();

        // scores S[4][4]: rows qr+i, cols cg*4+j
        float sacc[4][4];
#pragma unroll
        for (int i = 0; i < 4; ++i)
#pragma unroll
            for (int j = 0; j < 4; ++j) sacc[i][j] = 0.f;
#pragma unroll
        for (int d4 = 0; d4 < 16; ++d4) {
            float4 qv[4], kvv[4];
#pragma unroll
            for (int i = 0; i < 4; ++i) qv[i] = *(const float4*)(&Qs[qr + i][d4 * 4]);
#pragma unroll
            for (int j = 0; j < 4; ++j) kvv[j] = *(const float4*)(&Ks[cg * 4 + j][d4 * 4]);
#pragma unroll
            for (int i = 0; i < 4; ++i)
#pragma unroll
                for (int j = 0; j < 4; ++j) {
                    sacc[i][j] = fmaf(qv[i].x, kvv[j].x, sacc[i][j]);
                    sacc[i][j] = fmaf(qv[i].y, kvv[j].y, sacc[i][j]);
                    sacc[i][j] = fmaf(qv[i].z, kvv[j].z, sacc[i][j]);
                    sacc[i][j] = fmaf(qv[i].w, kvv[j].w, sacc[i][j]);
                }
        }

        // online softmax (row spread over 16 cg lanes)
        float pm[4], scl[4], ps[4];
#pragma unroll
        for (int i = 0; i < 4; ++i) {
            float m = -1e30f;
#pragma unroll
            for (int j = 0; j < 4; ++j) {
                sacc[i][j] *= 0.125f;
                m = fmaxf(m, sacc[i][j]);
            }
            m = fmaxf(m, __shfl_xor(m, 1));
            m = fmaxf(m, __shfl_xor(m, 2));
            m = fmaxf(m, __shfl_xor(m, 4));
            m = fmaxf(m, __shfl_xor(m, 8));
            const float mn = fmaxf(mr[i], m);
            scl[i] = expf(mr[i] - mn);
            mr[i] = mn;
            float s = 0.f;
#pragma unroll
            for (int j = 0; j < 4; ++j) {
                const float p = expf(sacc[i][j] - mn);
                Ps[qr + i][cg * 4 + j] = p;
                s += p;
            }
            s += __shfl_xor(s, 1);
            s += __shfl_xor(s, 2);
            s += __shfl_xor(s, 4);
            s += __shfl_xor(s, 8);
            ps[i] = s;
            lr_d[i] = lr_d[i] * (double)scl[i] + (double)s;
        }
        __syncthreads();

        // PV: O[rows qr+i][dims cg*4+j]
        float pacc[4][4];
#pragma unroll
        for (int i = 0; i < 4; ++i)
#pragma unroll
            for (int j = 0; j < 4; ++j) pacc[i][j] = 0.f;
#pragma unroll
        for (int k = 0; k < 64; ++k) {
            const float4 v4 = *(const float4*)(&Vs[k][cg * 4]);
#pragma unroll
            for (int i = 0; i < 4; ++i) {
                const float p = Ps[qr + i][k];
                pacc[i][0] = fmaf(p, v4.x, pacc[i][0]);
                pacc[i][1] = fmaf(p, v4.y, pacc[i][1]);
                pacc[i][2] = fmaf(p, v4.z, pacc[i][2]);
                pacc[i][3] = fmaf(p, v4.w, pacc[i][3]);
            }
        }
#pragma unroll
        for (int i = 0; i < 4; ++i)
#pragma unroll
            for (int j = 0; j < 4; ++j) otd[i][j] = otd[i][j] * (double)scl[i] + (double)pacc[i][j];
    }

#pragma unroll
    for (int i = 0; i < 4; ++i) {
        const double inv = 1.0 / lr_d[i];
        float* op = o + ((size_t)(bb * Ss + qt * 64 + qr + i)) * Dd + hh * HD + cg * 4;
        float4 ov;
        ov.x = (float)(otd[i][0] * inv);
        ov.y = (float)(otd[i][1] * inv);
        ov.z = (float)(otd[i][2] * inv);
        ov.w = (float)(otd[i][3] * inv);
        *(float4*)op = ov;
    }
}

// ---------------------------------------------------------------------------
// BT-GEMM bf16 MFMA (expert FFN): C[M,N] = A[M,K]*Bt[N,K]^T + bias
// MODE 0: bf16 out.  MODE 1: bf16 out + relu.
// ---------------------------------------------------------------------------
template <int MODE>
__global__ __launch_bounds__(256)
void gemm_bt(const u16* __restrict__ A, const u16* __restrict__ Bt, u16* __restrict__ Cout,
             const float* __restrict__ bias, int M, int N, int K,
             size_t sA, size_t sB, size_t sC, int sBias) {
    __shared__ u16 As[128 * 32];
    __shared__ u16 Bs[128 * 32];
    const int tid = threadIdx.x;
    const int lane = tid & 63, wid = tid >> 6;
    const int wm = wid >> 1, wn = wid & 1;
    const int m0 = blockIdx.y * 128, n0 = blockIdx.x * 128;
    const int e = blockIdx.z;
    const u16* Ab = A + (size_t)e * sA;
    const u16* Bb = Bt + (size_t)e * sB;
    const int lr = lane & 15, lg = lane >> 4;

    f32x4 acc[4][4];
#pragma unroll
    for (int i = 0; i < 4; ++i)
#pragma unroll
        for (int j = 0; j < 4; ++j) acc[i][j] = zf4();

    const int row0 = tid >> 2;
    const int kc0 = (tid & 3) * 8;

    for (int kt = 0; kt < K; kt += 32) {
        const short8 a0 = *(const short8*)(Ab + (size_t)(m0 + row0) * K + kt + kc0);
        const short8 a1 = *(const short8*)(Ab + (size_t)(m0 + row0 + 64) * K + kt + kc0);
        const short8 b0 = *(const short8*)(Bb + (size_t)(n0 + row0) * K + kt + kc0);
        const short8 b1 = *(const short8*)(Bb + (size_t)(n0 + row0 + 64) * K + kt + kc0);
        __syncthreads();
        *(short8*)(As + tid * 8) = a0;
        *(short8*)(As + tid * 8 + 2048) = a1;
        *(short8*)(Bs + tid * 8) = b0;
        *(short8*)(Bs + tid * 8 + 2048) = b1;
        __syncthreads();
        short8 af[4], bf[4];
#pragma unroll
        for (int i = 0; i < 4; ++i) {
            af[i] = *(const short8*)(As + (wm * 64 + i * 16 + lr) * 32 + lg * 8);
            bf[i] = *(const short8*)(Bs + (wn * 64 + i * 16 + lr) * 32 + lg * 8);
        }
#pragma unroll
        for (int i = 0; i < 4; ++i)
#pragma unroll
            for (int j = 0; j < 4; ++j)
                acc[i][j] = __builtin_amdgcn_mfma_f32_16x16x32_bf16(af[i], bf[j], acc[i][j], 0, 0, 0);
    }

    const int r4 = lg * 4;
#pragma unroll
    for (int j = 0; j < 4; ++j) {
        const int col = n0 + wn * 64 + j * 16 + lr;
        const float bv = bias[(size_t)e * sBias + col];
#pragma unroll
        for (int i = 0; i < 4; ++i) {
#pragma unroll
            for (int r = 0; r < 4; ++r) {
                const int rowg = m0 + wm * 64 + i * 16 + r4 + r;
                float v = acc[i][j][r] + bv;
                if (MODE == 1) v = fmaxf(v, 0.f);
                Cout[(size_t)e * sC + (size_t)rowg * N + col] = f2b(v);
            }
        }
    }
}

// ---------------------------------------------------------------------------
// block reduce (double) over 256 threads
// ---------------------------------------------------------------------------
DEVI double block_reduce_d(double v, double* sred, int tid) {
#pragma unroll
    for (int off = 32; off > 0; off >>= 1) v += __shfl_down(v, off);
    __syncthreads();
    if ((tid & 63) == 0) sred[tid >> 6] = v;
    __syncthreads();
    return sred[0] + sred[1] + sred[2] + sred[3];
}

// ---------------------------------------------------------------------------
// LN1: x1f = LN(x + aproj)
// ---------------------------------------------------------------------------
__global__ __launch_bounds__(256)
void ln1_kernel(const float* __restrict__ x, const float* __restrict__ ap,
                const float* __restrict__ g, const float* __restrict__ b,
                float* __restrict__ x1f) {
    __shared__ double sred[4];
    const int t = blockIdx.x, tid = threadIdx.x;
    const float4 xv = ((const float4*)(x + (size_t)t * Dd))[tid];
    const float4 av = ((const float4*)(ap + (size_t)t * Dd))[tid];
    const double v0 = (double)xv.x + (double)av.x;
    const double v1 = (double)xv.y + (double)av.y;
    const double v2 = (double)xv.z + (double)av.z;
    const double v3 = (double)xv.w + (double)av.w;
    const double s = block_reduce_d(v0 + v1 + v2 + v3, sred, tid);
    const double mean = s * (1.0 / Dd);
    const double c0 = v0 - mean, c1 = v1 - mean, c2 = v2 - mean, c3 = v3 - mean;
    const double s2 = block_reduce_d(c0 * c0 + c1 * c1 + c2 * c2 + c3 * c3, sred, tid);
    const double rstd = 1.0 / sqrt(s2 * (1.0 / Dd) + 1e-5);
    const float4 gv = ((const float4*)g)[tid];
    const float4 bv = ((const float4*)b)[tid];
    float4 ov;
    ov.x = (float)(c0 * rstd * (double)gv.x + (double)bv.x);
    ov.y = (float)(c1 * rstd * (double)gv.y + (double)bv.y);
    ov.z = (float)(c2 * rstd * (double)gv.z + (double)bv.z);
    ov.w = (float)(c3 * rstd * (double)gv.w + (double)bv.w);
    ((float4*)(x1f + (size_t)t * Dd))[tid] = ov;
}

// ---------------------------------------------------------------------------
// gating stage 1 (fp64): logits = x1 @ wg, softmax, top-2. One wave per token.
// ---------------------------------------------------------------------------
__global__ __launch_bounds__(256)
void gate1_kernel(const float* __restrict__ x1f, const float* __restrict__ wg,
                  int* __restrict__ idx1, int* __restrict__ idx2,
                  float* __restrict__ gate1, float* __restrict__ gate2) {
    const int tid = threadIdx.x, lane = tid & 63, wid = tid >> 6;
    const int t = blockIdx.x * 4 + wid;
    double acc[16];
#pragma unroll
    for (int e = 0; e < 16; ++e) acc[e] = 0.0;
    for (int i = 0; i < 16; ++i) {
        const int d = i * 64 + lane;
        const double xv = (double)x1f[(size_t)t * Dd + d];
        const float4* wr = (const float4*)(wg + (size_t)d * 16);
        const float4 w0 = wr[0], w1 = wr[1], w2 = wr[2], w3 = wr[3];
        acc[0] += xv * (double)w0.x;  acc[1] += xv * (double)w0.y;
        acc[2] += xv * (double)w0.z;  acc[3] += xv * (double)w0.w;
        acc[4] += xv * (double)w1.x;  acc[5] += xv * (double)w1.y;
        acc[6] += xv * (double)w1.z;  acc[7] += xv * (double)w1.w;
        acc[8] += xv * (double)w2.x;  acc[9] += xv * (double)w2.y;
        acc[10] += xv * (double)w2.z; acc[11] += xv * (double)w2.w;
        acc[12] += xv * (double)w3.x; acc[13] += xv * (double)w3.y;
        acc[14] += xv * (double)w3.z; acc[15] += xv * (double)w3.w;
    }
#pragma unroll
    for (int e = 0; e < 16; ++e) {
        acc[e] += __shfl_xor(acc[e], 1);
        acc[e] += __shfl_xor(acc[e], 2);
        acc[e] += __shfl_xor(acc[e], 4);
        acc[e] += __shfl_xor(acc[e], 8);
        acc[e] += __shfl_xor(acc[e], 16);
        acc[e] += __shfl_xor(acc[e], 32);
    }
    if (lane == 0) {
        double mx = acc[0];
#pragma unroll
        for (int e = 1; e < 16; ++e) mx = fmax(mx, acc[e]);
        double z = 0.0, ex[16];
#pragma unroll
        for (int e = 0; e < 16; ++e) { ex[e] = exp(acc[e] - mx); z += ex[e]; }
        int b1 = 0; double v1 = acc[0];
#pragma unroll
        for (int e = 1; e < 16; ++e) if (acc[e] > v1) { v1 = acc[e]; b1 = e; }
        int b2 = (b1 == 0) ? 1 : 0; double v2 = acc[b2];
#pragma unroll
        for (int e = 0; e < 16; ++e) if (e != b1 && acc[e] > v2) { v2 = acc[e]; b2 = e; }
        const double rz = 1.0 / z;
        idx1[t] = b1; idx2[t] = b2;
        gate1[t] = (float)(ex[b1] * rz); gate2[t] = (float)(ex[b2] * rz);
    }
}

// ---------------------------------------------------------------------------
// gating stage 2 (single block): deterministic prefix positions + capacity.
// ---------------------------------------------------------------------------
__global__ __launch_bounds__(256)
void gate2_kernel(const int* __restrict__ idx1, const int* __restrict__ idx2,
                  const float* __restrict__ gate1, const float* __restrict__ gate2,
                  int* __restrict__ p1, int* __restrict__ p2,
                  int* __restrict__ k1, int* __restrict__ k2,
                  float* __restrict__ w1, float* __restrict__ w2) {
    __shared__ int hist[16];
    __shared__ unsigned long long sb1[4][16], sb2[4][16];
    __shared__ int sbase1[16], sbase2[16];
    const int tid = threadIdx.x, lane = tid & 63, wid = tid >> 6;
    if (tid < 16) hist[tid] = 0;
    __syncthreads();
    for (int t = tid; t < Tt; t += 256) atomicAdd(&hist[idx1[t]], 1);
    __syncthreads();
    if (tid < 16) { sbase1[tid] = 0; sbase2[tid] = hist[tid]; }
    __syncthreads();
    const unsigned long long below = (1ULL << lane) - 1ULL;
    for (int ch = 0; ch < Tt / 256; ++ch) {
        const int t = ch * 256 + tid;
        const int a = idx1[t], b = idx2[t];
#pragma unroll
        for (int e = 0; e < 16; ++e) {
            const unsigned long long m1 = __ballot(a == e);
            const unsigned long long m2 = __ballot(b == e);
            if (lane == 0) { sb1[wid][e] = m1; sb2[wid][e] = m2; }
        }
        __syncthreads();
        int r1 = __popcll(sb1[wid][a] & below);
        int r2 = __popcll(sb2[wid][b] & below);
#pragma unroll
        for (int w = 0; w < 4; ++w)
            if (w < wid) { r1 += __popcll(sb1[w][a]); r2 += __popcll(sb2[w][b]); }
        const int loc1 = sbase1[a] + r1, loc2 = sbase2[b] + r2;
        const int kk1 = loc1 < Cap, kk2 = loc2 < Cap;
        const float g1 = kk1 ? gate1[t] : 0.f;
        const float g2 = kk2 ? gate2[t] : 0.f;
        const float dn = fmaxf(g1 + g2, EPSc);
        p1[t] = kk1 ? loc1 : 0;
        p2[t] = kk2 ? loc2 : 0;
        k1[t] = kk1; k2[t] = kk2;
        w1[t] = g1 / dn; w2[t] = g2 / dn;
        __syncthreads();
        if (tid == 0) {
#pragma unroll
            for (int e = 0; e < 16; ++e) {
                int c1 = 0, c2 = 0;
#pragma unroll
                for (int w = 0; w < 4; ++w) { c1 += __popcll(sb1[w][e]); c2 += __popcll(sb2[w][e]); }
                sbase1[e] += c1; sbase2[e] += c2;
            }
        }
        __syncthreads();
    }
}

// ---------------------------------------------------------------------------
// dispatch: scatter kept tokens (f32 -> bf16) into [E,C,D] buffers (pre-zeroed)
// ---------------------------------------------------------------------------
__global__ __launch_bounds__(256)
void dispatch_kernel(const float* __restrict__ x1f,
                     const int* __restrict__ i1, const int* __restrict__ p1, const int* __restrict__ k1,
                     const int* __restrict__ i2, const int* __restrict__ p2, const int* __restrict__ k2,
                     u16* __restrict__ buf) {
    const int t = blockIdx.x, tid = threadIdx.x;
    const float4 v = ((const float4*)(x1f + (size_t)t * Dd))[tid];
    u16x4 pw;
    pw[0] = f2b(v.x); pw[1] = f2b(v.y); pw[2] = f2b(v.z); pw[3] = f2b(v.w);
    if (k1[t]) *(u16x4*)(buf + ((size_t)i1[t] * Cap + p1[t]) * Dd + tid * 4) = pw;
    if (k2[t]) *(u16x4*)(buf + ((size_t)i2[t] * Cap + p2[t]) * Dd + tid * 4) = pw;
}

// ---------------------------------------------------------------------------
// combine + residual + LN2 -> d_out (f32)
// ---------------------------------------------------------------------------
__global__ __launch_bounds__(256)
void combine_ln2(const float* __restrict__ x1f, const u16* __restrict__ y,
                 const int* __restrict__ i1, const int* __restrict__ p1, const float* __restrict__ w1,
                 const int* __restrict__ i2, const int* __restrict__ p2, const float* __restrict__ w2,
                 const float* __restrict__ g, const float* __restrict__ b,
                 float* __restrict__ out) {
    __shared__ double sred[4];
    const int t = blockIdx.x, tid = threadIdx.x;
    const size_t r1 = ((size_t)i1[t] * Cap + p1[t]) * Dd;
    const size_t r2 = ((size_t)i2[t] * Cap + p2[t]) * Dd;
    const double a1 = (double)w1[t], a2 = (double)w2[t];
    const u16x4 y1 = *(const u16x4*)(y + r1 + tid * 4);
    const u16x4 y2 = *(const u16x4*)(y + r2 + tid * 4);
    const float4 xv = ((const float4*)(x1f + (size_t)t * Dd))[tid];
    const double v0 = (double)xv.x + a1 * (double)b2f(y1[0]) + a2 * (double)b2f(y2[0]);
    const double v1 = (double)xv.y + a1 * (double)b2f(y1[1]) + a2 * (double)b2f(y2[1]);
    const double v2 = (double)xv.z + a1 * (double)b2f(y1[2]) + a2 * (double)b2f(y2[2]);
    const double v3 = (double)xv.w + a1 * (double)b2f(y1[3]) + a2 * (double)b2f(y2[3]);
    const double s = block_reduce_d(v0 + v1 + v2 + v3, sred, tid);
    const double mean = s * (1.0 / Dd);
    const double c0 = v0 - mean, c1 = v1 - mean, c2 = v2 - mean, c3 = v3 - mean;
    const double s2 = block_reduce_d(c0 * c0 + c1 * c1 + c2 * c2 + c3 * c3, sred, tid);
    const double rstd = 1.0 / sqrt(s2 * (1.0 / Dd) + 1e-5);
    const float4 gv = ((const float4*)g)[tid];
    const float4 bv = ((const float4*)b)[tid];
    float4 ov;
    ov.x = (float)(c0 * rstd * (double)gv.x + (double)bv.x);
    ov.y = (float)(c1 * rstd * (double)gv.y + (double)bv.y);
    ov.z = (float)(c2 * rstd * (double)gv.z + (double)bv.z);
    ov.w = (float)(c3 * rstd * (double)gv.w + (double)bv.w);
    ((float4*)(out + (size_t)t * Dd))[tid] = ov;
}

// ---------------------------------------------------------------------------
extern "C" void kernel_launch(void* const* d_in, const int* in_sizes, int n_in,
                              void* d_out, int out_size, void* d_ws, size_t ws_size,
                              hipStream_t stream) {
    (void)in_sizes; (void)n_in; (void)out_size; (void)ws_size;
    const float* x    = (const float*)d_in[0];
    const float* inW  = (const float*)d_in[1];
    const float* inB  = (const float*)d_in[2];
    const float* outW = (const float*)d_in[3];
    const float* outB = (const float*)d_in[4];
    const float* ln1g = (const float*)d_in[5];
    const float* ln1b = (const float*)d_in[6];
    const float* ln2g = (const float*)d_in[7];
    const float* ln2b = (const float*)d_in[8];
    const float* wg   = (const float*)d_in[9];
    const float* w1   = (const float*)d_in[10];
    const float* b1   = (const float*)d_in[11];
    const float* w2   = (const float*)d_in[12];
    const float* b2   = (const float*)d_in[13];
    float* out = (float*)d_out;

    char* ws = (char*)d_ws;
    size_t off = 0;
    auto alloc = [&](size_t bytes) -> char* {
        char* p = ws + off;
        off = (off + bytes + 255) & ~(size_t)255;
        return p;
    };

    const size_t sz_qkv = (size_t)Tt * D3 * 4;       // 100.7 MB f32
    const size_t sz_o   = (size_t)Tt * Dd * 4;       // 33.6 MB f32
    const size_t sz_h   = (size_t)Ee * Cap * DFF * 2; // 134.2 MB bf16
    // arena A: phase1 {qkv32, o32} / phase2 {hbuf}
    char* arenaA = alloc(sz_qkv + sz_o > sz_h ? sz_qkv + sz_o : sz_h);
    float* qkv32 = (float*)arenaA;
    float* o32   = (float*)(arenaA + sz_qkv);
    u16*   hbuf  = (u16*)arenaA;
    // arena B: {aproj} / {ebuf}
    char* arenaB = alloc((size_t)Tt * Dd * 4);
    float* aproj = (float*)arenaB;
    u16*   ebuf  = (u16*)arenaB;

    u16*   wt   = (u16*)alloc((size_t)Ee * DFF * Dd * 2);  // w1t then w2t
    u16*   ybuf = (u16*)alloc((size_t)Ee * Cap * Dd * 2);
    float* x1f  = (float*)alloc((size_t)Tt * Dd * 4);
    int*   idx1 = (int*)alloc(Tt * 4);
    int*   idx2 = (int*)alloc(Tt * 4);
    float* gt1  = (float*)alloc(Tt * 4);
    float* gt2  = (float*)alloc(Tt * 4);
    int*   p1   = (int*)alloc(Tt * 4);
    int*   p2   = (int*)alloc(Tt * 4);
    int*   k1   = (int*)alloc(Tt * 4);
    int*   k2   = (int*)alloc(Tt * 4);
    float* w1c  = (float*)alloc(Tt * 4);
    float* w2c  = (float*)alloc(Tt * 4);

    // 1: QKV projection (fp32, fp64 accum)
    gemm32<<<dim3(D3 / 64, Tt / 128), 256, 0, stream>>>(x, inW, qkv32, inB, Tt, D3, Dd);
    // 2: attention (fp32, fp64 accum)
    attn32<<<dim3(Ss / 64, Bz * Hh), 256, 0, stream>>>(qkv32, o32);
    // 3: output projection
    gemm32<<<dim3(Dd / 64, Tt / 128), 256, 0, stream>>>(o32, outW, aproj, outB, Tt, Dd, Dd);
    // 4: LN1
    ln1_kernel<<<Tt, 256, 0, stream>>>(x, aproj, ln1g, ln1b, x1f);
    // 5-6: gating
    gate1_kernel<<<Tt / 4, 256, 0, stream>>>(x1f, wg, idx1, idx2, gt1, gt2);
    gate2_kernel<<<1, 256, 0, stream>>>(idx1, idx2, gt1, gt2, p1, p2, k1, k2, w1c, w2c);
    // 7: dispatch
    hipMemsetAsync(ebuf, 0, (size_t)Ee * Cap * Dd * 2, stream);
    dispatch_kernel<<<Tt, 256, 0, stream>>>(x1f, idx1, p1, k1, idx2, p2, k2, ebuf);
    // 8-11: expert FFN (bf16 MFMA), wt staged sequentially
    tconv_kernel<<<dim3(DFF / 32, Dd / 32, Ee), 256, 0, stream>>>(w1, wt, Dd, DFF);
    gemm_bt<1><<<dim3(DFF / 128, Cap / 128, Ee), 256, 0, stream>>>(
        ebuf, wt, hbuf, b1, Cap, DFF, Dd,
        (size_t)Cap * Dd, (size_t)DFF * Dd, (size_t)Cap * DFF, DFF);
    tconv_kernel<<<dim3(Dd / 32, DFF / 32, Ee), 256, 0, stream>>>(w2, wt, DFF, Dd);
    gemm_bt<0><<<dim3(Dd / 128, Cap / 128, Ee), 256, 0, stream>>>(
        hbuf, wt, ybuf, b2, Cap, Dd, DFF,
        (size_t)Cap * DFF, (size_t)Dd * DFF, (size_t)Cap * Dd, Dd);
    // 12: combine + residual + LN2
    combine_ln2<<<Tt, 256, 0, stream>>>(x1f, ybuf, idx1, p1, w1c, idx2, p2, w2c, ln2g, ln2b, out);
}

// Round 3
// 2086.004 us; speedup vs baseline: 1.4202x; 1.4202x over previous
//
#include <hip/hip_runtime.h>
#include <cstdint>

#define DEVI __device__ __forceinline__

typedef short short8 __attribute__((ext_vector_type(8)));
typedef float f32x4 __attribute__((ext_vector_type(4)));
typedef unsigned short u16;
typedef u16 u16x4 __attribute__((ext_vector_type(4)));

static constexpr int Bz = 8, Ss = 1024, Dd = 1024, Hh = 16, HD = 64, DFF = 4096, Ee = 16;
static constexpr int Tt = Bz * Ss;           // 8192 tokens
static constexpr int Cap = (2 * Tt) / Ee;    // 1024 capacity
static constexpr int D3 = 3 * Dd;            // 3072
static constexpr float EPSc = 1.1920929e-07f;

DEVI u16 f2b(float f) {
    union { float f; uint32_t u; } v; v.f = f;
    return (u16)((v.u + 0x7FFFu + ((v.u >> 16) & 1u)) >> 16);
}
DEVI float b2f(u16 h) {
    union { uint32_t u; float f; } v; v.u = ((uint32_t)h) << 16; return v.f;
}
DEVI f32x4 zf4() { f32x4 v; v[0] = 0.f; v[1] = 0.f; v[2] = 0.f; v[3] = 0.f; return v; }

// swizzled u16 index for [R][64] bf16 tiles (128B rows): byte ^= (row&7)<<4
DEVI int swzb(int row, int col) {
    int byte = (row * 64 + col) * 2;
    byte ^= (row & 7) << 4;
    return byte >> 1;
}

// ---------------------------------------------------------------------------
// transpose + convert: in [Z][R][Cc] f32 -> out [Z][Cc][R] bf16
// ---------------------------------------------------------------------------
__global__ __launch_bounds__(256)
void tconv_kernel(const float* __restrict__ in, u16* __restrict__ out, int R, int Cc) {
    __shared__ float tile[32][33];
    const int z = blockIdx.z;
    const int r0 = blockIdx.y * 32, c0 = blockIdx.x * 32;
    const int tr = threadIdx.x >> 5, tc = threadIdx.x & 31;
    const float* ip = in + (size_t)z * R * Cc;
#pragma unroll
    for (int i = 0; i < 4; ++i)
        tile[tr + i * 8][tc] = ip[(size_t)(r0 + tr + i * 8) * Cc + c0 + tc];
    __syncthreads();
    u16* op = out + (size_t)z * R * Cc;
#pragma unroll
    for (int i = 0; i < 4; ++i)
        op[(size_t)(c0 + tr + i * 8) * R + r0 + tc] = f2b(tile[tc][tr + i * 8]);
}

// ---------------------------------------------------------------------------
// fp32 GEMM, fp64 accumulation: C[M,N] = A[M,K] * Bt[N,K]^T + bias
// ---------------------------------------------------------------------------
__global__ __launch_bounds__(256)
void gemm32(const float* __restrict__ A, const float* __restrict__ Bt,
            float* __restrict__ C, const float* __restrict__ bias,
            int M, int N, int K) {
    __shared__ float As[16][128];
    __shared__ float Bs[16][64];
    const int tid = threadIdx.x;
    const int m0 = blockIdx.y * 128, n0 = blockIdx.x * 64;
    const int rgp = tid >> 3, cgp = tid & 7;

    double accd[4][8];
    float acc[4][8];
#pragma unroll
    for (int i = 0; i < 4; ++i)
#pragma unroll
        for (int j = 0; j < 8; ++j) { accd[i][j] = 0.0; acc[i][j] = 0.f; }

    const int arow = tid >> 1, akq = (tid & 1) * 8;
    const int brow = tid >> 2, bkq = (tid & 3) * 4;

    for (int kt = 0; kt < K; kt += 16) {
        const float4 a0 = *(const float4*)(A + (size_t)(m0 + arow) * K + kt + akq);
        const float4 a1 = *(const float4*)(A + (size_t)(m0 + arow) * K + kt + akq + 4);
        const float4 b0 = *(const float4*)(Bt + (size_t)(n0 + brow) * K + kt + bkq);
        __syncthreads();
        As[akq + 0][arow] = a0.x; As[akq + 1][arow] = a0.y;
        As[akq + 2][arow] = a0.z; As[akq + 3][arow] = a0.w;
        As[akq + 4][arow] = a1.x; As[akq + 5][arow] = a1.y;
        As[akq + 6][arow] = a1.z; As[akq + 7][arow] = a1.w;
        Bs[bkq + 0][brow] = b0.x; Bs[bkq + 1][brow] = b0.y;
        Bs[bkq + 2][brow] = b0.z; Bs[bkq + 3][brow] = b0.w;
        __syncthreads();
#pragma unroll
        for (int k = 0; k < 16; ++k) {
            const float4 av = *(const float4*)(&As[k][rgp * 4]);
            const float4 bv0 = *(const float4*)(&Bs[k][cgp * 8]);
            const float4 bv1 = *(const float4*)(&Bs[k][cgp * 8 + 4]);
            const float a4[4] = {av.x, av.y, av.z, av.w};
            const float b8[8] = {bv0.x, bv0.y, bv0.z, bv0.w, bv1.x, bv1.y, bv1.z, bv1.w};
#pragma unroll
            for (int i = 0; i < 4; ++i)
#pragma unroll
                for (int j = 0; j < 8; ++j) acc[i][j] = fmaf(a4[i], b8[j], acc[i][j]);
        }
#pragma unroll
        for (int i = 0; i < 4; ++i)
#pragma unroll
            for (int j = 0; j < 8; ++j) { accd[i][j] += (double)acc[i][j]; acc[i][j] = 0.f; }
    }

    float bj[8];
#pragma unroll
    for (int j = 0; j < 8; ++j) bj[j] = bias[n0 + cgp * 8 + j];
#pragma unroll
    for (int i = 0; i < 4; ++i) {
        const size_t row = (size_t)(m0 + rgp * 4 + i);
        float4 o0, o1;
        o0.x = (float)(accd[i][0] + (double)bj[0]);
        o0.y = (float)(accd[i][1] + (double)bj[1]);
        o0.z = (float)(accd[i][2] + (double)bj[2]);
        o0.w = (float)(accd[i][3] + (double)bj[3]);
        o1.x = (float)(accd[i][4] + (double)bj[4]);
        o1.y = (float)(accd[i][5] + (double)bj[5]);
        o1.z = (float)(accd[i][6] + (double)bj[6]);
        o1.w = (float)(accd[i][7] + (double)bj[7]);
        *(float4*)(C + row * N + n0 + cgp * 8) = o0;
        *(float4*)(C + row * N + n0 + cgp * 8 + 4) = o1;
    }
}

// ---------------------------------------------------------------------------
// Split-bf16 MFMA flash attention, fp32-equivalent precision.
// Q,K,P,V each split hi+lo bf16; all 4 cross products kept (err ~2^-18).
// Block = (64 q-rows, b*h); 4 waves, wave owns 16 q-rows.
// LDS tiles [.][64] bf16 with XOR swizzle byte^=(row&7)<<4.
// ---------------------------------------------------------------------------
__global__ __launch_bounds__(256)
void attn_mfma(const float* __restrict__ qkv, float* __restrict__ o) {
    __shared__ u16 Khi[64 * 64], Klo[64 * 64];
    __shared__ u16 Vhi[64 * 64], Vlo[64 * 64];   // transposed: [d][kk]
    __shared__ u16 Phi[4][16 * 64], Plo[4][16 * 64];

    const int qt = blockIdx.x, bh = blockIdx.y;
    const int bb = bh >> 4, hh = bh & 15;
    const int tid = threadIdx.x, lane = tid & 63, wid = tid >> 6;
    const int lr = lane & 15, lg = lane >> 4;

    // Q fragments (A-layout: row lr, cols ks*32 + lg*8), 0.125 scale folded in
    short8 qhi[2], qlo[2];
    {
        const float* qp = qkv + ((size_t)(bb * Ss + qt * 64 + wid * 16 + lr)) * D3 + hh * HD;
#pragma unroll
        for (int ks = 0; ks < 2; ++ks) {
            const float4 f0 = *(const float4*)(qp + ks * 32 + lg * 8);
            const float4 f1 = *(const float4*)(qp + ks * 32 + lg * 8 + 4);
            const float f[8] = {f0.x, f0.y, f0.z, f0.w, f1.x, f1.y, f1.z, f1.w};
#pragma unroll
            for (int j = 0; j < 8; ++j) {
                const float fs = f[j] * 0.125f;
                const u16 h = f2b(fs);
                qhi[ks][j] = (short)h;
                qlo[ks][j] = (short)f2b(fs - b2f(h));
            }
        }
    }

    float mrun[4], lrun[4];
    f32x4 oacc[4];
#pragma unroll
    for (int r = 0; r < 4; ++r) { mrun[r] = -1e30f; lrun[r] = 0.f; }
#pragma unroll
    for (int nf = 0; nf < 4; ++nf) oacc[nf] = zf4();

    const int srow = tid >> 2;        // 0..63
    const int sd = (tid & 3) * 16;    // 0,16,32,48

    u16* const PhiW = Phi[wid];
    u16* const PloW = Plo[wid];

    for (int kt = 0; kt < Ss / 64; ++kt) {
        // ---- stage K,V (split hi/lo) ----
        const float* kp = qkv + ((size_t)(bb * Ss + kt * 64 + srow)) * D3 + hh * HD + sd;
        float4 kq[4], vq[4];
#pragma unroll
        for (int q = 0; q < 4; ++q) {
            kq[q] = *(const float4*)(kp + Dd + q * 4);
            vq[q] = *(const float4*)(kp + 2 * Dd + q * 4);
        }
        __syncthreads();
        {
            const float kf[16] = {kq[0].x, kq[0].y, kq[0].z, kq[0].w, kq[1].x, kq[1].y, kq[1].z, kq[1].w,
                                  kq[2].x, kq[2].y, kq[2].z, kq[2].w, kq[3].x, kq[3].y, kq[3].z, kq[3].w};
            const float vf[16] = {vq[0].x, vq[0].y, vq[0].z, vq[0].w, vq[1].x, vq[1].y, vq[1].z, vq[1].w,
                                  vq[2].x, vq[2].y, vq[2].z, vq[2].w, vq[3].x, vq[3].y, vq[3].z, vq[3].w};
            short8 kh[2], kl[2];
#pragma unroll
            for (int half = 0; half < 2; ++half)
#pragma unroll
                for (int j = 0; j < 8; ++j) {
                    const float f = kf[half * 8 + j];
                    const u16 h = f2b(f);
                    kh[half][j] = (short)h;
                    kl[half][j] = (short)f2b(f - b2f(h));
                }
            *(short8*)(Khi + swzb(srow, sd)) = kh[0];
            *(short8*)(Khi + swzb(srow, sd + 8)) = kh[1];
            *(short8*)(Klo + swzb(srow, sd)) = kl[0];
            *(short8*)(Klo + swzb(srow, sd + 8)) = kl[1];
#pragma unroll
            for (int j = 0; j < 16; ++j) {
                const float f = vf[j];
                const u16 h = f2b(f);
                const int d = sd + j;
                Vhi[swzb(d, srow)] = h;
                Vlo[swzb(d, srow)] = f2b(f - b2f(h));
            }
        }
        __syncthreads();

        // ---- QK^T: 4 products per frag ----
        f32x4 sc[4];
#pragma unroll
        for (int nf = 0; nf < 4; ++nf) sc[nf] = zf4();
#pragma unroll
        for (int nf = 0; nf < 4; ++nf)
#pragma unroll
            for (int ks = 0; ks < 2; ++ks) {
                const short8 kh = *(const short8*)(Khi + swzb(nf * 16 + lr, ks * 32 + lg * 8));
                const short8 kl = *(const short8*)(Klo + swzb(nf * 16 + lr, ks * 32 + lg * 8));
                sc[nf] = __builtin_amdgcn_mfma_f32_16x16x32_bf16(qhi[ks], kh, sc[nf], 0, 0, 0);
                sc[nf] = __builtin_amdgcn_mfma_f32_16x16x32_bf16(qhi[ks], kl, sc[nf], 0, 0, 0);
                sc[nf] = __builtin_amdgcn_mfma_f32_16x16x32_bf16(qlo[ks], kh, sc[nf], 0, 0, 0);
                sc[nf] = __builtin_amdgcn_mfma_f32_16x16x32_bf16(qlo[ks], kl, sc[nf], 0, 0, 0);
            }

        // ---- online softmax (row = lg*4+r, col = nf*16+lr) ----
        float scl[4];
#pragma unroll
        for (int r = 0; r < 4; ++r) {
            float m = fmaxf(fmaxf(sc[0][r], sc[1][r]), fmaxf(sc[2][r], sc[3][r]));
            m = fmaxf(m, __shfl_xor(m, 1));
            m = fmaxf(m, __shfl_xor(m, 2));
            m = fmaxf(m, __shfl_xor(m, 4));
            m = fmaxf(m, __shfl_xor(m, 8));
            const float mn = fmaxf(mrun[r], m);
            scl[r] = __expf(mrun[r] - mn);
            mrun[r] = mn;
            float s = 0.f;
#pragma unroll
            for (int nf = 0; nf < 4; ++nf) {
                const float p = __expf(sc[nf][r] - mn);
                sc[nf][r] = p;
                s += p;
            }
            s += __shfl_xor(s, 1);
            s += __shfl_xor(s, 2);
            s += __shfl_xor(s, 4);
            s += __shfl_xor(s, 8);
            lrun[r] = lrun[r] * scl[r] + s;
        }

        // ---- P split -> per-wave LDS (A-layout rows) ----
#pragma unroll
        for (int nf = 0; nf < 4; ++nf)
#pragma unroll
            for (int r = 0; r < 4; ++r) {
                const float p = sc[nf][r];
                const u16 h = f2b(p);
                const int idx = swzb(lg * 4 + r, nf * 16 + lr);
                PhiW[idx] = h;
                PloW[idx] = f2b(p - b2f(h));
            }

        // ---- rescale O, then PV ----
#pragma unroll
        for (int nf = 0; nf < 4; ++nf)
#pragma unroll
            for (int r = 0; r < 4; ++r) oacc[nf][r] *= scl[r];

#pragma unroll
        for (int ks = 0; ks < 2; ++ks) {
            const short8 ph = *(const short8*)(PhiW + swzb(lr, ks * 32 + lg * 8));
            const short8 pl = *(const short8*)(PloW + swzb(lr, ks * 32 + lg * 8));
#pragma unroll
            for (int nf = 0; nf < 4; ++nf) {
                const short8 vh = *(const short8*)(Vhi + swzb(nf * 16 + lr, ks * 32 + lg * 8));
                const short8 vl = *(const short8*)(Vlo + swzb(nf * 16 + lr, ks * 32 + lg * 8));
                oacc[nf] = __builtin_amdgcn_mfma_f32_16x16x32_bf16(ph, vh, oacc[nf], 0, 0, 0);
                oacc[nf] = __builtin_amdgcn_mfma_f32_16x16x32_bf16(ph, vl, oacc[nf], 0, 0, 0);
                oacc[nf] = __builtin_amdgcn_mfma_f32_16x16x32_bf16(pl, vh, oacc[nf], 0, 0, 0);
                oacc[nf] = __builtin_amdgcn_mfma_f32_16x16x32_bf16(pl, vl, oacc[nf], 0, 0, 0);
            }
        }
    }

#pragma unroll
    for (int r = 0; r < 4; ++r) {
        const float inv = 1.f / lrun[r];
        float* op = o + ((size_t)(bb * Ss + qt * 64 + wid * 16 + lg * 4 + r)) * Dd + hh * HD;
#pragma unroll
        for (int nf = 0; nf < 4; ++nf)
            op[nf * 16 + lr] = oacc[nf][r] * inv;
    }
}

// ---------------------------------------------------------------------------
// BT-GEMM bf16 MFMA (expert FFN)
// ---------------------------------------------------------------------------
template <int MODE>
__global__ __launch_bounds__(256)
void gemm_bt(const u16* __restrict__ A, const u16* __restrict__ Bt, u16* __restrict__ Cout,
             const float* __restrict__ bias, int M, int N, int K,
             size_t sA, size_t sB, size_t sC, int sBias) {
    __shared__ u16 As[128 * 32];
    __shared__ u16 Bs[128 * 32];
    const int tid = threadIdx.x;
    const int lane = tid & 63, wid = tid >> 6;
    const int wm = wid >> 1, wn = wid & 1;
    const int m0 = blockIdx.y * 128, n0 = blockIdx.x * 128;
    const int e = blockIdx.z;
    const u16* Ab = A + (size_t)e * sA;
    const u16* Bb = Bt + (size_t)e * sB;
    const int lr = lane & 15, lg = lane >> 4;

    f32x4 acc[4][4];
#pragma unroll
    for (int i = 0; i < 4; ++i)
#pragma unroll
        for (int j = 0; j < 4; ++j) acc[i][j] = zf4();

    const int row0 = tid >> 2;
    const int kc0 = (tid & 3) * 8;

    for (int kt = 0; kt < K; kt += 32) {
        const short8 a0 = *(const short8*)(Ab + (size_t)(m0 + row0) * K + kt + kc0);
        const short8 a1 = *(const short8*)(Ab + (size_t)(m0 + row0 + 64) * K + kt + kc0);
        const short8 b0 = *(const short8*)(Bb + (size_t)(n0 + row0) * K + kt + kc0);
        const short8 b1 = *(const short8*)(Bb + (size_t)(n0 + row0 + 64) * K + kt + kc0);
        __syncthreads();
        *(short8*)(As + tid * 8) = a0;
        *(short8*)(As + tid * 8 + 2048) = a1;
        *(short8*)(Bs + tid * 8) = b0;
        *(short8*)(Bs + tid * 8 + 2048) = b1;
        __syncthreads();
        short8 af[4], bf[4];
#pragma unroll
        for (int i = 0; i < 4; ++i) {
            af[i] = *(const short8*)(As + (wm * 64 + i * 16 + lr) * 32 + lg * 8);
            bf[i] = *(const short8*)(Bs + (wn * 64 + i * 16 + lr) * 32 + lg * 8);
        }
#pragma unroll
        for (int i = 0; i < 4; ++i)
#pragma unroll
            for (int j = 0; j < 4; ++j)
                acc[i][j] = __builtin_amdgcn_mfma_f32_16x16x32_bf16(af[i], bf[j], acc[i][j], 0, 0, 0);
    }

    const int r4 = lg * 4;
#pragma unroll
    for (int j = 0; j < 4; ++j) {
        const int col = n0 + wn * 64 + j * 16 + lr;
        const float bv = bias[(size_t)e * sBias + col];
#pragma unroll
        for (int i = 0; i < 4; ++i) {
#pragma unroll
            for (int r = 0; r < 4; ++r) {
                const int rowg = m0 + wm * 64 + i * 16 + r4 + r;
                float v = acc[i][j][r] + bv;
                if (MODE == 1) v = fmaxf(v, 0.f);
                Cout[(size_t)e * sC + (size_t)rowg * N + col] = f2b(v);
            }
        }
    }
}

// ---------------------------------------------------------------------------
DEVI double block_reduce_d(double v, double* sred, int tid) {
#pragma unroll
    for (int off = 32; off > 0; off >>= 1) v += __shfl_down(v, off);
    __syncthreads();
    if ((tid & 63) == 0) sred[tid >> 6] = v;
    __syncthreads();
    return sred[0] + sred[1] + sred[2] + sred[3];
}

// ---------------------------------------------------------------------------
// LN1: x1f = LN(x + aproj)
// ---------------------------------------------------------------------------
__global__ __launch_bounds__(256)
void ln1_kernel(const float* __restrict__ x, const float* __restrict__ ap,
                const float* __restrict__ g, const float* __restrict__ b,
                float* __restrict__ x1f) {
    __shared__ double sred[4];
    const int t = blockIdx.x, tid = threadIdx.x;
    const float4 xv = ((const float4*)(x + (size_t)t * Dd))[tid];
    const float4 av = ((const float4*)(ap + (size_t)t * Dd))[tid];
    const double v0 = (double)xv.x + (double)av.x;
    const double v1 = (double)xv.y + (double)av.y;
    const double v2 = (double)xv.z + (double)av.z;
    const double v3 = (double)xv.w + (double)av.w;
    const double s = block_reduce_d(v0 + v1 + v2 + v3, sred, tid);
    const double mean = s * (1.0 / Dd);
    const double c0 = v0 - mean, c1 = v1 - mean, c2 = v2 - mean, c3 = v3 - mean;
    const double s2 = block_reduce_d(c0 * c0 + c1 * c1 + c2 * c2 + c3 * c3, sred, tid);
    const double rstd = 1.0 / sqrt(s2 * (1.0 / Dd) + 1e-5);
    const float4 gv = ((const float4*)g)[tid];
    const float4 bv = ((const float4*)b)[tid];
    float4 ov;
    ov.x = (float)(c0 * rstd * (double)gv.x + (double)bv.x);
    ov.y = (float)(c1 * rstd * (double)gv.y + (double)bv.y);
    ov.z = (float)(c2 * rstd * (double)gv.z + (double)bv.z);
    ov.w = (float)(c3 * rstd * (double)gv.w + (double)bv.w);
    ((float4*)(x1f + (size_t)t * Dd))[tid] = ov;
}

// ---------------------------------------------------------------------------
// gating stage 1 (fp64)
// ---------------------------------------------------------------------------
__global__ __launch_bounds__(256)
void gate1_kernel(const float* __restrict__ x1f, const float* __restrict__ wg,
                  int* __restrict__ idx1, int* __restrict__ idx2,
                  float* __restrict__ gate1, float* __restrict__ gate2) {
    const int tid = threadIdx.x, lane = tid & 63, wid = tid >> 6;
    const int t = blockIdx.x * 4 + wid;
    double acc[16];
#pragma unroll
    for (int e = 0; e < 16; ++e) acc[e] = 0.0;
    for (int i = 0; i < 16; ++i) {
        const int d = i * 64 + lane;
        const double xv = (double)x1f[(size_t)t * Dd + d];
        const float4* wr = (const float4*)(wg + (size_t)d * 16);
        const float4 w0 = wr[0], w1 = wr[1], w2 = wr[2], w3 = wr[3];
        acc[0] += xv * (double)w0.x;  acc[1] += xv * (double)w0.y;
        acc[2] += xv * (double)w0.z;  acc[3] += xv * (double)w0.w;
        acc[4] += xv * (double)w1.x;  acc[5] += xv * (double)w1.y;
        acc[6] += xv * (double)w1.z;  acc[7] += xv * (double)w1.w;
        acc[8] += xv * (double)w2.x;  acc[9] += xv * (double)w2.y;
        acc[10] += xv * (double)w2.z; acc[11] += xv * (double)w2.w;
        acc[12] += xv * (double)w3.x; acc[13] += xv * (double)w3.y;
        acc[14] += xv * (double)w3.z; acc[15] += xv * (double)w3.w;
    }
#pragma unroll
    for (int e = 0; e < 16; ++e) {
        acc[e] += __shfl_xor(acc[e], 1);
        acc[e] += __shfl_xor(acc[e], 2);
        acc[e] += __shfl_xor(acc[e], 4);
        acc[e] += __shfl_xor(acc[e], 8);
        acc[e] += __shfl_xor(acc[e], 16);
        acc[e] += __shfl_xor(acc[e], 32);
    }
    if (lane == 0) {
        double mx = acc[0];
#pragma unroll
        for (int e = 1; e < 16; ++e) mx = fmax(mx, acc[e]);
        double z = 0.0, ex[16];
#pragma unroll
        for (int e = 0; e < 16; ++e) { ex[e] = exp(acc[e] - mx); z += ex[e]; }
        int b1 = 0; double v1 = acc[0];
#pragma unroll
        for (int e = 1; e < 16; ++e) if (acc[e] > v1) { v1 = acc[e]; b1 = e; }
        int b2 = (b1 == 0) ? 1 : 0; double v2 = acc[b2];
#pragma unroll
        for (int e = 0; e < 16; ++e) if (e != b1 && acc[e] > v2) { v2 = acc[e]; b2 = e; }
        const double rz = 1.0 / z;
        idx1[t] = b1; idx2[t] = b2;
        gate1[t] = (float)(ex[b1] * rz); gate2[t] = (float)(ex[b2] * rz);
    }
}

// ---------------------------------------------------------------------------
// gating stage 2 (single block)
// ---------------------------------------------------------------------------
__global__ __launch_bounds__(256)
void gate2_kernel(const int* __restrict__ idx1, const int* __restrict__ idx2,
                  const float* __restrict__ gate1, const float* __restrict__ gate2,
                  int* __restrict__ p1, int* __restrict__ p2,
                  int* __restrict__ k1, int* __restrict__ k2,
                  float* __restrict__ w1, float* __restrict__ w2) {
    __shared__ int hist[16];
    __shared__ unsigned long long sb1[4][16], sb2[4][16];
    __shared__ int sbase1[16], sbase2[16];
    const int tid = threadIdx.x, lane = tid & 63, wid = tid >> 6;
    if (tid < 16) hist[tid] = 0;
    __syncthreads();
    for (int t = tid; t < Tt; t += 256) atomicAdd(&hist[idx1[t]], 1);
    __syncthreads();
    if (tid < 16) { sbase1[tid] = 0; sbase2[tid] = hist[tid]; }
    __syncthreads();
    const unsigned long long below = (1ULL << lane) - 1ULL;
    for (int ch = 0; ch < Tt / 256; ++ch) {
        const int t = ch * 256 + tid;
        const int a = idx1[t], b = idx2[t];
#pragma unroll
        for (int e = 0; e < 16; ++e) {
            const unsigned long long m1 = __ballot(a == e);
            const unsigned long long m2 = __ballot(b == e);
            if (lane == 0) { sb1[wid][e] = m1; sb2[wid][e] = m2; }
        }
        __syncthreads();
        int r1 = __popcll(sb1[wid][a] & below);
        int r2 = __popcll(sb2[wid][b] & below);
#pragma unroll
        for (int w = 0; w < 4; ++w)
            if (w < wid) { r1 += __popcll(sb1[w][a]); r2 += __popcll(sb2[w][b]); }
        const int loc1 = sbase1[a] + r1, loc2 = sbase2[b] + r2;
        const int kk1 = loc1 < Cap, kk2 = loc2 < Cap;
        const float g1 = kk1 ? gate1[t] : 0.f;
        const float g2 = kk2 ? gate2[t] : 0.f;
        const float dn = fmaxf(g1 + g2, EPSc);
        p1[t] = kk1 ? loc1 : 0;
        p2[t] = kk2 ? loc2 : 0;
        k1[t] = kk1; k2[t] = kk2;
        w1[t] = g1 / dn; w2[t] = g2 / dn;
        __syncthreads();
        if (tid == 0) {
#pragma unroll
            for (int e = 0; e < 16; ++e) {
                int c1 = 0, c2 = 0;
#pragma unroll
                for (int w = 0; w < 4; ++w) { c1 += __popcll(sb1[w][e]); c2 += __popcll(sb2[w][e]); }
                sbase1[e] += c1; sbase2[e] += c2;
            }
        }
        __syncthreads();
    }
}

// ---------------------------------------------------------------------------
// dispatch: scatter kept tokens (f32 -> bf16) into [E,C,D] buffers (pre-zeroed)
// ---------------------------------------------------------------------------
__global__ __launch_bounds__(256)
void dispatch_kernel(const float* __restrict__ x1f,
                     const int* __restrict__ i1, const int* __restrict__ p1, const int* __restrict__ k1,
                     const int* __restrict__ i2, const int* __restrict__ p2, const int* __restrict__ k2,
                     u16* __restrict__ buf) {
    const int t = blockIdx.x, tid = threadIdx.x;
    const float4 v = ((const float4*)(x1f + (size_t)t * Dd))[tid];
    u16x4 pw;
    pw[0] = f2b(v.x); pw[1] = f2b(v.y); pw[2] = f2b(v.z); pw[3] = f2b(v.w);
    if (k1[t]) *(u16x4*)(buf + ((size_t)i1[t] * Cap + p1[t]) * Dd + tid * 4) = pw;
    if (k2[t]) *(u16x4*)(buf + ((size_t)i2[t] * Cap + p2[t]) * Dd + tid * 4) = pw;
}

// ---------------------------------------------------------------------------
// combine + residual + LN2 -> d_out (f32)
// ---------------------------------------------------------------------------
__global__ __launch_bounds__(256)
void combine_ln2(const float* __restrict__ x1f, const u16* __restrict__ y,
                 const int* __restrict__ i1, const int* __restrict__ p1, const float* __restrict__ w1,
                 const int* __restrict__ i2, const int* __restrict__ p2, const float* __restrict__ w2,
                 const float* __restrict__ g, const float* __restrict__ b,
                 float* __restrict__ out) {
    __shared__ double sred[4];
    const int t = blockIdx.x, tid = threadIdx.x;
    const size_t r1 = ((size_t)i1[t] * Cap + p1[t]) * Dd;
    const size_t r2 = ((size_t)i2[t] * Cap + p2[t]) * Dd;
    const double a1 = (double)w1[t], a2 = (double)w2[t];
    const u16x4 y1 = *(const u16x4*)(y + r1 + tid * 4);
    const u16x4 y2 = *(const u16x4*)(y + r2 + tid * 4);
    const float4 xv = ((const float4*)(x1f + (size_t)t * Dd))[tid];
    const double v0 = (double)xv.x + a1 * (double)b2f(y1[0]) + a2 * (double)b2f(y2[0]);
    const double v1 = (double)xv.y + a1 * (double)b2f(y1[1]) + a2 * (double)b2f(y2[1]);
    const double v2 = (double)xv.z + a1 * (double)b2f(y1[2]) + a2 * (double)b2f(y2[2]);
    const double v3 = (double)xv.w + a1 * (double)b2f(y1[3]) + a2 * (double)b2f(y2[3]);
    const double s = block_reduce_d(v0 + v1 + v2 + v3, sred, tid);
    const double mean = s * (1.0 / Dd);
    const double c0 = v0 - mean, c1 = v1 - mean, c2 = v2 - mean, c3 = v3 - mean;
    const double s2 = block_reduce_d(c0 * c0 + c1 * c1 + c2 * c2 + c3 * c3, sred, tid);
    const double rstd = 1.0 / sqrt(s2 * (1.0 / Dd) + 1e-5);
    const float4 gv = ((const float4*)g)[tid];
    const float4 bv = ((const float4*)b)[tid];
    float4 ov;
    ov.x = (float)(c0 * rstd * (double)gv.x + (double)bv.x);
    ov.y = (float)(c1 * rstd * (double)gv.y + (double)bv.y);
    ov.z = (float)(c2 * rstd * (double)gv.z + (double)bv.z);
    ov.w = (float)(c3 * rstd * (double)gv.w + (double)bv.w);
    ((float4*)(out + (size_t)t * Dd))[tid] = ov;
}

// ---------------------------------------------------------------------------
extern "C" void kernel_launch(void* const* d_in, const int* in_sizes, int n_in,
                              void* d_out, int out_size, void* d_ws, size_t ws_size,
                              hipStream_t stream) {
    (void)in_sizes; (void)n_in; (void)out_size; (void)ws_size;
    const float* x    = (const float*)d_in[0];
    const float* inW  = (const float*)d_in[1];
    const float* inB  = (const float*)d_in[2];
    const float* outW = (const float*)d_in[3];
    const float* outB = (const float*)d_in[4];
    const float* ln1g = (const float*)d_in[5];
    const float* ln1b = (const float*)d_in[6];
    const float* ln2g = (const float*)d_in[7];
    const float* ln2b = (const float*)d_in[8];
    const float* wg   = (const float*)d_in[9];
    const float* w1   = (const float*)d_in[10];
    const float* b1   = (const float*)d_in[11];
    const float* w2   = (const float*)d_in[12];
    const float* b2   = (const float*)d_in[13];
    float* out = (float*)d_out;

    char* ws = (char*)d_ws;
    size_t off = 0;
    auto alloc = [&](size_t bytes) -> char* {
        char* p = ws + off;
        off = (off + bytes + 255) & ~(size_t)255;
        return p;
    };

    const size_t sz_qkv = (size_t)Tt * D3 * 4;        // 100.7 MB f32
    const size_t sz_o   = (size_t)Tt * Dd * 4;        // 33.6 MB f32
    const size_t sz_h   = (size_t)Ee * Cap * DFF * 2; // 134.2 MB bf16
    char* arenaA = alloc(sz_qkv + sz_o > sz_h ? sz_qkv + sz_o : sz_h);
    float* qkv32 = (float*)arenaA;
    float* o32   = (float*)(arenaA + sz_qkv);
    u16*   hbuf  = (u16*)arenaA;
    char* arenaB = alloc((size_t)Tt * Dd * 4);
    float* aproj = (float*)arenaB;
    u16*   ebuf  = (u16*)arenaB;

    u16*   wt   = (u16*)alloc((size_t)Ee * DFF * Dd * 2);
    u16*   ybuf = (u16*)alloc((size_t)Ee * Cap * Dd * 2);
    float* x1f  = (float*)alloc((size_t)Tt * Dd * 4);
    int*   idx1 = (int*)alloc(Tt * 4);
    int*   idx2 = (int*)alloc(Tt * 4);
    float* gt1  = (float*)alloc(Tt * 4);
    float* gt2  = (float*)alloc(Tt * 4);
    int*   p1   = (int*)alloc(Tt * 4);
    int*   p2   = (int*)alloc(Tt * 4);
    int*   k1   = (int*)alloc(Tt * 4);
    int*   k2   = (int*)alloc(Tt * 4);
    float* w1c  = (float*)alloc(Tt * 4);
    float* w2c  = (float*)alloc(Tt * 4);

    // 1: QKV projection (fp32, fp64 accum)
    gemm32<<<dim3(D3 / 64, Tt / 128), 256, 0, stream>>>(x, inW, qkv32, inB, Tt, D3, Dd);
    // 2: attention (split-bf16 MFMA, fp32-equivalent)
    attn_mfma<<<dim3(Ss / 64, Bz * Hh), 256, 0, stream>>>(qkv32, o32);
    // 3: output projection
    gemm32<<<dim3(Dd / 64, Tt / 128), 256, 0, stream>>>(o32, outW, aproj, outB, Tt, Dd, Dd);
    // 4: LN1
    ln1_kernel<<<Tt, 256, 0, stream>>>(x, aproj, ln1g, ln1b, x1f);
    // 5-6: gating
    gate1_kernel<<<Tt / 4, 256, 0, stream>>>(x1f, wg, idx1, idx2, gt1, gt2);
    gate2_kernel<<<1, 256, 0, stream>>>(idx1, idx2, gt1, gt2, p1, p2, k1, k2, w1c, w2c);
    // 7: dispatch
    hipMemsetAsync(ebuf, 0, (size_t)Ee * Cap * Dd * 2, stream);
    dispatch_kernel<<<Tt, 256, 0, stream>>>(x1f, idx1, p1, k1, idx2, p2, k2, ebuf);
    // 8-11: expert FFN (bf16 MFMA), wt staged sequentially
    tconv_kernel<<<dim3(DFF / 32, Dd / 32, Ee), 256, 0, stream>>>(w1, wt, Dd, DFF);
    gemm_bt<1><<<dim3(DFF / 128, Cap / 128, Ee), 256, 0, stream>>>(
        ebuf, wt, hbuf, b1, Cap, DFF, Dd,
        (size_t)Cap * Dd, (size_t)DFF * Dd, (size_t)Cap * DFF, DFF);
    tconv_kernel<<<dim3(Dd / 32, DFF / 32, Ee), 256, 0, stream>>>(w2, wt, DFF, Dd);
    gemm_bt<0><<<dim3(Dd / 128, Cap / 128, Ee), 256, 0, stream>>>(
        hbuf, wt, ybuf, b2, Cap, Dd, DFF,
        (size_t)Cap * DFF, (size_t)Dd * DFF, (size_t)Cap * Dd, Dd);
    // 12: combine + residual + LN2
    combine_ln2<<<Tt, 256, 0, stream>>>(x1f, ybuf, idx1, p1, w1c, idx2, p2, w2c, ln2g, ln2b, out);
}

// Round 4
// 1481.611 us; speedup vs baseline: 1.9995x; 1.4079x over previous
//
#include <hip/hip_runtime.h>
#include <cstdint>

#define DEVI __device__ __forceinline__

typedef short short8 __attribute__((ext_vector_type(8)));
typedef float f32x4 __attribute__((ext_vector_type(4)));
typedef unsigned short u16;
typedef u16 u16x4 __attribute__((ext_vector_type(4)));

static constexpr int Bz = 8, Ss = 1024, Dd = 1024, Hh = 16, HD = 64, DFF = 4096, Ee = 16;
static constexpr int Tt = Bz * Ss;           // 8192 tokens
static constexpr int Cap = (2 * Tt) / Ee;    // 1024 capacity
static constexpr int D3 = 3 * Dd;            // 3072
static constexpr float EPSc = 1.1920929e-07f;

DEVI u16 f2b(float f) {
    union { float f; uint32_t u; } v; v.f = f;
    return (u16)((v.u + 0x7FFFu + ((v.u >> 16) & 1u)) >> 16);
}
DEVI float b2f(u16 h) {
    union { uint32_t u; float f; } v; v.u = ((uint32_t)h) << 16; return v.f;
}
DEVI f32x4 zf4() { f32x4 v; v[0] = 0.f; v[1] = 0.f; v[2] = 0.f; v[3] = 0.f; return v; }

// async global->LDS, 16B per lane. LDS dest must be wave-uniform base + lane*16B.
DEVI void gl16(const u16* g, u16* l) {
    __builtin_amdgcn_global_load_lds(
        (const __attribute__((address_space(1))) void*)g,
        (__attribute__((address_space(3))) void*)l, 16, 0, 0);
}

// swizzled u16 index for [R][64] bf16 tiles (128B rows): byte ^= (row&7)<<4
DEVI int swzb(int row, int col) {
    int byte = (row * 64 + col) * 2;
    byte ^= (row & 7) << 4;
    return byte >> 1;
}

// ---------------------------------------------------------------------------
// split fp32 -> 3 bf16 planes (hi/mid/lo), plane stride = n. n % 1024 == 0.
// ---------------------------------------------------------------------------
__global__ __launch_bounds__(256)
void split3_kernel(const float* __restrict__ in, u16* __restrict__ out, long long n) {
    const long long i = ((long long)blockIdx.x * 256 + threadIdx.x) * 4;
    if (i >= n) return;
    const float4 v = *(const float4*)(in + i);
    const float f[4] = {v.x, v.y, v.z, v.w};
    u16x4 ph, pm, pl;
#pragma unroll
    for (int c = 0; c < 4; ++c) {
        const u16 hi = f2b(f[c]);
        const float r1 = f[c] - b2f(hi);     // exact
        const u16 mi = f2b(r1);
        const float r2 = r1 - b2f(mi);       // exact
        const u16 lo = f2b(r2);
        ph[c] = hi; pm[c] = mi; pl[c] = lo;
    }
    *(u16x4*)(out + i) = ph;
    *(u16x4*)(out + n + i) = pm;
    *(u16x4*)(out + 2 * n + i) = pl;
}

// ---------------------------------------------------------------------------
// transpose + convert: in [Z][R][Cc] f32 -> out [Z][Cc][R] bf16
// ---------------------------------------------------------------------------
__global__ __launch_bounds__(256)
void tconv_kernel(const float* __restrict__ in, u16* __restrict__ out, int R, int Cc) {
    __shared__ float tile[32][33];
    const int z = blockIdx.z;
    const int r0 = blockIdx.y * 32, c0 = blockIdx.x * 32;
    const int tr = threadIdx.x >> 5, tc = threadIdx.x & 31;
    const float* ip = in + (size_t)z * R * Cc;
#pragma unroll
    for (int i = 0; i < 4; ++i)
        tile[tr + i * 8][tc] = ip[(size_t)(r0 + tr + i * 8) * Cc + c0 + tc];
    __syncthreads();
    u16* op = out + (size_t)z * R * Cc;
#pragma unroll
    for (int i = 0; i < 4; ++i)
        op[(size_t)(c0 + tr + i * 8) * R + r0 + tc] = f2b(tile[tc][tr + i * 8]);
}

// ---------------------------------------------------------------------------
// Unified MFMA BT-GEMM: C[M,N] = A[M,K] * Bt[N,K]^T + bias
// SPLITS=1: plain bf16.  SPLITS=3: hi/mid/lo planes, 6 products (fp32-grade).
// 128x128 tile, BK=32, 4 waves, global_load_lds staging (m97 structure).
// ---------------------------------------------------------------------------
template <int SPLITS, int RELU, int OUTF32>
__global__ __launch_bounds__(256)
void gemm_gl(const u16* __restrict__ A, const u16* __restrict__ Bt, void* __restrict__ Cout,
             const float* __restrict__ bias, int M, int N, int K,
             size_t psA, size_t psB,
             size_t sA, size_t sB, size_t sC, int sBias) {
    __shared__ u16 As[SPLITS * 128 * 32];
    __shared__ u16 Bs[SPLITS * 128 * 32];
    const int tid = threadIdx.x;
    const int lane = tid & 63, wid = tid >> 6;
    const int wm = wid >> 1, wn = wid & 1;
    const int m0 = blockIdx.y * 128, n0 = blockIdx.x * 128;
    const int e = blockIdx.z;
    const u16* Ab = A + (size_t)e * sA;
    const u16* Bb = Bt + (size_t)e * sB;
    const int lr = lane & 15, lg = lane >> 4;
    const int lrow = lane >> 2;          // 0..15
    const int lcol = (lane & 3) * 8;     // 0,8,16,24

    f32x4 acc[4][4];
#pragma unroll
    for (int i = 0; i < 4; ++i)
#pragma unroll
        for (int j = 0; j < 4; ++j) acc[i][j] = zf4();

    for (int kt = 0; kt < K; kt += 32) {
        // ---- stage: 1KB per call, 16 rows; 2 calls/wave per plane per matrix
#pragma unroll
        for (int p = 0; p < SPLITS; ++p) {
#pragma unroll
            for (int c = 0; c < 2; ++c) {
                const int r0 = wid * 32 + c * 16;
                gl16(Ab + p * psA + (size_t)(m0 + r0 + lrow) * K + kt + lcol,
                     As + p * 4096 + r0 * 32 + lane * 8);
                gl16(Bb + p * psB + (size_t)(n0 + r0 + lrow) * K + kt + lcol,
                     Bs + p * 4096 + r0 * 32 + lane * 8);
            }
        }
        __syncthreads();   // drains vmcnt -> staging visible

        short8 af[SPLITS][4];
#pragma unroll
        for (int p = 0; p < SPLITS; ++p)
#pragma unroll
            for (int i = 0; i < 4; ++i)
                af[p][i] = *(const short8*)(As + p * 4096 + (wm * 64 + i * 16 + lr) * 32 + lg * 8);

#pragma unroll
        for (int bp = 0; bp < SPLITS; ++bp) {
            short8 bf[4];
#pragma unroll
            for (int j = 0; j < 4; ++j)
                bf[j] = *(const short8*)(Bs + bp * 4096 + (wn * 64 + j * 16 + lr) * 32 + lg * 8);
#pragma unroll
            for (int ap = 0; ap + bp < SPLITS; ++ap)
#pragma unroll
                for (int i = 0; i < 4; ++i)
#pragma unroll
                    for (int j = 0; j < 4; ++j)
                        acc[i][j] = __builtin_amdgcn_mfma_f32_16x16x32_bf16(af[ap][i], bf[j], acc[i][j], 0, 0, 0);
        }
        __syncthreads();   // all reads done before next stage overwrites
    }

    const int r4 = lg * 4;
#pragma unroll
    for (int j = 0; j < 4; ++j) {
        const int col = n0 + wn * 64 + j * 16 + lr;
        const float bv = bias[(size_t)e * sBias + col];
#pragma unroll
        for (int i = 0; i < 4; ++i) {
#pragma unroll
            for (int r = 0; r < 4; ++r) {
                const int rowg = m0 + wm * 64 + i * 16 + r4 + r;
                float v = acc[i][j][r] + bv;
                if (RELU) v = fmaxf(v, 0.f);
                if (OUTF32)
                    ((float*)Cout)[(size_t)e * sC + (size_t)rowg * N + col] = v;
                else
                    ((u16*)Cout)[(size_t)e * sC + (size_t)rowg * N + col] = f2b(v);
            }
        }
    }
}

// ---------------------------------------------------------------------------
// Split-bf16 MFMA flash attention (UNCHANGED from round 3 — validated numerics)
// ---------------------------------------------------------------------------
__global__ __launch_bounds__(256)
void attn_mfma(const float* __restrict__ qkv, float* __restrict__ o) {
    __shared__ u16 Khi[64 * 64], Klo[64 * 64];
    __shared__ u16 Vhi[64 * 64], Vlo[64 * 64];   // transposed: [d][kk]
    __shared__ u16 Phi[4][16 * 64], Plo[4][16 * 64];

    const int qt = blockIdx.x, bh = blockIdx.y;
    const int bb = bh >> 4, hh = bh & 15;
    const int tid = threadIdx.x, lane = tid & 63, wid = tid >> 6;
    const int lr = lane & 15, lg = lane >> 4;

    short8 qhi[2], qlo[2];
    {
        const float* qp = qkv + ((size_t)(bb * Ss + qt * 64 + wid * 16 + lr)) * D3 + hh * HD;
#pragma unroll
        for (int ks = 0; ks < 2; ++ks) {
            const float4 f0 = *(const float4*)(qp + ks * 32 + lg * 8);
            const float4 f1 = *(const float4*)(qp + ks * 32 + lg * 8 + 4);
            const float f[8] = {f0.x, f0.y, f0.z, f0.w, f1.x, f1.y, f1.z, f1.w};
#pragma unroll
            for (int j = 0; j < 8; ++j) {
                const float fs = f[j] * 0.125f;
                const u16 h = f2b(fs);
                qhi[ks][j] = (short)h;
                qlo[ks][j] = (short)f2b(fs - b2f(h));
            }
        }
    }

    float mrun[4], lrun[4];
    f32x4 oacc[4];
#pragma unroll
    for (int r = 0; r < 4; ++r) { mrun[r] = -1e30f; lrun[r] = 0.f; }
#pragma unroll
    for (int nf = 0; nf < 4; ++nf) oacc[nf] = zf4();

    const int srow = tid >> 2;
    const int sd = (tid & 3) * 16;

    u16* const PhiW = Phi[wid];
    u16* const PloW = Plo[wid];

    for (int kt = 0; kt < Ss / 64; ++kt) {
        const float* kp = qkv + ((size_t)(bb * Ss + kt * 64 + srow)) * D3 + hh * HD + sd;
        float4 kq[4], vq[4];
#pragma unroll
        for (int q = 0; q < 4; ++q) {
            kq[q] = *(const float4*)(kp + Dd + q * 4);
            vq[q] = *(const float4*)(kp + 2 * Dd + q * 4);
        }
        __syncthreads();
        {
            const float kf[16] = {kq[0].x, kq[0].y, kq[0].z, kq[0].w, kq[1].x, kq[1].y, kq[1].z, kq[1].w,
                                  kq[2].x, kq[2].y, kq[2].z, kq[2].w, kq[3].x, kq[3].y, kq[3].z, kq[3].w};
            const float vf[16] = {vq[0].x, vq[0].y, vq[0].z, vq[0].w, vq[1].x, vq[1].y, vq[1].z, vq[1].w,
                                  vq[2].x, vq[2].y, vq[2].z, vq[2].w, vq[3].x, vq[3].y, vq[3].z, vq[3].w};
            short8 kh[2], kl[2];
#pragma unroll
            for (int half = 0; half < 2; ++half)
#pragma unroll
                for (int j = 0; j < 8; ++j) {
                    const float f = kf[half * 8 + j];
                    const u16 h = f2b(f);
                    kh[half][j] = (short)h;
                    kl[half][j] = (short)f2b(f - b2f(h));
                }
            *(short8*)(Khi + swzb(srow, sd)) = kh[0];
            *(short8*)(Khi + swzb(srow, sd + 8)) = kh[1];
            *(short8*)(Klo + swzb(srow, sd)) = kl[0];
            *(short8*)(Klo + swzb(srow, sd + 8)) = kl[1];
#pragma unroll
            for (int j = 0; j < 16; ++j) {
                const float f = vf[j];
                const u16 h = f2b(f);
                const int d = sd + j;
                Vhi[swzb(d, srow)] = h;
                Vlo[swzb(d, srow)] = f2b(f - b2f(h));
            }
        }
        __syncthreads();

        f32x4 sc[4];
#pragma unroll
        for (int nf = 0; nf < 4; ++nf) sc[nf] = zf4();
#pragma unroll
        for (int nf = 0; nf < 4; ++nf)
#pragma unroll
            for (int ks = 0; ks < 2; ++ks) {
                const short8 kh = *(const short8*)(Khi + swzb(nf * 16 + lr, ks * 32 + lg * 8));
                const short8 kl = *(const short8*)(Klo + swzb(nf * 16 + lr, ks * 32 + lg * 8));
                sc[nf] = __builtin_amdgcn_mfma_f32_16x16x32_bf16(qhi[ks], kh, sc[nf], 0, 0, 0);
                sc[nf] = __builtin_amdgcn_mfma_f32_16x16x32_bf16(qhi[ks], kl, sc[nf], 0, 0, 0);
                sc[nf] = __builtin_amdgcn_mfma_f32_16x16x32_bf16(qlo[ks], kh, sc[nf], 0, 0, 0);
                sc[nf] = __builtin_amdgcn_mfma_f32_16x16x32_bf16(qlo[ks], kl, sc[nf], 0, 0, 0);
            }

        float scl[4];
#pragma unroll
        for (int r = 0; r < 4; ++r) {
            float m = fmaxf(fmaxf(sc[0][r], sc[1][r]), fmaxf(sc[2][r], sc[3][r]));
            m = fmaxf(m, __shfl_xor(m, 1));
            m = fmaxf(m, __shfl_xor(m, 2));
            m = fmaxf(m, __shfl_xor(m, 4));
            m = fmaxf(m, __shfl_xor(m, 8));
            const float mn = fmaxf(mrun[r], m);
            scl[r] = __expf(mrun[r] - mn);
            mrun[r] = mn;
            float s = 0.f;
#pragma unroll
            for (int nf = 0; nf < 4; ++nf) {
                const float p = __expf(sc[nf][r] - mn);
                sc[nf][r] = p;
                s += p;
            }
            s += __shfl_xor(s, 1);
            s += __shfl_xor(s, 2);
            s += __shfl_xor(s, 4);
            s += __shfl_xor(s, 8);
            lrun[r] = lrun[r] * scl[r] + s;
        }

#pragma unroll
        for (int nf = 0; nf < 4; ++nf)
#pragma unroll
            for (int r = 0; r < 4; ++r) {
                const float p = sc[nf][r];
                const u16 h = f2b(p);
                const int idx = swzb(lg * 4 + r, nf * 16 + lr);
                PhiW[idx] = h;
                PloW[idx] = f2b(p - b2f(h));
            }

#pragma unroll
        for (int nf = 0; nf < 4; ++nf)
#pragma unroll
            for (int r = 0; r < 4; ++r) oacc[nf][r] *= scl[r];

#pragma unroll
        for (int ks = 0; ks < 2; ++ks) {
            const short8 ph = *(const short8*)(PhiW + swzb(lr, ks * 32 + lg * 8));
            const short8 pl = *(const short8*)(PloW + swzb(lr, ks * 32 + lg * 8));
#pragma unroll
            for (int nf = 0; nf < 4; ++nf) {
                const short8 vh = *(const short8*)(Vhi + swzb(nf * 16 + lr, ks * 32 + lg * 8));
                const short8 vl = *(const short8*)(Vlo + swzb(nf * 16 + lr, ks * 32 + lg * 8));
                oacc[nf] = __builtin_amdgcn_mfma_f32_16x16x32_bf16(ph, vh, oacc[nf], 0, 0, 0);
                oacc[nf] = __builtin_amdgcn_mfma_f32_16x16x32_bf16(ph, vl, oacc[nf], 0, 0, 0);
                oacc[nf] = __builtin_amdgcn_mfma_f32_16x16x32_bf16(pl, vh, oacc[nf], 0, 0, 0);
                oacc[nf] = __builtin_amdgcn_mfma_f32_16x16x32_bf16(pl, vl, oacc[nf], 0, 0, 0);
            }
        }
    }

#pragma unroll
    for (int r = 0; r < 4; ++r) {
        const float inv = 1.f / lrun[r];
        float* op = o + ((size_t)(bb * Ss + qt * 64 + wid * 16 + lg * 4 + r)) * Dd + hh * HD;
#pragma unroll
        for (int nf = 0; nf < 4; ++nf)
            op[nf * 16 + lr] = oacc[nf][r] * inv;
    }
}

// ---------------------------------------------------------------------------
DEVI double block_reduce_d(double v, double* sred, int tid) {
#pragma unroll
    for (int off = 32; off > 0; off >>= 1) v += __shfl_down(v, off);
    __syncthreads();
    if ((tid & 63) == 0) sred[tid >> 6] = v;
    __syncthreads();
    return sred[0] + sred[1] + sred[2] + sred[3];
}

// ---------------------------------------------------------------------------
// LN1: x1f = LN(x + aproj)
// ---------------------------------------------------------------------------
__global__ __launch_bounds__(256)
void ln1_kernel(const float* __restrict__ x, const float* __restrict__ ap,
                const float* __restrict__ g, const float* __restrict__ b,
                float* __restrict__ x1f) {
    __shared__ double sred[4];
    const int t = blockIdx.x, tid = threadIdx.x;
    const float4 xv = ((const float4*)(x + (size_t)t * Dd))[tid];
    const float4 av = ((const float4*)(ap + (size_t)t * Dd))[tid];
    const double v0 = (double)xv.x + (double)av.x;
    const double v1 = (double)xv.y + (double)av.y;
    const double v2 = (double)xv.z + (double)av.z;
    const double v3 = (double)xv.w + (double)av.w;
    const double s = block_reduce_d(v0 + v1 + v2 + v3, sred, tid);
    const double mean = s * (1.0 / Dd);
    const double c0 = v0 - mean, c1 = v1 - mean, c2 = v2 - mean, c3 = v3 - mean;
    const double s2 = block_reduce_d(c0 * c0 + c1 * c1 + c2 * c2 + c3 * c3, sred, tid);
    const double rstd = 1.0 / sqrt(s2 * (1.0 / Dd) + 1e-5);
    const float4 gv = ((const float4*)g)[tid];
    const float4 bv = ((const float4*)b)[tid];
    float4 ov;
    ov.x = (float)(c0 * rstd * (double)gv.x + (double)bv.x);
    ov.y = (float)(c1 * rstd * (double)gv.y + (double)bv.y);
    ov.z = (float)(c2 * rstd * (double)gv.z + (double)bv.z);
    ov.w = (float)(c3 * rstd * (double)gv.w + (double)bv.w);
    ((float4*)(x1f + (size_t)t * Dd))[tid] = ov;
}

// ---------------------------------------------------------------------------
// gating stage 1 (fp64)
// ---------------------------------------------------------------------------
__global__ __launch_bounds__(256)
void gate1_kernel(const float* __restrict__ x1f, const float* __restrict__ wg,
                  int* __restrict__ idx1, int* __restrict__ idx2,
                  float* __restrict__ gate1, float* __restrict__ gate2) {
    const int tid = threadIdx.x, lane = tid & 63, wid = tid >> 6;
    const int t = blockIdx.x * 4 + wid;
    double acc[16];
#pragma unroll
    for (int e = 0; e < 16; ++e) acc[e] = 0.0;
    for (int i = 0; i < 16; ++i) {
        const int d = i * 64 + lane;
        const double xv = (double)x1f[(size_t)t * Dd + d];
        const float4* wr = (const float4*)(wg + (size_t)d * 16);
        const float4 w0 = wr[0], w1 = wr[1], w2 = wr[2], w3 = wr[3];
        acc[0] += xv * (double)w0.x;  acc[1] += xv * (double)w0.y;
        acc[2] += xv * (double)w0.z;  acc[3] += xv * (double)w0.w;
        acc[4] += xv * (double)w1.x;  acc[5] += xv * (double)w1.y;
        acc[6] += xv * (double)w1.z;  acc[7] += xv * (double)w1.w;
        acc[8] += xv * (double)w2.x;  acc[9] += xv * (double)w2.y;
        acc[10] += xv * (double)w2.z; acc[11] += xv * (double)w2.w;
        acc[12] += xv * (double)w3.x; acc[13] += xv * (double)w3.y;
        acc[14] += xv * (double)w3.z; acc[15] += xv * (double)w3.w;
    }
#pragma unroll
    for (int e = 0; e < 16; ++e) {
        acc[e] += __shfl_xor(acc[e], 1);
        acc[e] += __shfl_xor(acc[e], 2);
        acc[e] += __shfl_xor(acc[e], 4);
        acc[e] += __shfl_xor(acc[e], 8);
        acc[e] += __shfl_xor(acc[e], 16);
        acc[e] += __shfl_xor(acc[e], 32);
    }
    if (lane == 0) {
        double mx = acc[0];
#pragma unroll
        for (int e = 1; e < 16; ++e) mx = fmax(mx, acc[e]);
        double z = 0.0, ex[16];
#pragma unroll
        for (int e = 0; e < 16; ++e) { ex[e] = exp(acc[e] - mx); z += ex[e]; }
        int b1 = 0; double v1 = acc[0];
#pragma unroll
        for (int e = 1; e < 16; ++e) if (acc[e] > v1) { v1 = acc[e]; b1 = e; }
        int b2 = (b1 == 0) ? 1 : 0; double v2 = acc[b2];
#pragma unroll
        for (int e = 0; e < 16; ++e) if (e != b1 && acc[e] > v2) { v2 = acc[e]; b2 = e; }
        const double rz = 1.0 / z;
        idx1[t] = b1; idx2[t] = b2;
        gate1[t] = (float)(ex[b1] * rz); gate2[t] = (float)(ex[b2] * rz);
    }
}

// ---------------------------------------------------------------------------
// gating stage 2 (single block)
// ---------------------------------------------------------------------------
__global__ __launch_bounds__(256)
void gate2_kernel(const int* __restrict__ idx1, const int* __restrict__ idx2,
                  const float* __restrict__ gate1, const float* __restrict__ gate2,
                  int* __restrict__ p1, int* __restrict__ p2,
                  int* __restrict__ k1, int* __restrict__ k2,
                  float* __restrict__ w1, float* __restrict__ w2) {
    __shared__ int hist[16];
    __shared__ unsigned long long sb1[4][16], sb2[4][16];
    __shared__ int sbase1[16], sbase2[16];
    const int tid = threadIdx.x, lane = tid & 63, wid = tid >> 6;
    if (tid < 16) hist[tid] = 0;
    __syncthreads();
    for (int t = tid; t < Tt; t += 256) atomicAdd(&hist[idx1[t]], 1);
    __syncthreads();
    if (tid < 16) { sbase1[tid] = 0; sbase2[tid] = hist[tid]; }
    __syncthreads();
    const unsigned long long below = (1ULL << lane) - 1ULL;
    for (int ch = 0; ch < Tt / 256; ++ch) {
        const int t = ch * 256 + tid;
        const int a = idx1[t], b = idx2[t];
#pragma unroll
        for (int e = 0; e < 16; ++e) {
            const unsigned long long m1 = __ballot(a == e);
            const unsigned long long m2 = __ballot(b == e);
            if (lane == 0) { sb1[wid][e] = m1; sb2[wid][e] = m2; }
        }
        __syncthreads();
        int r1 = __popcll(sb1[wid][a] & below);
        int r2 = __popcll(sb2[wid][b] & below);
#pragma unroll
        for (int w = 0; w < 4; ++w)
            if (w < wid) { r1 += __popcll(sb1[w][a]); r2 += __popcll(sb2[w][b]); }
        const int loc1 = sbase1[a] + r1, loc2 = sbase2[b] + r2;
        const int kk1 = loc1 < Cap, kk2 = loc2 < Cap;
        const float g1 = kk1 ? gate1[t] : 0.f;
        const float g2 = kk2 ? gate2[t] : 0.f;
        const float dn = fmaxf(g1 + g2, EPSc);
        p1[t] = kk1 ? loc1 : 0;
        p2[t] = kk2 ? loc2 : 0;
        k1[t] = kk1; k2[t] = kk2;
        w1[t] = g1 / dn; w2[t] = g2 / dn;
        __syncthreads();
        if (tid == 0) {
#pragma unroll
            for (int e = 0; e < 16; ++e) {
                int c1 = 0, c2 = 0;
#pragma unroll
                for (int w = 0; w < 4; ++w) { c1 += __popcll(sb1[w][e]); c2 += __popcll(sb2[w][e]); }
                sbase1[e] += c1; sbase2[e] += c2;
            }
        }
        __syncthreads();
    }
}

// ---------------------------------------------------------------------------
// dispatch: scatter kept tokens (f32 -> bf16) into [E,C,D] buffers (pre-zeroed)
// ---------------------------------------------------------------------------
__global__ __launch_bounds__(256)
void dispatch_kernel(const float* __restrict__ x1f,
                     const int* __restrict__ i1, const int* __restrict__ p1, const int* __restrict__ k1,
                     const int* __restrict__ i2, const int* __restrict__ p2, const int* __restrict__ k2,
                     u16* __restrict__ buf) {
    const int t = blockIdx.x, tid = threadIdx.x;
    const float4 v = ((const float4*)(x1f + (size_t)t * Dd))[tid];
    u16x4 pw;
    pw[0] = f2b(v.x); pw[1] = f2b(v.y); pw[2] = f2b(v.z); pw[3] = f2b(v.w);
    if (k1[t]) *(u16x4*)(buf + ((size_t)i1[t] * Cap + p1[t]) * Dd + tid * 4) = pw;
    if (k2[t]) *(u16x4*)(buf + ((size_t)i2[t] * Cap + p2[t]) * Dd + tid * 4) = pw;
}

// ---------------------------------------------------------------------------
// combine + residual + LN2 -> d_out (f32)
// ---------------------------------------------------------------------------
__global__ __launch_bounds__(256)
void combine_ln2(const float* __restrict__ x1f, const u16* __restrict__ y,
                 const int* __restrict__ i1, const int* __restrict__ p1, const float* __restrict__ w1,
                 const int* __restrict__ i2, const int* __restrict__ p2, const float* __restrict__ w2,
                 const float* __restrict__ g, const float* __restrict__ b,
                 float* __restrict__ out) {
    __shared__ double sred[4];
    const int t = blockIdx.x, tid = threadIdx.x;
    const size_t r1 = ((size_t)i1[t] * Cap + p1[t]) * Dd;
    const size_t r2 = ((size_t)i2[t] * Cap + p2[t]) * Dd;
    const double a1 = (double)w1[t], a2 = (double)w2[t];
    const u16x4 y1 = *(const u16x4*)(y + r1 + tid * 4);
    const u16x4 y2 = *(const u16x4*)(y + r2 + tid * 4);
    const float4 xv = ((const float4*)(x1f + (size_t)t * Dd))[tid];
    const double v0 = (double)xv.x + a1 * (double)b2f(y1[0]) + a2 * (double)b2f(y2[0]);
    const double v1 = (double)xv.y + a1 * (double)b2f(y1[1]) + a2 * (double)b2f(y2[1]);
    const double v2 = (double)xv.z + a1 * (double)b2f(y1[2]) + a2 * (double)b2f(y2[2]);
    const double v3 = (double)xv.w + a1 * (double)b2f(y1[3]) + a2 * (double)b2f(y2[3]);
    const double s = block_reduce_d(v0 + v1 + v2 + v3, sred, tid);
    const double mean = s * (1.0 / Dd);
    const double c0 = v0 - mean, c1 = v1 - mean, c2 = v2 - mean, c3 = v3 - mean;
    const double s2 = block_reduce_d(c0 * c0 + c1 * c1 + c2 * c2 + c3 * c3, sred, tid);
    const double rstd = 1.0 / sqrt(s2 * (1.0 / Dd) + 1e-5);
    const float4 gv = ((const float4*)g)[tid];
    const float4 bv = ((const float4*)b)[tid];
    float4 ov;
    ov.x = (float)(c0 * rstd * (double)gv.x + (double)bv.x);
    ov.y = (float)(c1 * rstd * (double)gv.y + (double)bv.y);
    ov.z = (float)(c2 * rstd * (double)gv.z + (double)bv.z);
    ov.w = (float)(c3 * rstd * (double)gv.w + (double)bv.w);
    ((float4*)(out + (size_t)t * Dd))[tid] = ov;
}

// ---------------------------------------------------------------------------
extern "C" void kernel_launch(void* const* d_in, const int* in_sizes, int n_in,
                              void* d_out, int out_size, void* d_ws, size_t ws_size,
                              hipStream_t stream) {
    (void)in_sizes; (void)n_in; (void)out_size; (void)ws_size;
    const float* x    = (const float*)d_in[0];
    const float* inW  = (const float*)d_in[1];
    const float* inB  = (const float*)d_in[2];
    const float* outW = (const float*)d_in[3];
    const float* outB = (const float*)d_in[4];
    const float* ln1g = (const float*)d_in[5];
    const float* ln1b = (const float*)d_in[6];
    const float* ln2g = (const float*)d_in[7];
    const float* ln2b = (const float*)d_in[8];
    const float* wg   = (const float*)d_in[9];
    const float* w1   = (const float*)d_in[10];
    const float* b1   = (const float*)d_in[11];
    const float* w2   = (const float*)d_in[12];
    const float* b2   = (const float*)d_in[13];
    float* out = (float*)d_out;

    char* ws = (char*)d_ws;
    const size_t MB = 1024 * 1024;
    // --- hand-laid arena (peak ~370 MB, overlap-checked by phase) ---
    const size_t szTD4  = (size_t)Tt * Dd * 4;        // 33.6 MB
    const size_t szTD3  = (size_t)Tt * D3 * 4;        // 100.7 MB
    float* qkv32 = (float*)(ws + 0);                              // [0,100.7)
    u16*   xs3   = (u16*)(ws + szTD3);                            // [100.7,151.0)
    u16*   inW3  = (u16*)(ws + szTD3 + 3 * (size_t)Tt * Dd * 2);  // [151.0,169.9)
    float* o32   = (float*)(ws + szTD3);                          // [100.7,134.3) over xs3
    u16*   os3   = (u16*)(ws + 202 * MB);                         // [202,252.3)
    u16*   outW3 = (u16*)(ws + 253 * MB);                         // [253,259.3)
    float* aproj = (float*)(ws + szTD4);                          // [33.6,67.2) over qkv32
    float* x1f   = (float*)(ws + 0);                              // [0,33.6) over qkv32
    u16*   ebuf  = (u16*)(ws + szTD4);                            // [33.6,67.2) over aproj
    u16*   wt    = (u16*)(ws + 68 * MB);                          // [68,202.2) dead zones
    u16*   hbuf  = (u16*)(ws + 203 * MB);                         // [203,337.2) over os3/outW3
    u16*   ybuf  = (u16*)(ws + 338 * MB);                         // [338,371.6)
    char*  gbase = ws + 372 * MB;
    int*   idx1 = (int*)(gbase + 0 * Tt * 4);
    int*   idx2 = (int*)(gbase + 1 * Tt * 4);
    float* gt1  = (float*)(gbase + 2 * Tt * 4);
    float* gt2  = (float*)(gbase + 3 * Tt * 4);
    int*   p1   = (int*)(gbase + 4 * Tt * 4);
    int*   p2   = (int*)(gbase + 5 * Tt * 4);
    int*   k1   = (int*)(gbase + 6 * Tt * 4);
    int*   k2   = (int*)(gbase + 7 * Tt * 4);
    float* w1c  = (float*)(gbase + 8 * Tt * 4);
    float* w2c  = (float*)(gbase + 9 * Tt * 4);

    const long long nTD = (long long)Tt * Dd;
    const long long nW1 = (long long)D3 * Dd;
    const long long nW2 = (long long)Dd * Dd;

    // 1: split x, inW -> 3 bf16 planes; QKV = split3 GEMM (fp32-grade)
    split3_kernel<<<(int)(nTD / 1024), 256, 0, stream>>>(x, xs3, nTD);
    split3_kernel<<<(int)(nW1 / 1024), 256, 0, stream>>>(inW, inW3, nW1);
    gemm_gl<3, 0, 1><<<dim3(D3 / 128, Tt / 128, 1), 256, 0, stream>>>(
        xs3, inW3, qkv32, inB, Tt, D3, Dd, (size_t)nTD, (size_t)nW1, 0, 0, 0, 0);
    // 2: attention (split-bf16 MFMA, validated)
    attn_mfma<<<dim3(Ss / 64, Bz * Hh), 256, 0, stream>>>(qkv32, o32);
    // 3: out-proj = split3 GEMM
    split3_kernel<<<(int)(nTD / 1024), 256, 0, stream>>>(o32, os3, nTD);
    split3_kernel<<<(int)(nW2 / 1024), 256, 0, stream>>>(outW, outW3, nW2);
    gemm_gl<3, 0, 1><<<dim3(Dd / 128, Tt / 128, 1), 256, 0, stream>>>(
        os3, outW3, aproj, outB, Tt, Dd, Dd, (size_t)nTD, (size_t)nW2, 0, 0, 0, 0);
    // 4: LN1
    ln1_kernel<<<Tt, 256, 0, stream>>>(x, aproj, ln1g, ln1b, x1f);
    // 5-6: gating
    gate1_kernel<<<Tt / 4, 256, 0, stream>>>(x1f, wg, idx1, idx2, gt1, gt2);
    gate2_kernel<<<1, 256, 0, stream>>>(idx1, idx2, gt1, gt2, p1, p2, k1, k2, w1c, w2c);
    // 7: dispatch
    hipMemsetAsync(ebuf, 0, (size_t)Ee * Cap * Dd * 2, stream);
    dispatch_kernel<<<Tt, 256, 0, stream>>>(x1f, idx1, p1, k1, idx2, p2, k2, ebuf);
    // 8-11: expert FFN (plain bf16 MFMA, global_load_lds staging)
    tconv_kernel<<<dim3(DFF / 32, Dd / 32, Ee), 256, 0, stream>>>(w1, wt, Dd, DFF);
    gemm_gl<1, 1, 0><<<dim3(DFF / 128, Cap / 128, Ee), 256, 0, stream>>>(
        ebuf, wt, hbuf, b1, Cap, DFF, Dd, 0, 0,
        (size_t)Cap * Dd, (size_t)DFF * Dd, (size_t)Cap * DFF, DFF);
    tconv_kernel<<<dim3(Dd / 32, DFF / 32, Ee), 256, 0, stream>>>(w2, wt, DFF, Dd);
    gemm_gl<1, 0, 0><<<dim3(Dd / 128, Cap / 128, Ee), 256, 0, stream>>>(
        hbuf, wt, ybuf, b2, Cap, Dd, DFF, 0, 0,
        (size_t)Cap * DFF, (size_t)Dd * DFF, (size_t)Cap * Dd, Dd);
    // 12: combine + residual + LN2
    combine_ln2<<<Tt, 256, 0, stream>>>(x1f, ybuf, idx1, p1, w1c, idx2, p2, w2c, ln2g, ln2b, out);
}

// Round 6
// 1461.490 us; speedup vs baseline: 2.0271x; 1.0138x over previous
//
#include <hip/hip_runtime.h>
#include <cstdint>

#define DEVI __device__ __forceinline__

typedef short short8 __attribute__((ext_vector_type(8)));
typedef float f32x4 __attribute__((ext_vector_type(4)));
typedef unsigned short u16;
typedef u16 u16x4 __attribute__((ext_vector_type(4)));

static constexpr int Bz = 8, Ss = 1024, Dd = 1024, Hh = 16, HD = 64, DFF = 4096, Ee = 16;
static constexpr int Tt = Bz * Ss;           // 8192 tokens
static constexpr int Cap = (2 * Tt) / Ee;    // 1024 capacity
static constexpr int D3 = 3 * Dd;            // 3072
static constexpr float EPSc = 1.1920929e-07f;
static constexpr size_t PT = (size_t)Tt * Dd;   // plane elements (token-major)

DEVI u16 f2b(float f) {
    union { float f; uint32_t u; } v; v.f = f;
    return (u16)((v.u + 0x7FFFu + ((v.u >> 16) & 1u)) >> 16);
}
DEVI float b2f(u16 h) {
    union { uint32_t u; float f; } v; v.u = ((uint32_t)h) << 16; return v.f;
}
DEVI f32x4 zf4() { f32x4 v; v[0] = 0.f; v[1] = 0.f; v[2] = 0.f; v[3] = 0.f; return v; }

// async global->LDS, 16B per lane. LDS dest must be wave-uniform base + lane*16B.
DEVI void gl16(const u16* g, u16* l) {
    __builtin_amdgcn_global_load_lds(
        (const __attribute__((address_space(1))) void*)g,
        (__attribute__((address_space(3))) void*)l, 16, 0, 0);
}

// swizzled u16 index for [R][64] bf16 tiles (128B rows): byte ^= (row&7)<<4
DEVI int swzb(int row, int col) {
    int byte = (row * 64 + col) * 2;
    byte ^= (row & 7) << 4;
    return byte >> 1;
}

// ---------------------------------------------------------------------------
// split fp32 -> 3 bf16 planes (hi/mid/lo), plane stride = n. n % 1024 == 0.
// ---------------------------------------------------------------------------
__global__ __launch_bounds__(256)
void split3_kernel(const float* __restrict__ in, u16* __restrict__ out, long long n) {
    const long long i = ((long long)blockIdx.x * 256 + threadIdx.x) * 4;
    if (i >= n) return;
    const float4 v = *(const float4*)(in + i);
    const float f[4] = {v.x, v.y, v.z, v.w};
    u16x4 ph, pm, pl;
#pragma unroll
    for (int c = 0; c < 4; ++c) {
        const u16 hi = f2b(f[c]);
        const float r1 = f[c] - b2f(hi);     // exact
        const u16 mi = f2b(r1);
        const float r2 = r1 - b2f(mi);       // exact
        const u16 lo = f2b(r2);
        ph[c] = hi; pm[c] = mi; pl[c] = lo;
    }
    *(u16x4*)(out + i) = ph;
    *(u16x4*)(out + n + i) = pm;
    *(u16x4*)(out + 2 * n + i) = pl;
}

// ---------------------------------------------------------------------------
// transpose + convert: in [Z][R][Cc] f32 -> out [Z][Cc][R] bf16
// ---------------------------------------------------------------------------
__global__ __launch_bounds__(256)
void tconv_kernel(const float* __restrict__ in, u16* __restrict__ out, int R, int Cc) {
    __shared__ float tile[32][33];
    const int z = blockIdx.z;
    const int r0 = blockIdx.y * 32, c0 = blockIdx.x * 32;
    const int tr = threadIdx.x >> 5, tc = threadIdx.x & 31;
    const float* ip = in + (size_t)z * R * Cc;
#pragma unroll
    for (int i = 0; i < 4; ++i)
        tile[tr + i * 8][tc] = ip[(size_t)(r0 + tr + i * 8) * Cc + c0 + tc];
    __syncthreads();
    u16* op = out + (size_t)z * R * Cc;
#pragma unroll
    for (int i = 0; i < 4; ++i)
        op[(size_t)(c0 + tr + i * 8) * R + r0 + tc] = f2b(tile[tc][tr + i * 8]);
}

// ---------------------------------------------------------------------------
// V-plane transpose: vh/vl [Tt][Dd] (per bh: [s][64]) -> vth/vtl [bh][64][Ss]
// ---------------------------------------------------------------------------
__global__ __launch_bounds__(256)
void vtrans_kernel(const u16* __restrict__ vh, const u16* __restrict__ vl,
                   u16* __restrict__ vth, u16* __restrict__ vtl) {
    __shared__ u16 th[32][33], tl[32][33];
    const int bh = blockIdx.z, d0 = blockIdx.y * 32, s0 = blockIdx.x * 32;
    const int bb = bh >> 4, hh = bh & 15;
    const int tr = threadIdx.x >> 5, tc = threadIdx.x & 31;
#pragma unroll
    for (int i = 0; i < 4; ++i) {
        const size_t src = (size_t)(bb * Ss + s0 + tr + i * 8) * Dd + hh * HD + d0 + tc;
        th[tr + i * 8][tc] = vh[src];
        tl[tr + i * 8][tc] = vl[src];
    }
    __syncthreads();
#pragma unroll
    for (int i = 0; i < 4; ++i) {
        const size_t dst = ((size_t)bh * HD + d0 + tr + i * 8) * Ss + s0 + tc;
        vth[dst] = th[tc][tr + i * 8];
        vtl[dst] = tl[tc][tr + i * 8];
    }
}

// ---------------------------------------------------------------------------
// Unified MFMA BT-GEMM: C[M,N] = A[M,K] * Bt[N,K]^T + bias
// SPLITS=1 plain bf16; SPLITS=3 hi/mid/lo planes, 6 products (fp32-grade).
// MODE: 0 bf16 out, 1 bf16+relu, 2 f32 out, 3 QKV split-plane out.
// 128x128 tile, BK=32, 4 waves, global_load_lds staging.
// ---------------------------------------------------------------------------
template <int SPLITS, int MODE>
__global__ __launch_bounds__(256)
void gemm_gl(const u16* __restrict__ A, const u16* __restrict__ Bt, void* __restrict__ Cout,
             const float* __restrict__ bias, int M, int N, int K,
             size_t psA, size_t psB,
             size_t sA, size_t sB, size_t sC, int sBias,
             u16* __restrict__ qh, u16* __restrict__ ql,
             u16* __restrict__ kh, u16* __restrict__ kl,
             u16* __restrict__ vh, u16* __restrict__ vl) {
    __shared__ u16 As[SPLITS * 128 * 32];
    __shared__ u16 Bs[SPLITS * 128 * 32];
    const int tid = threadIdx.x;
    const int lane = tid & 63, wid = tid >> 6;
    const int wm = wid >> 1, wn = wid & 1;
    const int m0 = blockIdx.y * 128, n0 = blockIdx.x * 128;
    const int e = blockIdx.z;
    const u16* Ab = A + (size_t)e * sA;
    const u16* Bb = Bt + (size_t)e * sB;
    const int lr = lane & 15, lg = lane >> 4;
    const int lrow = lane >> 2;          // 0..15
    const int lcol = (lane & 3) * 8;     // 0,8,16,24

    f32x4 acc[4][4];
#pragma unroll
    for (int i = 0; i < 4; ++i)
#pragma unroll
        for (int j = 0; j < 4; ++j) acc[i][j] = zf4();

    for (int kt = 0; kt < K; kt += 32) {
#pragma unroll
        for (int p = 0; p < SPLITS; ++p) {
#pragma unroll
            for (int c = 0; c < 2; ++c) {
                const int r0 = wid * 32 + c * 16;
                gl16(Ab + p * psA + (size_t)(m0 + r0 + lrow) * K + kt + lcol,
                     As + p * 4096 + r0 * 32 + lane * 8);
                gl16(Bb + p * psB + (size_t)(n0 + r0 + lrow) * K + kt + lcol,
                     Bs + p * 4096 + r0 * 32 + lane * 8);
            }
        }
        __syncthreads();

        short8 af[SPLITS][4];
#pragma unroll
        for (int p = 0; p < SPLITS; ++p)
#pragma unroll
            for (int i = 0; i < 4; ++i)
                af[p][i] = *(const short8*)(As + p * 4096 + (wm * 64 + i * 16 + lr) * 32 + lg * 8);

#pragma unroll
        for (int bp = 0; bp < SPLITS; ++bp) {
            short8 bf[4];
#pragma unroll
            for (int j = 0; j < 4; ++j)
                bf[j] = *(const short8*)(Bs + bp * 4096 + (wn * 64 + j * 16 + lr) * 32 + lg * 8);
#pragma unroll
            for (int ap = 0; ap + bp < SPLITS; ++ap)
#pragma unroll
                for (int i = 0; i < 4; ++i)
#pragma unroll
                    for (int j = 0; j < 4; ++j)
                        acc[i][j] = __builtin_amdgcn_mfma_f32_16x16x32_bf16(af[ap][i], bf[j], acc[i][j], 0, 0, 0);
        }
        __syncthreads();
    }

    const int r4 = lg * 4;
    const int region = n0 >> 10;   // MODE 3: 0=Q,1=K,2=V (uniform per block)
#pragma unroll
    for (int j = 0; j < 4; ++j) {
        const int col = n0 + wn * 64 + j * 16 + lr;
        const float bv = bias[(size_t)e * sBias + col];
#pragma unroll
        for (int i = 0; i < 4; ++i) {
#pragma unroll
            for (int r = 0; r < 4; ++r) {
                const int rowg = m0 + wm * 64 + i * 16 + r4 + r;
                float v = acc[i][j][r] + bv;
                if (MODE == 1) v = fmaxf(v, 0.f);
                if (MODE == 2) {
                    ((float*)Cout)[(size_t)e * sC + (size_t)rowg * N + col] = v;
                } else if (MODE == 3) {
                    const size_t off = (size_t)rowg * Dd + (col & 1023);
                    if (region == 0) {
                        const float fs = v * 0.125f;
                        const u16 h = f2b(fs);
                        qh[off] = h; ql[off] = f2b(fs - b2f(h));
                    } else if (region == 1) {
                        const u16 h = f2b(v);
                        kh[off] = h; kl[off] = f2b(v - b2f(h));
                    } else {
                        const u16 h = f2b(v);
                        vh[off] = h; vl[off] = f2b(v - b2f(h));
                    }
                } else {
                    ((u16*)Cout)[(size_t)e * sC + (size_t)rowg * N + col] = f2b(v);
                }
            }
        }
    }
}

// ---------------------------------------------------------------------------
// Split-bf16 MFMA flash attention v2: pre-split bf16 planes in, os3 planes out.
// MFMA/softmax sequence bit-identical to round-3/4 kernel.
// ---------------------------------------------------------------------------
__global__ __launch_bounds__(256)
void attn_mfma(const u16* __restrict__ qhp, const u16* __restrict__ qlp,
               const u16* __restrict__ khp, const u16* __restrict__ klp,
               const u16* __restrict__ vthp, const u16* __restrict__ vtlp,
               u16* __restrict__ os) {
    __shared__ u16 Khi[64 * 64], Klo[64 * 64];
    __shared__ u16 Vhi[64 * 64], Vlo[64 * 64];   // [d][kk]
    __shared__ u16 Phi[4][16 * 64], Plo[4][16 * 64];

    const int qt = blockIdx.x, bh = blockIdx.y;
    const int bb = bh >> 4, hh = bh & 15;
    const int tid = threadIdx.x, lane = tid & 63, wid = tid >> 6;
    const int lr = lane & 15, lg = lane >> 4;

    short8 qhi[2], qlo[2];
    {
        const size_t qbase = (size_t)(bb * Ss + qt * 64 + wid * 16 + lr) * Dd + hh * HD;
#pragma unroll
        for (int ks = 0; ks < 2; ++ks) {
            qhi[ks] = *(const short8*)(qhp + qbase + ks * 32 + lg * 8);
            qlo[ks] = *(const short8*)(qlp + qbase + ks * 32 + lg * 8);
        }
    }

    float mrun[4], lrun[4];
    f32x4 oacc[4];
#pragma unroll
    for (int r = 0; r < 4; ++r) { mrun[r] = -1e30f; lrun[r] = 0.f; }
#pragma unroll
    for (int nf = 0; nf < 4; ++nf) oacc[nf] = zf4();

    const int srow = tid >> 2;        // 0..63
    const int sd = (tid & 3) * 16;    // 0,16,32,48

    u16* const PhiW = Phi[wid];
    u16* const PloW = Plo[wid];

    for (int kt = 0; kt < Ss / 64; ++kt) {
        // ---- load K/Vt tiles (bf16, no split math) ----
        const size_t krow = (size_t)(bb * Ss + kt * 64 + srow) * Dd + hh * HD + sd;
        const short8 k0 = *(const short8*)(khp + krow);
        const short8 k1 = *(const short8*)(khp + krow + 8);
        const short8 l0 = *(const short8*)(klp + krow);
        const short8 l1 = *(const short8*)(klp + krow + 8);
        const size_t vrow = ((size_t)bh * HD + srow) * Ss + kt * 64 + sd;
        const short8 v0 = *(const short8*)(vthp + vrow);
        const short8 v1 = *(const short8*)(vthp + vrow + 8);
        const short8 w0 = *(const short8*)(vtlp + vrow);
        const short8 w1 = *(const short8*)(vtlp + vrow + 8);
        __syncthreads();
        *(short8*)(Khi + swzb(srow, sd)) = k0;
        *(short8*)(Khi + swzb(srow, sd + 8)) = k1;
        *(short8*)(Klo + swzb(srow, sd)) = l0;
        *(short8*)(Klo + swzb(srow, sd + 8)) = l1;
        *(short8*)(Vhi + swzb(srow, sd)) = v0;
        *(short8*)(Vhi + swzb(srow, sd + 8)) = v1;
        *(short8*)(Vlo + swzb(srow, sd)) = w0;
        *(short8*)(Vlo + swzb(srow, sd + 8)) = w1;
        __syncthreads();

        f32x4 sc[4];
#pragma unroll
        for (int nf = 0; nf < 4; ++nf) sc[nf] = zf4();
#pragma unroll
        for (int nf = 0; nf < 4; ++nf)
#pragma unroll
            for (int ks = 0; ks < 2; ++ks) {
                const short8 kh = *(const short8*)(Khi + swzb(nf * 16 + lr, ks * 32 + lg * 8));
                const short8 kl = *(const short8*)(Klo + swzb(nf * 16 + lr, ks * 32 + lg * 8));
                sc[nf] = __builtin_amdgcn_mfma_f32_16x16x32_bf16(qhi[ks], kh, sc[nf], 0, 0, 0);
                sc[nf] = __builtin_amdgcn_mfma_f32_16x16x32_bf16(qhi[ks], kl, sc[nf], 0, 0, 0);
                sc[nf] = __builtin_amdgcn_mfma_f32_16x16x32_bf16(qlo[ks], kh, sc[nf], 0, 0, 0);
                sc[nf] = __builtin_amdgcn_mfma_f32_16x16x32_bf16(qlo[ks], kl, sc[nf], 0, 0, 0);
            }

        float scl[4];
#pragma unroll
        for (int r = 0; r < 4; ++r) {
            float m = fmaxf(fmaxf(sc[0][r], sc[1][r]), fmaxf(sc[2][r], sc[3][r]));
            m = fmaxf(m, __shfl_xor(m, 1));
            m = fmaxf(m, __shfl_xor(m, 2));
            m = fmaxf(m, __shfl_xor(m, 4));
            m = fmaxf(m, __shfl_xor(m, 8));
            const float mn = fmaxf(mrun[r], m);
            scl[r] = __expf(mrun[r] - mn);
            mrun[r] = mn;
            float s = 0.f;
#pragma unroll
            for (int nf = 0; nf < 4; ++nf) {
                const float p = __expf(sc[nf][r] - mn);
                sc[nf][r] = p;
                s += p;
            }
            s += __shfl_xor(s, 1);
            s += __shfl_xor(s, 2);
            s += __shfl_xor(s, 4);
            s += __shfl_xor(s, 8);
            lrun[r] = lrun[r] * scl[r] + s;
        }

#pragma unroll
        for (int nf = 0; nf < 4; ++nf)
#pragma unroll
            for (int r = 0; r < 4; ++r) {
                const float p = sc[nf][r];
                const u16 h = f2b(p);
                const int idx = swzb(lg * 4 + r, nf * 16 + lr);
                PhiW[idx] = h;
                PloW[idx] = f2b(p - b2f(h));
            }

#pragma unroll
        for (int nf = 0; nf < 4; ++nf)
#pragma unroll
            for (int r = 0; r < 4; ++r) oacc[nf][r] *= scl[r];

#pragma unroll
        for (int ks = 0; ks < 2; ++ks) {
            const short8 ph = *(const short8*)(PhiW + swzb(lr, ks * 32 + lg * 8));
            const short8 pl = *(const short8*)(PloW + swzb(lr, ks * 32 + lg * 8));
#pragma unroll
            for (int nf = 0; nf < 4; ++nf) {
                const short8 vh = *(const short8*)(Vhi + swzb(nf * 16 + lr, ks * 32 + lg * 8));
                const short8 vl = *(const short8*)(Vlo + swzb(nf * 16 + lr, ks * 32 + lg * 8));
                oacc[nf] = __builtin_amdgcn_mfma_f32_16x16x32_bf16(ph, vh, oacc[nf], 0, 0, 0);
                oacc[nf] = __builtin_amdgcn_mfma_f32_16x16x32_bf16(ph, vl, oacc[nf], 0, 0, 0);
                oacc[nf] = __builtin_amdgcn_mfma_f32_16x16x32_bf16(pl, vh, oacc[nf], 0, 0, 0);
                oacc[nf] = __builtin_amdgcn_mfma_f32_16x16x32_bf16(pl, vl, oacc[nf], 0, 0, 0);
            }
        }
    }

    // epilogue: 3-split planes (identical chain to split3_kernel)
#pragma unroll
    for (int r = 0; r < 4; ++r) {
        const float inv = 1.f / lrun[r];
        const size_t base = (size_t)(bb * Ss + qt * 64 + wid * 16 + lg * 4 + r) * Dd + hh * HD;
#pragma unroll
        for (int nf = 0; nf < 4; ++nf) {
            const float o = oacc[nf][r] * inv;
            const u16 h = f2b(o);
            const float r1 = o - b2f(h);
            const u16 m = f2b(r1);
            const u16 l = f2b(r1 - b2f(m));
            const size_t off = base + nf * 16 + lr;
            os[off] = h;
            os[PT + off] = m;
            os[2 * PT + off] = l;
        }
    }
}

// ---------------------------------------------------------------------------
DEVI double block_reduce_d(double v, double* sred, int tid) {
#pragma unroll
    for (int off = 32; off > 0; off >>= 1) v += __shfl_down(v, off);
    __syncthreads();
    if ((tid & 63) == 0) sred[tid >> 6] = v;
    __syncthreads();
    return sred[0] + sred[1] + sred[2] + sred[3];
}

// ---------------------------------------------------------------------------
// LN1: x1f = LN(x + aproj)
// ---------------------------------------------------------------------------
__global__ __launch_bounds__(256)
void ln1_kernel(const float* __restrict__ x, const float* __restrict__ ap,
                const float* __restrict__ g, const float* __restrict__ b,
                float* __restrict__ x1f) {
    __shared__ double sred[4];
    const int t = blockIdx.x, tid = threadIdx.x;
    const float4 xv = ((const float4*)(x + (size_t)t * Dd))[tid];
    const float4 av = ((const float4*)(ap + (size_t)t * Dd))[tid];
    const double v0 = (double)xv.x + (double)av.x;
    const double v1 = (double)xv.y + (double)av.y;
    const double v2 = (double)xv.z + (double)av.z;
    const double v3 = (double)xv.w + (double)av.w;
    const double s = block_reduce_d(v0 + v1 + v2 + v3, sred, tid);
    const double mean = s * (1.0 / Dd);
    const double c0 = v0 - mean, c1 = v1 - mean, c2 = v2 - mean, c3 = v3 - mean;
    const double s2 = block_reduce_d(c0 * c0 + c1 * c1 + c2 * c2 + c3 * c3, sred, tid);
    const double rstd = 1.0 / sqrt(s2 * (1.0 / Dd) + 1e-5);
    const float4 gv = ((const float4*)g)[tid];
    const float4 bv = ((const float4*)b)[tid];
    float4 ov;
    ov.x = (float)(c0 * rstd * (double)gv.x + (double)bv.x);
    ov.y = (float)(c1 * rstd * (double)gv.y + (double)bv.y);
    ov.z = (float)(c2 * rstd * (double)gv.z + (double)bv.z);
    ov.w = (float)(c3 * rstd * (double)gv.w + (double)bv.w);
    ((float4*)(x1f + (size_t)t * Dd))[tid] = ov;
}

// ---------------------------------------------------------------------------
// gating stage 1 (fp64)
// ---------------------------------------------------------------------------
__global__ __launch_bounds__(256)
void gate1_kernel(const float* __restrict__ x1f, const float* __restrict__ wg,
                  int* __restrict__ idx1, int* __restrict__ idx2,
                  float* __restrict__ gate1, float* __restrict__ gate2) {
    const int tid = threadIdx.x, lane = tid & 63, wid = tid >> 6;
    const int t = blockIdx.x * 4 + wid;
    double acc[16];
#pragma unroll
    for (int e = 0; e < 16; ++e) acc[e] = 0.0;
    for (int i = 0; i < 16; ++i) {
        const int d = i * 64 + lane;
        const double xv = (double)x1f[(size_t)t * Dd + d];
        const float4* wr = (const float4*)(wg + (size_t)d * 16);
        const float4 w0 = wr[0], w1 = wr[1], w2 = wr[2], w3 = wr[3];
        acc[0] += xv * (double)w0.x;  acc[1] += xv * (double)w0.y;
        acc[2] += xv * (double)w0.z;  acc[3] += xv * (double)w0.w;
        acc[4] += xv * (double)w1.x;  acc[5] += xv * (double)w1.y;
        acc[6] += xv * (double)w1.z;  acc[7] += xv * (double)w1.w;
        acc[8] += xv * (double)w2.x;  acc[9] += xv * (double)w2.y;
        acc[10] += xv * (double)w2.z; acc[11] += xv * (double)w2.w;
        acc[12] += xv * (double)w3.x; acc[13] += xv * (double)w3.y;
        acc[14] += xv * (double)w3.z; acc[15] += xv * (double)w3.w;
    }
#pragma unroll
    for (int e = 0; e < 16; ++e) {
        acc[e] += __shfl_xor(acc[e], 1);
        acc[e] += __shfl_xor(acc[e], 2);
        acc[e] += __shfl_xor(acc[e], 4);
        acc[e] += __shfl_xor(acc[e], 8);
        acc[e] += __shfl_xor(acc[e], 16);
        acc[e] += __shfl_xor(acc[e], 32);
    }
    if (lane == 0) {
        double mx = acc[0];
#pragma unroll
        for (int e = 1; e < 16; ++e) mx = fmax(mx, acc[e]);
        double z = 0.0, ex[16];
#pragma unroll
        for (int e = 0; e < 16; ++e) { ex[e] = exp(acc[e] - mx); z += ex[e]; }
        int b1 = 0; double v1 = acc[0];
#pragma unroll
        for (int e = 1; e < 16; ++e) if (acc[e] > v1) { v1 = acc[e]; b1 = e; }
        int b2 = (b1 == 0) ? 1 : 0; double v2 = acc[b2];
#pragma unroll
        for (int e = 0; e < 16; ++e) if (e != b1 && acc[e] > v2) { v2 = acc[e]; b2 = e; }
        const double rz = 1.0 / z;
        idx1[t] = b1; idx2[t] = b2;
        gate1[t] = (float)(ex[b1] * rz); gate2[t] = (float)(ex[b2] * rz);
    }
}

// ---------------------------------------------------------------------------
// gating stage 2 (single block)
// ---------------------------------------------------------------------------
__global__ __launch_bounds__(256)
void gate2_kernel(const int* __restrict__ idx1, const int* __restrict__ idx2,
                  const float* __restrict__ gate1, const float* __restrict__ gate2,
                  int* __restrict__ p1, int* __restrict__ p2,
                  int* __restrict__ k1, int* __restrict__ k2,
                  float* __restrict__ w1, float* __restrict__ w2) {
    __shared__ int hist[16];
    __shared__ unsigned long long sb1[4][16], sb2[4][16];
    __shared__ int sbase1[16], sbase2[16];
    const int tid = threadIdx.x, lane = tid & 63, wid = tid >> 6;
    if (tid < 16) hist[tid] = 0;
    __syncthreads();
    for (int t = tid; t < Tt; t += 256) atomicAdd(&hist[idx1[t]], 1);
    __syncthreads();
    if (tid < 16) { sbase1[tid] = 0; sbase2[tid] = hist[tid]; }
    __syncthreads();
    const unsigned long long below = (1ULL << lane) - 1ULL;
    for (int ch = 0; ch < Tt / 256; ++ch) {
        const int t = ch * 256 + tid;
        const int a = idx1[t], b = idx2[t];
#pragma unroll
        for (int e = 0; e < 16; ++e) {
            const unsigned long long m1 = __ballot(a == e);
            const unsigned long long m2 = __ballot(b == e);
            if (lane == 0) { sb1[wid][e] = m1; sb2[wid][e] = m2; }
        }
        __syncthreads();
        int r1 = __popcll(sb1[wid][a] & below);
        int r2 = __popcll(sb2[wid][b] & below);
#pragma unroll
        for (int w = 0; w < 4; ++w)
            if (w < wid) { r1 += __popcll(sb1[w][a]); r2 += __popcll(sb2[w][b]); }
        const int loc1 = sbase1[a] + r1, loc2 = sbase2[b] + r2;
        const int kk1 = loc1 < Cap, kk2 = loc2 < Cap;
        const float g1 = kk1 ? gate1[t] : 0.f;
        const float g2 = kk2 ? gate2[t] : 0.f;
        const float dn = fmaxf(g1 + g2, EPSc);
        p1[t] = kk1 ? loc1 : 0;
        p2[t] = kk2 ? loc2 : 0;
        k1[t] = kk1; k2[t] = kk2;
        w1[t] = g1 / dn; w2[t] = g2 / dn;
        __syncthreads();
        if (tid == 0) {
#pragma unroll
            for (int e = 0; e < 16; ++e) {
                int c1 = 0, c2 = 0;
#pragma unroll
                for (int w = 0; w < 4; ++w) { c1 += __popcll(sb1[w][e]); c2 += __popcll(sb2[w][e]); }
                sbase1[e] += c1; sbase2[e] += c2;
            }
        }
        __syncthreads();
    }
}

// ---------------------------------------------------------------------------
// dispatch: scatter kept tokens (f32 -> bf16) into [E,C,D] buffers (pre-zeroed)
// ---------------------------------------------------------------------------
__global__ __launch_bounds__(256)
void dispatch_kernel(const float* __restrict__ x1f,
                     const int* __restrict__ i1, const int* __restrict__ p1, const int* __restrict__ k1,
                     const int* __restrict__ i2, const int* __restrict__ p2, const int* __restrict__ k2,
                     u16* __restrict__ buf) {
    const int t = blockIdx.x, tid = threadIdx.x;
    const float4 v = ((const float4*)(x1f + (size_t)t * Dd))[tid];
    u16x4 pw;
    pw[0] = f2b(v.x); pw[1] = f2b(v.y); pw[2] = f2b(v.z); pw[3] = f2b(v.w);
    if (k1[t]) *(u16x4*)(buf + ((size_t)i1[t] * Cap + p1[t]) * Dd + tid * 4) = pw;
    if (k2[t]) *(u16x4*)(buf + ((size_t)i2[t] * Cap + p2[t]) * Dd + tid * 4) = pw;
}

// ---------------------------------------------------------------------------
// combine + residual + LN2 -> d_out (f32)
// ---------------------------------------------------------------------------
__global__ __launch_bounds__(256)
void combine_ln2(const float* __restrict__ x1f, const u16* __restrict__ y,
                 const int* __restrict__ i1, const int* __restrict__ p1, const float* __restrict__ w1,
                 const int* __restrict__ i2, const int* __restrict__ p2, const float* __restrict__ w2,
                 const float* __restrict__ g, const float* __restrict__ b,
                 float* __restrict__ out) {
    __shared__ double sred[4];
    const int t = blockIdx.x, tid = threadIdx.x;
    const size_t r1 = ((size_t)i1[t] * Cap + p1[t]) * Dd;
    const size_t r2 = ((size_t)i2[t] * Cap + p2[t]) * Dd;
    const double a1 = (double)w1[t], a2 = (double)w2[t];
    const u16x4 y1 = *(const u16x4*)(y + r1 + tid * 4);
    const u16x4 y2 = *(const u16x4*)(y + r2 + tid * 4);
    const float4 xv = ((const float4*)(x1f + (size_t)t * Dd))[tid];
    const double v0 = (double)xv.x + a1 * (double)b2f(y1[0]) + a2 * (double)b2f(y2[0]);
    const double v1 = (double)xv.y + a1 * (double)b2f(y1[1]) + a2 * (double)b2f(y2[1]);
    const double v2 = (double)xv.z + a1 * (double)b2f(y1[2]) + a2 * (double)b2f(y2[2]);
    const double v3 = (double)xv.w + a1 * (double)b2f(y1[3]) + a2 * (double)b2f(y2[3]);
    const double s = block_reduce_d(v0 + v1 + v2 + v3, sred, tid);
    const double mean = s * (1.0 / Dd);
    const double c0 = v0 - mean, c1 = v1 - mean, c2 = v2 - mean, c3 = v3 - mean;
    const double s2 = block_reduce_d(c0 * c0 + c1 * c1 + c2 * c2 + c3 * c3, sred, tid);
    const double rstd = 1.0 / sqrt(s2 * (1.0 / Dd) + 1e-5);
    const float4 gv = ((const float4*)g)[tid];
    const float4 bv = ((const float4*)b)[tid];
    float4 ov;
    ov.x = (float)(c0 * rstd * (double)gv.x + (double)bv.x);
    ov.y = (float)(c1 * rstd * (double)gv.y + (double)bv.y);
    ov.z = (float)(c2 * rstd * (double)gv.z + (double)bv.z);
    ov.w = (float)(c3 * rstd * (double)gv.w + (double)bv.w);
    ((float4*)(out + (size_t)t * Dd))[tid] = ov;
}

// ---------------------------------------------------------------------------
extern "C" void kernel_launch(void* const* d_in, const int* in_sizes, int n_in,
                              void* d_out, int out_size, void* d_ws, size_t ws_size,
                              hipStream_t stream) {
    (void)in_sizes; (void)n_in; (void)out_size; (void)ws_size;
    const float* x    = (const float*)d_in[0];
    const float* inW  = (const float*)d_in[1];
    const float* inB  = (const float*)d_in[2];
    const float* outW = (const float*)d_in[3];
    const float* outB = (const float*)d_in[4];
    const float* ln1g = (const float*)d_in[5];
    const float* ln1b = (const float*)d_in[6];
    const float* ln2g = (const float*)d_in[7];
    const float* ln2b = (const float*)d_in[8];
    const float* wg   = (const float*)d_in[9];
    const float* w1   = (const float*)d_in[10];
    const float* b1   = (const float*)d_in[11];
    const float* w2   = (const float*)d_in[12];
    const float* b2   = (const float*)d_in[13];
    float* out = (float*)d_out;

    char* ws = (char*)d_ws;
    const size_t MB = 1024 * 1024;
    // ---- corrected phase-overlapped arena (all sizes in MiB, peak 352.4) ----
    // sizes: plane 16 (PT*2=16MiB exact); xs3 48; inW3 18; os3 48; outW3 6;
    //        aproj 32; x1f 32; ebuf 32 (16*1024*1024*2 = 32MiB!); ybuf 32;
    //        wt 128 (16*4096*1024*2); hbuf 128.
    // Phase A (QKV/attn/OP):
    u16*   xs3   = (u16*)(ws + 0);          // [0,48)    dead after QKV gemm
    u16*   inW3  = (u16*)(ws + 48 * MB);    // [48,66)   dead after QKV gemm
    u16*   qh    = (u16*)(ws + 66 * MB);    // [66,82)   dead after attn
    u16*   ql    = (u16*)(ws + 82 * MB);    // [82,98)   dead after attn
    u16*   kh    = (u16*)(ws + 98 * MB);    // [98,114)  dead after attn
    u16*   kl    = (u16*)(ws + 114 * MB);   // [114,130) dead after attn
    u16*   vh    = (u16*)(ws + 130 * MB);   // [130,146) dead after vtrans
    u16*   vl    = (u16*)(ws + 146 * MB);   // [146,162) dead after vtrans
    u16*   vth   = (u16*)(ws + 162 * MB);   // [162,178) dead after attn
    u16*   vtl   = (u16*)(ws + 178 * MB);   // [178,194) dead after attn
    u16*   os3   = (u16*)(ws + 194 * MB);   // [194,242) attn out, dead after OP
    u16*   outW3 = (u16*)(ws + 0);          // [0,6)     over dead xs3, dead after OP
    float* aproj = (float*)(ws + 6 * MB);   // [6,38)    over dead xs3, dead after LN1
    // Phase B (MoE):
    u16*   wt    = (u16*)(ws + 0);          // [0,128)   written post-LN1 (all dead)
    u16*   hbuf  = (u16*)(ws + 128 * MB);   // [128,256) over dead kl-tail/v*/os3
    u16*   ybuf  = (u16*)(ws + 256 * MB);   // [256,288) fresh
    u16*   ebuf  = (u16*)(ws + 288 * MB);   // [288,320) fresh
    float* x1f   = (float*)(ws + 320 * MB); // [320,352) fresh, live till end
    char*  gbase = ws + 352 * MB;           // [352,~352.4) gating arrays
    int*   idx1 = (int*)(gbase + 0 * Tt * 4);
    int*   idx2 = (int*)(gbase + 1 * Tt * 4);
    float* gt1  = (float*)(gbase + 2 * Tt * 4);
    float* gt2  = (float*)(gbase + 3 * Tt * 4);
    int*   p1   = (int*)(gbase + 4 * Tt * 4);
    int*   p2   = (int*)(gbase + 5 * Tt * 4);
    int*   k1   = (int*)(gbase + 6 * Tt * 4);
    int*   k2   = (int*)(gbase + 7 * Tt * 4);
    float* w1c  = (float*)(gbase + 8 * Tt * 4);
    float* w2c  = (float*)(gbase + 9 * Tt * 4);

    const long long nTD = (long long)Tt * Dd;
    const long long nW1 = (long long)D3 * Dd;
    const long long nW2 = (long long)Dd * Dd;

    // 1: split inputs; QKV GEMM writes split planes directly
    split3_kernel<<<(int)(nTD / 1024), 256, 0, stream>>>(x, xs3, nTD);
    split3_kernel<<<(int)(nW1 / 1024), 256, 0, stream>>>(inW, inW3, nW1);
    gemm_gl<3, 3><<<dim3(D3 / 128, Tt / 128, 1), 256, 0, stream>>>(
        xs3, inW3, nullptr, inB, Tt, D3, Dd, (size_t)nTD, (size_t)nW1, 0, 0, 0, 0,
        qh, ql, kh, kl, vh, vl);
    // 2: V transpose; attention (bit-identical math), writes os3 planes
    vtrans_kernel<<<dim3(Ss / 32, HD / 32, Bz * Hh), 256, 0, stream>>>(vh, vl, vth, vtl);
    attn_mfma<<<dim3(Ss / 64, Bz * Hh), 256, 0, stream>>>(qh, ql, kh, kl, vth, vtl, os3);
    // 3: out-proj (split3 GEMM, f32 out)
    split3_kernel<<<(int)(nW2 / 1024), 256, 0, stream>>>(outW, outW3, nW2);
    gemm_gl<3, 2><<<dim3(Dd / 128, Tt / 128, 1), 256, 0, stream>>>(
        os3, outW3, aproj, outB, Tt, Dd, Dd, (size_t)nTD, (size_t)nW2, 0, 0, 0, 0,
        nullptr, nullptr, nullptr, nullptr, nullptr, nullptr);
    // 4: LN1
    ln1_kernel<<<Tt, 256, 0, stream>>>(x, aproj, ln1g, ln1b, x1f);
    // 5-6: gating
    gate1_kernel<<<Tt / 4, 256, 0, stream>>>(x1f, wg, idx1, idx2, gt1, gt2);
    gate2_kernel<<<1, 256, 0, stream>>>(idx1, idx2, gt1, gt2, p1, p2, k1, k2, w1c, w2c);
    // 7: dispatch
    hipMemsetAsync(ebuf, 0, (size_t)Ee * Cap * Dd * 2, stream);
    dispatch_kernel<<<Tt, 256, 0, stream>>>(x1f, idx1, p1, k1, idx2, p2, k2, ebuf);
    // 8-11: expert FFN (plain bf16 MFMA)
    tconv_kernel<<<dim3(DFF / 32, Dd / 32, Ee), 256, 0, stream>>>(w1, wt, Dd, DFF);
    gemm_gl<1, 1><<<dim3(DFF / 128, Cap / 128, Ee), 256, 0, stream>>>(
        ebuf, wt, hbuf, b1, Cap, DFF, Dd, 0, 0,
        (size_t)Cap * Dd, (size_t)DFF * Dd, (size_t)Cap * DFF, DFF,
        nullptr, nullptr, nullptr, nullptr, nullptr, nullptr);
    tconv_kernel<<<dim3(Dd / 32, DFF / 32, Ee), 256, 0, stream>>>(w2, wt, DFF, Dd);
    gemm_gl<1, 0><<<dim3(Dd / 128, Cap / 128, Ee), 256, 0, stream>>>(
        hbuf, wt, ybuf, b2, Cap, Dd, DFF, 0, 0,
        (size_t)Cap * DFF, (size_t)Dd * DFF, (size_t)Cap * Dd, Dd,
        nullptr, nullptr, nullptr, nullptr, nullptr, nullptr);
    // 12: combine + residual + LN2
    combine_ln2<<<Tt, 256, 0, stream>>>(x1f, ybuf, idx1, p1, w1c, idx2, p2, w2c, ln2g, ln2b, out);
}

// Round 7
// 1366.858 us; speedup vs baseline: 2.1674x; 1.0692x over previous
//
#include <hip/hip_runtime.h>
#include <cstdint>

#define DEVI __device__ __forceinline__

typedef short short8 __attribute__((ext_vector_type(8)));
typedef float f32x4 __attribute__((ext_vector_type(4)));
typedef unsigned short u16;
typedef u16 u16x4 __attribute__((ext_vector_type(4)));

static constexpr int Bz = 8, Ss = 1024, Dd = 1024, Hh = 16, HD = 64, DFF = 4096, Ee = 16;
static constexpr int Tt = Bz * Ss;           // 8192 tokens
static constexpr int Cap = (2 * Tt) / Ee;    // 1024 capacity
static constexpr int D3 = 3 * Dd;            // 3072
static constexpr float EPSc = 1.1920929e-07f;
static constexpr size_t PT = (size_t)Tt * Dd;   // plane elements (token-major)

DEVI u16 f2b(float f) {
    union { float f; uint32_t u; } v; v.f = f;
    return (u16)((v.u + 0x7FFFu + ((v.u >> 16) & 1u)) >> 16);
}
DEVI float b2f(u16 h) {
    union { uint32_t u; float f; } v; v.u = ((uint32_t)h) << 16; return v.f;
}
DEVI f32x4 zf4() { f32x4 v; v[0] = 0.f; v[1] = 0.f; v[2] = 0.f; v[3] = 0.f; return v; }

// async global->LDS, 16B per lane. LDS dest must be wave-uniform base + lane*16B.
DEVI void gl16(const u16* g, u16* l) {
    __builtin_amdgcn_global_load_lds(
        (const __attribute__((address_space(1))) void*)g,
        (__attribute__((address_space(3))) void*)l, 16, 0, 0);
}

// swizzled u16 index for [R][64] bf16 tiles (128B rows): byte ^= (row&7)<<4
DEVI int swzb(int row, int col) {
    int byte = (row * 64 + col) * 2;
    byte ^= (row & 7) << 4;
    return byte >> 1;
}

// ---------------------------------------------------------------------------
// split fp32 -> 3 bf16 planes (hi/mid/lo), plane stride = n. n % 1024 == 0.
// ---------------------------------------------------------------------------
__global__ __launch_bounds__(256)
void split3_kernel(const float* __restrict__ in, u16* __restrict__ out, long long n) {
    const long long i = ((long long)blockIdx.x * 256 + threadIdx.x) * 4;
    if (i >= n) return;
    const float4 v = *(const float4*)(in + i);
    const float f[4] = {v.x, v.y, v.z, v.w};
    u16x4 ph, pm, pl;
#pragma unroll
    for (int c = 0; c < 4; ++c) {
        const u16 hi = f2b(f[c]);
        const float r1 = f[c] - b2f(hi);     // exact
        const u16 mi = f2b(r1);
        const float r2 = r1 - b2f(mi);       // exact
        const u16 lo = f2b(r2);
        ph[c] = hi; pm[c] = mi; pl[c] = lo;
    }
    *(u16x4*)(out + i) = ph;
    *(u16x4*)(out + n + i) = pm;
    *(u16x4*)(out + 2 * n + i) = pl;
}

// ---------------------------------------------------------------------------
// transpose + convert, vectorized: in [Z][R][Cc] f32 -> out [Z][Cc][R] bf16
// 64x64 tiles; float4 reads, u16x4 writes (both coalesced).
// ---------------------------------------------------------------------------
__global__ __launch_bounds__(256)
void tconv64_kernel(const float* __restrict__ in, u16* __restrict__ out, int R, int Cc) {
    __shared__ u16 tile[64][68];
    const int z = blockIdx.z;
    const int r0 = blockIdx.y * 64, c0 = blockIdx.x * 64;
    const int tr = threadIdx.x >> 4;          // 0..15
    const int tc4 = (threadIdx.x & 15) * 4;   // 0..60
    const float* ip = in + (size_t)z * R * Cc;
#pragma unroll
    for (int i = 0; i < 4; ++i) {
        const int row = tr + i * 16;
        const float4 v = *(const float4*)(ip + (size_t)(r0 + row) * Cc + c0 + tc4);
        u16x4 w;
        w[0] = f2b(v.x); w[1] = f2b(v.y); w[2] = f2b(v.z); w[3] = f2b(v.w);
        *(u16x4*)(&tile[row][tc4]) = w;
    }
    __syncthreads();
    u16* op = out + (size_t)z * R * Cc;
#pragma unroll
    for (int i = 0; i < 4; ++i) {
        const int orow = tr + i * 16;   // output row = source column c0+orow
        u16x4 w;
#pragma unroll
        for (int j = 0; j < 4; ++j) w[j] = tile[tc4 + j][orow];
        *(u16x4*)(op + (size_t)(c0 + orow) * R + r0 + tc4) = w;
    }
}

// ---------------------------------------------------------------------------
// V-plane transpose: vh/vl [Tt][Dd] (per bh: [s][64]) -> vth/vtl [bh][64][Ss]
// ---------------------------------------------------------------------------
__global__ __launch_bounds__(256)
void vtrans_kernel(const u16* __restrict__ vh, const u16* __restrict__ vl,
                   u16* __restrict__ vth, u16* __restrict__ vtl) {
    __shared__ u16 th[32][33], tl[32][33];
    const int bh = blockIdx.z, d0 = blockIdx.y * 32, s0 = blockIdx.x * 32;
    const int bb = bh >> 4, hh = bh & 15;
    const int tr = threadIdx.x >> 5, tc = threadIdx.x & 31;
#pragma unroll
    for (int i = 0; i < 4; ++i) {
        const size_t src = (size_t)(bb * Ss + s0 + tr + i * 8) * Dd + hh * HD + d0 + tc;
        th[tr + i * 8][tc] = vh[src];
        tl[tr + i * 8][tc] = vl[src];
    }
    __syncthreads();
#pragma unroll
    for (int i = 0; i < 4; ++i) {
        const size_t dst = ((size_t)bh * HD + d0 + tr + i * 8) * Ss + s0 + tc;
        vth[dst] = th[tc][tr + i * 8];
        vtl[dst] = tl[tc][tr + i * 8];
    }
}

// ---------------------------------------------------------------------------
// Unified MFMA BT-GEMM (128x128, 2-barrier) — routing path only (bit-stable).
// SPLITS=3 hi/mid/lo planes, 6 products (fp32-grade).
// MODE: 2 f32 out, 3 QKV split-plane out.
// ---------------------------------------------------------------------------
template <int SPLITS, int MODE>
__global__ __launch_bounds__(256)
void gemm_gl(const u16* __restrict__ A, const u16* __restrict__ Bt, void* __restrict__ Cout,
             const float* __restrict__ bias, int M, int N, int K,
             size_t psA, size_t psB,
             u16* __restrict__ qh, u16* __restrict__ ql,
             u16* __restrict__ kh, u16* __restrict__ kl,
             u16* __restrict__ vh, u16* __restrict__ vl) {
    __shared__ u16 As[SPLITS * 128 * 32];
    __shared__ u16 Bs[SPLITS * 128 * 32];
    const int tid = threadIdx.x;
    const int lane = tid & 63, wid = tid >> 6;
    const int wm = wid >> 1, wn = wid & 1;
    const int m0 = blockIdx.y * 128, n0 = blockIdx.x * 128;
    const int lr = lane & 15, lg = lane >> 4;
    const int lrow = lane >> 2;          // 0..15
    const int lcol = (lane & 3) * 8;     // 0,8,16,24

    f32x4 acc[4][4];
#pragma unroll
    for (int i = 0; i < 4; ++i)
#pragma unroll
        for (int j = 0; j < 4; ++j) acc[i][j] = zf4();

    for (int kt = 0; kt < K; kt += 32) {
#pragma unroll
        for (int p = 0; p < SPLITS; ++p) {
#pragma unroll
            for (int c = 0; c < 2; ++c) {
                const int r0 = wid * 32 + c * 16;
                gl16(A + p * psA + (size_t)(m0 + r0 + lrow) * K + kt + lcol,
                     As + p * 4096 + r0 * 32 + lane * 8);
                gl16(Bt + p * psB + (size_t)(n0 + r0 + lrow) * K + kt + lcol,
                     Bs + p * 4096 + r0 * 32 + lane * 8);
            }
        }
        __syncthreads();

        short8 af[SPLITS][4];
#pragma unroll
        for (int p = 0; p < SPLITS; ++p)
#pragma unroll
            for (int i = 0; i < 4; ++i)
                af[p][i] = *(const short8*)(As + p * 4096 + (wm * 64 + i * 16 + lr) * 32 + lg * 8);

#pragma unroll
        for (int bp = 0; bp < SPLITS; ++bp) {
            short8 bf[4];
#pragma unroll
            for (int j = 0; j < 4; ++j)
                bf[j] = *(const short8*)(Bs + bp * 4096 + (wn * 64 + j * 16 + lr) * 32 + lg * 8);
#pragma unroll
            for (int ap = 0; ap + bp < SPLITS; ++ap)
#pragma unroll
                for (int i = 0; i < 4; ++i)
#pragma unroll
                    for (int j = 0; j < 4; ++j)
                        acc[i][j] = __builtin_amdgcn_mfma_f32_16x16x32_bf16(af[ap][i], bf[j], acc[i][j], 0, 0, 0);
        }
        __syncthreads();
    }

    const int r4 = lg * 4;
    const int region = n0 >> 10;   // MODE 3: 0=Q,1=K,2=V (uniform per block)
#pragma unroll
    for (int j = 0; j < 4; ++j) {
        const int col = n0 + wn * 64 + j * 16 + lr;
        const float bv = bias[col];
#pragma unroll
        for (int i = 0; i < 4; ++i) {
#pragma unroll
            for (int r = 0; r < 4; ++r) {
                const int rowg = m0 + wm * 64 + i * 16 + r4 + r;
                float v = acc[i][j][r] + bv;
                if (MODE == 2) {
                    ((float*)Cout)[(size_t)rowg * N + col] = v;
                } else {
                    const size_t off = (size_t)rowg * Dd + (col & 1023);
                    if (region == 0) {
                        const float fs = v * 0.125f;
                        const u16 h = f2b(fs);
                        qh[off] = h; ql[off] = f2b(fs - b2f(h));
                    } else if (region == 1) {
                        const u16 h = f2b(v);
                        kh[off] = h; kl[off] = f2b(v - b2f(h));
                    } else {
                        const u16 h = f2b(v);
                        vh[off] = h; vl[off] = f2b(v - b2f(h));
                    }
                }
            }
        }
    }
}

// ---------------------------------------------------------------------------
// Expert GEMM, 256x256 tile, BK=64, 8 waves, double-buffered LDS,
// raw s_barrier + counted vmcnt(8) (loads stay in flight across barriers).
// C[M,N] = A[M,K] * Bt[N,K]^T + bias, bf16 out, optional relu.
// ---------------------------------------------------------------------------
template <int RELU>
__global__ __launch_bounds__(512)
void gemm_x2(const u16* __restrict__ A, const u16* __restrict__ Bt, u16* __restrict__ Cout,
             const float* __restrict__ bias, int M, int N, int K,
             size_t sA, size_t sB, size_t sC, int sBias) {
    __shared__ u16 lds[2][2][256 * 64];   // [buf][A/B][row*64+col] : 128 KiB
    const int tid = threadIdx.x, lane = tid & 63, wid = tid >> 6;
    const int wm = wid >> 2, wn = wid & 3;          // 2 x 4 waves
    const int lr = lane & 15, lg = lane >> 4;
    const int m0 = blockIdx.y * 256, n0 = blockIdx.x * 256;
    const int e = blockIdx.z;
    const u16* Ab = A + (size_t)e * sA;
    const u16* Bb = Bt + (size_t)e * sB;

    // per-call geometry: call c covers rows c*64 + wid*8 + lane/8, col (lane%8)*8
    const int srow = wid * 8 + (lane >> 3);
    const int scol = (lane & 7) * 8;

    f32x4 acc[8][4];
#pragma unroll
    for (int i = 0; i < 8; ++i)
#pragma unroll
        for (int j = 0; j < 4; ++j) acc[i][j] = zf4();

#define STAGE_X2(b, kt)                                                              \
    {                                                                                \
        _Pragma("unroll")                                                            \
        for (int c = 0; c < 4; ++c)                                                  \
            gl16(Ab + (size_t)(m0 + c * 64 + srow) * K + (kt) + scol,                \
                 &lds[b][0][(c * 64 + srow) * 64 + scol]);                           \
        _Pragma("unroll")                                                            \
        for (int c = 0; c < 4; ++c)                                                  \
            gl16(Bb + (size_t)(n0 + c * 64 + srow) * K + (kt) + scol,                \
                 &lds[b][1][(c * 64 + srow) * 64 + scol]);                           \
    }

#define COMPUTE_X2(b)                                                                \
    {                                                                                \
        _Pragma("unroll")                                                            \
        for (int ks = 0; ks < 2; ++ks) {                                             \
            short8 af[8], bf[4];                                                     \
            _Pragma("unroll")                                                        \
            for (int i = 0; i < 8; ++i)                                              \
                af[i] = *(const short8*)(&lds[b][0][(wm * 128 + i * 16 + lr) * 64 + ks * 32 + lg * 8]); \
            _Pragma("unroll")                                                        \
            for (int j = 0; j < 4; ++j)                                              \
                bf[j] = *(const short8*)(&lds[b][1][(wn * 64 + j * 16 + lr) * 64 + ks * 32 + lg * 8]);  \
            _Pragma("unroll")                                                        \
            for (int i = 0; i < 8; ++i)                                              \
                _Pragma("unroll")                                                    \
                for (int j = 0; j < 4; ++j)                                          \
                    acc[i][j] = __builtin_amdgcn_mfma_f32_16x16x32_bf16(af[i], bf[j], acc[i][j], 0, 0, 0); \
        }                                                                            \
    }

    const int nt = K >> 6;
    STAGE_X2(0, 0)
    for (int t = 0; t < nt - 1; ++t) {
        const int cur = t & 1;
        STAGE_X2(cur ^ 1, (t + 1) * 64)
        asm volatile("s_waitcnt vmcnt(8)" ::: "memory");
        __builtin_amdgcn_s_barrier();
        COMPUTE_X2(cur)
        asm volatile("s_waitcnt lgkmcnt(0)" ::: "memory");
        __builtin_amdgcn_s_barrier();
    }
    asm volatile("s_waitcnt vmcnt(0)" ::: "memory");
    __builtin_amdgcn_s_barrier();
    COMPUTE_X2((nt - 1) & 1)

#undef STAGE_X2
#undef COMPUTE_X2

    const int r4 = lg * 4;
#pragma unroll
    for (int j = 0; j < 4; ++j) {
        const int col = n0 + wn * 64 + j * 16 + lr;
        const float bv = bias[(size_t)e * sBias + col];
#pragma unroll
        for (int i = 0; i < 8; ++i) {
#pragma unroll
            for (int r = 0; r < 4; ++r) {
                const int rowg = m0 + wm * 128 + i * 16 + r4 + r;
                float v = acc[i][j][r] + bv;
                if (RELU) v = fmaxf(v, 0.f);
                Cout[(size_t)e * sC + (size_t)rowg * N + col] = f2b(v);
            }
        }
    }
}

// ---------------------------------------------------------------------------
// Split-bf16 MFMA flash attention (UNCHANGED — bit-stable routing path)
// ---------------------------------------------------------------------------
__global__ __launch_bounds__(256)
void attn_mfma(const u16* __restrict__ qhp, const u16* __restrict__ qlp,
               const u16* __restrict__ khp, const u16* __restrict__ klp,
               const u16* __restrict__ vthp, const u16* __restrict__ vtlp,
               u16* __restrict__ os) {
    __shared__ u16 Khi[64 * 64], Klo[64 * 64];
    __shared__ u16 Vhi[64 * 64], Vlo[64 * 64];   // [d][kk]
    __shared__ u16 Phi[4][16 * 64], Plo[4][16 * 64];

    const int qt = blockIdx.x, bh = blockIdx.y;
    const int bb = bh >> 4, hh = bh & 15;
    const int tid = threadIdx.x, lane = tid & 63, wid = tid >> 6;
    const int lr = lane & 15, lg = lane >> 4;

    short8 qhi[2], qlo[2];
    {
        const size_t qbase = (size_t)(bb * Ss + qt * 64 + wid * 16 + lr) * Dd + hh * HD;
#pragma unroll
        for (int ks = 0; ks < 2; ++ks) {
            qhi[ks] = *(const short8*)(qhp + qbase + ks * 32 + lg * 8);
            qlo[ks] = *(const short8*)(qlp + qbase + ks * 32 + lg * 8);
        }
    }

    float mrun[4], lrun[4];
    f32x4 oacc[4];
#pragma unroll
    for (int r = 0; r < 4; ++r) { mrun[r] = -1e30f; lrun[r] = 0.f; }
#pragma unroll
    for (int nf = 0; nf < 4; ++nf) oacc[nf] = zf4();

    const int srow = tid >> 2;        // 0..63
    const int sd = (tid & 3) * 16;    // 0,16,32,48

    u16* const PhiW = Phi[wid];
    u16* const PloW = Plo[wid];

    for (int kt = 0; kt < Ss / 64; ++kt) {
        const size_t krow = (size_t)(bb * Ss + kt * 64 + srow) * Dd + hh * HD + sd;
        const short8 k0 = *(const short8*)(khp + krow);
        const short8 k1 = *(const short8*)(khp + krow + 8);
        const short8 l0 = *(const short8*)(klp + krow);
        const short8 l1 = *(const short8*)(klp + krow + 8);
        const size_t vrow = ((size_t)bh * HD + srow) * Ss + kt * 64 + sd;
        const short8 v0 = *(const short8*)(vthp + vrow);
        const short8 v1 = *(const short8*)(vthp + vrow + 8);
        const short8 w0 = *(const short8*)(vtlp + vrow);
        const short8 w1 = *(const short8*)(vtlp + vrow + 8);
        __syncthreads();
        *(short8*)(Khi + swzb(srow, sd)) = k0;
        *(short8*)(Khi + swzb(srow, sd + 8)) = k1;
        *(short8*)(Klo + swzb(srow, sd)) = l0;
        *(short8*)(Klo + swzb(srow, sd + 8)) = l1;
        *(short8*)(Vhi + swzb(srow, sd)) = v0;
        *(short8*)(Vhi + swzb(srow, sd + 8)) = v1;
        *(short8*)(Vlo + swzb(srow, sd)) = w0;
        *(short8*)(Vlo + swzb(srow, sd + 8)) = w1;
        __syncthreads();

        f32x4 sc[4];
#pragma unroll
        for (int nf = 0; nf < 4; ++nf) sc[nf] = zf4();
#pragma unroll
        for (int nf = 0; nf < 4; ++nf)
#pragma unroll
            for (int ks = 0; ks < 2; ++ks) {
                const short8 kh = *(const short8*)(Khi + swzb(nf * 16 + lr, ks * 32 + lg * 8));
                const short8 kl = *(const short8*)(Klo + swzb(nf * 16 + lr, ks * 32 + lg * 8));
                sc[nf] = __builtin_amdgcn_mfma_f32_16x16x32_bf16(qhi[ks], kh, sc[nf], 0, 0, 0);
                sc[nf] = __builtin_amdgcn_mfma_f32_16x16x32_bf16(qhi[ks], kl, sc[nf], 0, 0, 0);
                sc[nf] = __builtin_amdgcn_mfma_f32_16x16x32_bf16(qlo[ks], kh, sc[nf], 0, 0, 0);
                sc[nf] = __builtin_amdgcn_mfma_f32_16x16x32_bf16(qlo[ks], kl, sc[nf], 0, 0, 0);
            }

        float scl[4];
#pragma unroll
        for (int r = 0; r < 4; ++r) {
            float m = fmaxf(fmaxf(sc[0][r], sc[1][r]), fmaxf(sc[2][r], sc[3][r]));
            m = fmaxf(m, __shfl_xor(m, 1));
            m = fmaxf(m, __shfl_xor(m, 2));
            m = fmaxf(m, __shfl_xor(m, 4));
            m = fmaxf(m, __shfl_xor(m, 8));
            const float mn = fmaxf(mrun[r], m);
            scl[r] = __expf(mrun[r] - mn);
            mrun[r] = mn;
            float s = 0.f;
#pragma unroll
            for (int nf = 0; nf < 4; ++nf) {
                const float p = __expf(sc[nf][r] - mn);
                sc[nf][r] = p;
                s += p;
            }
            s += __shfl_xor(s, 1);
            s += __shfl_xor(s, 2);
            s += __shfl_xor(s, 4);
            s += __shfl_xor(s, 8);
            lrun[r] = lrun[r] * scl[r] + s;
        }

#pragma unroll
        for (int nf = 0; nf < 4; ++nf)
#pragma unroll
            for (int r = 0; r < 4; ++r) {
                const float p = sc[nf][r];
                const u16 h = f2b(p);
                const int idx = swzb(lg * 4 + r, nf * 16 + lr);
                PhiW[idx] = h;
                PloW[idx] = f2b(p - b2f(h));
            }

#pragma unroll
        for (int nf = 0; nf < 4; ++nf)
#pragma unroll
            for (int r = 0; r < 4; ++r) oacc[nf][r] *= scl[r];

#pragma unroll
        for (int ks = 0; ks < 2; ++ks) {
            const short8 ph = *(const short8*)(PhiW + swzb(lr, ks * 32 + lg * 8));
            const short8 pl = *(const short8*)(PloW + swzb(lr, ks * 32 + lg * 8));
#pragma unroll
            for (int nf = 0; nf < 4; ++nf) {
                const short8 vh = *(const short8*)(Vhi + swzb(nf * 16 + lr, ks * 32 + lg * 8));
                const short8 vl = *(const short8*)(Vlo + swzb(nf * 16 + lr, ks * 32 + lg * 8));
                oacc[nf] = __builtin_amdgcn_mfma_f32_16x16x32_bf16(ph, vh, oacc[nf], 0, 0, 0);
                oacc[nf] = __builtin_amdgcn_mfma_f32_16x16x32_bf16(ph, vl, oacc[nf], 0, 0, 0);
                oacc[nf] = __builtin_amdgcn_mfma_f32_16x16x32_bf16(pl, vh, oacc[nf], 0, 0, 0);
                oacc[nf] = __builtin_amdgcn_mfma_f32_16x16x32_bf16(pl, vl, oacc[nf], 0, 0, 0);
            }
        }
    }

#pragma unroll
    for (int r = 0; r < 4; ++r) {
        const float inv = 1.f / lrun[r];
        const size_t base = (size_t)(bb * Ss + qt * 64 + wid * 16 + lg * 4 + r) * Dd + hh * HD;
#pragma unroll
        for (int nf = 0; nf < 4; ++nf) {
            const float o = oacc[nf][r] * inv;
            const u16 h = f2b(o);
            const float r1 = o - b2f(h);
            const u16 m = f2b(r1);
            const u16 l = f2b(r1 - b2f(m));
            const size_t off = base + nf * 16 + lr;
            os[off] = h;
            os[PT + off] = m;
            os[2 * PT + off] = l;
        }
    }
}

// ---------------------------------------------------------------------------
DEVI double block_reduce_d(double v, double* sred, int tid) {
#pragma unroll
    for (int off = 32; off > 0; off >>= 1) v += __shfl_down(v, off);
    __syncthreads();
    if ((tid & 63) == 0) sred[tid >> 6] = v;
    __syncthreads();
    return sred[0] + sred[1] + sred[2] + sred[3];
}

// ---------------------------------------------------------------------------
// LN1: x1f = LN(x + aproj)
// ---------------------------------------------------------------------------
__global__ __launch_bounds__(256)
void ln1_kernel(const float* __restrict__ x, const float* __restrict__ ap,
                const float* __restrict__ g, const float* __restrict__ b,
                float* __restrict__ x1f) {
    __shared__ double sred[4];
    const int t = blockIdx.x, tid = threadIdx.x;
    const float4 xv = ((const float4*)(x + (size_t)t * Dd))[tid];
    const float4 av = ((const float4*)(ap + (size_t)t * Dd))[tid];
    const double v0 = (double)xv.x + (double)av.x;
    const double v1 = (double)xv.y + (double)av.y;
    const double v2 = (double)xv.z + (double)av.z;
    const double v3 = (double)xv.w + (double)av.w;
    const double s = block_reduce_d(v0 + v1 + v2 + v3, sred, tid);
    const double mean = s * (1.0 / Dd);
    const double c0 = v0 - mean, c1 = v1 - mean, c2 = v2 - mean, c3 = v3 - mean;
    const double s2 = block_reduce_d(c0 * c0 + c1 * c1 + c2 * c2 + c3 * c3, sred, tid);
    const double rstd = 1.0 / sqrt(s2 * (1.0 / Dd) + 1e-5);
    const float4 gv = ((const float4*)g)[tid];
    const float4 bv = ((const float4*)b)[tid];
    float4 ov;
    ov.x = (float)(c0 * rstd * (double)gv.x + (double)bv.x);
    ov.y = (float)(c1 * rstd * (double)gv.y + (double)bv.y);
    ov.z = (float)(c2 * rstd * (double)gv.z + (double)bv.z);
    ov.w = (float)(c3 * rstd * (double)gv.w + (double)bv.w);
    ((float4*)(x1f + (size_t)t * Dd))[tid] = ov;
}

// ---------------------------------------------------------------------------
// gating stage 1 (fp64)
// ---------------------------------------------------------------------------
__global__ __launch_bounds__(256)
void gate1_kernel(const float* __restrict__ x1f, const float* __restrict__ wg,
                  int* __restrict__ idx1, int* __restrict__ idx2,
                  float* __restrict__ gate1, float* __restrict__ gate2) {
    const int tid = threadIdx.x, lane = tid & 63, wid = tid >> 6;
    const int t = blockIdx.x * 4 + wid;
    double acc[16];
#pragma unroll
    for (int e = 0; e < 16; ++e) acc[e] = 0.0;
    for (int i = 0; i < 16; ++i) {
        const int d = i * 64 + lane;
        const double xv = (double)x1f[(size_t)t * Dd + d];
        const float4* wr = (const float4*)(wg + (size_t)d * 16);
        const float4 w0 = wr[0], w1 = wr[1], w2 = wr[2], w3 = wr[3];
        acc[0] += xv * (double)w0.x;  acc[1] += xv * (double)w0.y;
        acc[2] += xv * (double)w0.z;  acc[3] += xv * (double)w0.w;
        acc[4] += xv * (double)w1.x;  acc[5] += xv * (double)w1.y;
        acc[6] += xv * (double)w1.z;  acc[7] += xv * (double)w1.w;
        acc[8] += xv * (double)w2.x;  acc[9] += xv * (double)w2.y;
        acc[10] += xv * (double)w2.z; acc[11] += xv * (double)w2.w;
        acc[12] += xv * (double)w3.x; acc[13] += xv * (double)w3.y;
        acc[14] += xv * (double)w3.z; acc[15] += xv * (double)w3.w;
    }
#pragma unroll
    for (int e = 0; e < 16; ++e) {
        acc[e] += __shfl_xor(acc[e], 1);
        acc[e] += __shfl_xor(acc[e], 2);
        acc[e] += __shfl_xor(acc[e], 4);
        acc[e] += __shfl_xor(acc[e], 8);
        acc[e] += __shfl_xor(acc[e], 16);
        acc[e] += __shfl_xor(acc[e], 32);
    }
    if (lane == 0) {
        double mx = acc[0];
#pragma unroll
        for (int e = 1; e < 16; ++e) mx = fmax(mx, acc[e]);
        double z = 0.0, ex[16];
#pragma unroll
        for (int e = 0; e < 16; ++e) { ex[e] = exp(acc[e] - mx); z += ex[e]; }
        int b1 = 0; double v1 = acc[0];
#pragma unroll
        for (int e = 1; e < 16; ++e) if (acc[e] > v1) { v1 = acc[e]; b1 = e; }
        int b2 = (b1 == 0) ? 1 : 0; double v2 = acc[b2];
#pragma unroll
        for (int e = 0; e < 16; ++e) if (e != b1 && acc[e] > v2) { v2 = acc[e]; b2 = e; }
        const double rz = 1.0 / z;
        idx1[t] = b1; idx2[t] = b2;
        gate1[t] = (float)(ex[b1] * rz); gate2[t] = (float)(ex[b2] * rz);
    }
}

// ---------------------------------------------------------------------------
// gating stage 2 (single block)
// ---------------------------------------------------------------------------
__global__ __launch_bounds__(256)
void gate2_kernel(const int* __restrict__ idx1, const int* __restrict__ idx2,
                  const float* __restrict__ gate1, const float* __restrict__ gate2,
                  int* __restrict__ p1, int* __restrict__ p2,
                  int* __restrict__ k1, int* __restrict__ k2,
                  float* __restrict__ w1, float* __restrict__ w2) {
    __shared__ int hist[16];
    __shared__ unsigned long long sb1[4][16], sb2[4][16];
    __shared__ int sbase1[16], sbase2[16];
    const int tid = threadIdx.x, lane = tid & 63, wid = tid >> 6;
    if (tid < 16) hist[tid] = 0;
    __syncthreads();
    for (int t = tid; t < Tt; t += 256) atomicAdd(&hist[idx1[t]], 1);
    __syncthreads();
    if (tid < 16) { sbase1[tid] = 0; sbase2[tid] = hist[tid]; }
    __syncthreads();
    const unsigned long long below = (1ULL << lane) - 1ULL;
    for (int ch = 0; ch < Tt / 256; ++ch) {
        const int t = ch * 256 + tid;
        const int a = idx1[t], b = idx2[t];
#pragma unroll
        for (int e = 0; e < 16; ++e) {
            const unsigned long long m1 = __ballot(a == e);
            const unsigned long long m2 = __ballot(b == e);
            if (lane == 0) { sb1[wid][e] = m1; sb2[wid][e] = m2; }
        }
        __syncthreads();
        int r1 = __popcll(sb1[wid][a] & below);
        int r2 = __popcll(sb2[wid][b] & below);
#pragma unroll
        for (int w = 0; w < 4; ++w)
            if (w < wid) { r1 += __popcll(sb1[w][a]); r2 += __popcll(sb2[w][b]); }
        const int loc1 = sbase1[a] + r1, loc2 = sbase2[b] + r2;
        const int kk1 = loc1 < Cap, kk2 = loc2 < Cap;
        const float g1 = kk1 ? gate1[t] : 0.f;
        const float g2 = kk2 ? gate2[t] : 0.f;
        const float dn = fmaxf(g1 + g2, EPSc);
        p1[t] = kk1 ? loc1 : 0;
        p2[t] = kk2 ? loc2 : 0;
        k1[t] = kk1; k2[t] = kk2;
        w1[t] = g1 / dn; w2[t] = g2 / dn;
        __syncthreads();
        if (tid == 0) {
#pragma unroll
            for (int e = 0; e < 16; ++e) {
                int c1 = 0, c2 = 0;
#pragma unroll
                for (int w = 0; w < 4; ++w) { c1 += __popcll(sb1[w][e]); c2 += __popcll(sb2[w][e]); }
                sbase1[e] += c1; sbase2[e] += c2;
            }
        }
        __syncthreads();
    }
}

// ---------------------------------------------------------------------------
// dispatch: scatter kept tokens (f32 -> bf16) into [E,C,D] buffers (pre-zeroed)
// ---------------------------------------------------------------------------
__global__ __launch_bounds__(256)
void dispatch_kernel(const float* __restrict__ x1f,
                     const int* __restrict__ i1, const int* __restrict__ p1, const int* __restrict__ k1,
                     const int* __restrict__ i2, const int* __restrict__ p2, const int* __restrict__ k2,
                     u16* __restrict__ buf) {
    const int t = blockIdx.x, tid = threadIdx.x;
    const float4 v = ((const float4*)(x1f + (size_t)t * Dd))[tid];
    u16x4 pw;
    pw[0] = f2b(v.x); pw[1] = f2b(v.y); pw[2] = f2b(v.z); pw[3] = f2b(v.w);
    if (k1[t]) *(u16x4*)(buf + ((size_t)i1[t] * Cap + p1[t]) * Dd + tid * 4) = pw;
    if (k2[t]) *(u16x4*)(buf + ((size_t)i2[t] * Cap + p2[t]) * Dd + tid * 4) = pw;
}

// ---------------------------------------------------------------------------
// combine + residual + LN2 -> d_out (f32)
// ---------------------------------------------------------------------------
__global__ __launch_bounds__(256)
void combine_ln2(const float* __restrict__ x1f, const u16* __restrict__ y,
                 const int* __restrict__ i1, const int* __restrict__ p1, const float* __restrict__ w1,
                 const int* __restrict__ i2, const int* __restrict__ p2, const float* __restrict__ w2,
                 const float* __restrict__ g, const float* __restrict__ b,
                 float* __restrict__ out) {
    __shared__ double sred[4];
    const int t = blockIdx.x, tid = threadIdx.x;
    const size_t r1 = ((size_t)i1[t] * Cap + p1[t]) * Dd;
    const size_t r2 = ((size_t)i2[t] * Cap + p2[t]) * Dd;
    const double a1 = (double)w1[t], a2 = (double)w2[t];
    const u16x4 y1 = *(const u16x4*)(y + r1 + tid * 4);
    const u16x4 y2 = *(const u16x4*)(y + r2 + tid * 4);
    const float4 xv = ((const float4*)(x1f + (size_t)t * Dd))[tid];
    const double v0 = (double)xv.x + a1 * (double)b2f(y1[0]) + a2 * (double)b2f(y2[0]);
    const double v1 = (double)xv.y + a1 * (double)b2f(y1[1]) + a2 * (double)b2f(y2[1]);
    const double v2 = (double)xv.z + a1 * (double)b2f(y1[2]) + a2 * (double)b2f(y2[2]);
    const double v3 = (double)xv.w + a1 * (double)b2f(y1[3]) + a2 * (double)b2f(y2[3]);
    const double s = block_reduce_d(v0 + v1 + v2 + v3, sred, tid);
    const double mean = s * (1.0 / Dd);
    const double c0 = v0 - mean, c1 = v1 - mean, c2 = v2 - mean, c3 = v3 - mean;
    const double s2 = block_reduce_d(c0 * c0 + c1 * c1 + c2 * c2 + c3 * c3, sred, tid);
    const double rstd = 1.0 / sqrt(s2 * (1.0 / Dd) + 1e-5);
    const float4 gv = ((const float4*)g)[tid];
    const float4 bv = ((const float4*)b)[tid];
    float4 ov;
    ov.x = (float)(c0 * rstd * (double)gv.x + (double)bv.x);
    ov.y = (float)(c1 * rstd * (double)gv.y + (double)bv.y);
    ov.z = (float)(c2 * rstd * (double)gv.z + (double)bv.z);
    ov.w = (float)(c3 * rstd * (double)gv.w + (double)bv.w);
    ((float4*)(out + (size_t)t * Dd))[tid] = ov;
}

// ---------------------------------------------------------------------------
extern "C" void kernel_launch(void* const* d_in, const int* in_sizes, int n_in,
                              void* d_out, int out_size, void* d_ws, size_t ws_size,
                              hipStream_t stream) {
    (void)in_sizes; (void)n_in; (void)out_size; (void)ws_size;
    const float* x    = (const float*)d_in[0];
    const float* inW  = (const float*)d_in[1];
    const float* inB  = (const float*)d_in[2];
    const float* outW = (const float*)d_in[3];
    const float* outB = (const float*)d_in[4];
    const float* ln1g = (const float*)d_in[5];
    const float* ln1b = (const float*)d_in[6];
    const float* ln2g = (const float*)d_in[7];
    const float* ln2b = (const float*)d_in[8];
    const float* wg   = (const float*)d_in[9];
    const float* w1   = (const float*)d_in[10];
    const float* b1   = (const float*)d_in[11];
    const float* w2   = (const float*)d_in[12];
    const float* b2   = (const float*)d_in[13];
    float* out = (float*)d_out;

    char* ws = (char*)d_ws;
    const size_t MB = 1024 * 1024;
    // ---- phase-overlapped arena (verified layout from round 6, peak 352.4 MiB) ----
    u16*   xs3   = (u16*)(ws + 0);          // [0,48)    dead after QKV gemm
    u16*   inW3  = (u16*)(ws + 48 * MB);    // [48,66)   dead after QKV gemm
    u16*   qh    = (u16*)(ws + 66 * MB);    // [66,82)   dead after attn
    u16*   ql    = (u16*)(ws + 82 * MB);    // [82,98)   dead after attn
    u16*   kh    = (u16*)(ws + 98 * MB);    // [98,114)  dead after attn
    u16*   kl    = (u16*)(ws + 114 * MB);   // [114,130) dead after attn
    u16*   vh    = (u16*)(ws + 130 * MB);   // [130,146) dead after vtrans
    u16*   vl    = (u16*)(ws + 146 * MB);   // [146,162) dead after vtrans
    u16*   vth   = (u16*)(ws + 162 * MB);   // [162,178) dead after attn
    u16*   vtl   = (u16*)(ws + 178 * MB);   // [178,194) dead after attn
    u16*   os3   = (u16*)(ws + 194 * MB);   // [194,242) attn out, dead after OP
    u16*   outW3 = (u16*)(ws + 0);          // [0,6)     over dead xs3, dead after OP
    float* aproj = (float*)(ws + 6 * MB);   // [6,38)    over dead xs3, dead after LN1
    u16*   wt    = (u16*)(ws + 0);          // [0,128)   written post-LN1 (all dead)
    u16*   hbuf  = (u16*)(ws + 128 * MB);   // [128,256) over dead kl-tail/v*/os3
    u16*   ybuf  = (u16*)(ws + 256 * MB);   // [256,288) fresh
    u16*   ebuf  = (u16*)(ws + 288 * MB);   // [288,320) fresh
    float* x1f   = (float*)(ws + 320 * MB); // [320,352) fresh, live till end
    char*  gbase = ws + 352 * MB;           // [352,~352.4) gating arrays
    int*   idx1 = (int*)(gbase + 0 * Tt * 4);
    int*   idx2 = (int*)(gbase + 1 * Tt * 4);
    float* gt1  = (float*)(gbase + 2 * Tt * 4);
    float* gt2  = (float*)(gbase + 3 * Tt * 4);
    int*   p1   = (int*)(gbase + 4 * Tt * 4);
    int*   p2   = (int*)(gbase + 5 * Tt * 4);
    int*   k1   = (int*)(gbase + 6 * Tt * 4);
    int*   k2   = (int*)(gbase + 7 * Tt * 4);
    float* w1c  = (float*)(gbase + 8 * Tt * 4);
    float* w2c  = (float*)(gbase + 9 * Tt * 4);

    const long long nTD = (long long)Tt * Dd;
    const long long nW1 = (long long)D3 * Dd;
    const long long nW2 = (long long)Dd * Dd;

    // 1: split inputs; QKV GEMM writes split planes directly (bit-stable path)
    split3_kernel<<<(int)(nTD / 1024), 256, 0, stream>>>(x, xs3, nTD);
    split3_kernel<<<(int)(nW1 / 1024), 256, 0, stream>>>(inW, inW3, nW1);
    gemm_gl<3, 3><<<dim3(D3 / 128, Tt / 128, 1), 256, 0, stream>>>(
        xs3, inW3, nullptr, inB, Tt, D3, Dd, (size_t)nTD, (size_t)nW1,
        qh, ql, kh, kl, vh, vl);
    // 2: V transpose; attention (bit-identical), writes os3 planes
    vtrans_kernel<<<dim3(Ss / 32, HD / 32, Bz * Hh), 256, 0, stream>>>(vh, vl, vth, vtl);
    attn_mfma<<<dim3(Ss / 64, Bz * Hh), 256, 0, stream>>>(qh, ql, kh, kl, vth, vtl, os3);
    // 3: out-proj (split3 GEMM, f32 out)
    split3_kernel<<<(int)(nW2 / 1024), 256, 0, stream>>>(outW, outW3, nW2);
    gemm_gl<3, 2><<<dim3(Dd / 128, Tt / 128, 1), 256, 0, stream>>>(
        os3, outW3, aproj, outB, Tt, Dd, Dd, (size_t)nTD, (size_t)nW2,
        nullptr, nullptr, nullptr, nullptr, nullptr, nullptr);
    // 4: LN1
    ln1_kernel<<<Tt, 256, 0, stream>>>(x, aproj, ln1g, ln1b, x1f);
    // 5-6: gating
    gate1_kernel<<<Tt / 4, 256, 0, stream>>>(x1f, wg, idx1, idx2, gt1, gt2);
    gate2_kernel<<<1, 256, 0, stream>>>(idx1, idx2, gt1, gt2, p1, p2, k1, k2, w1c, w2c);
    // 7: dispatch
    hipMemsetAsync(ebuf, 0, (size_t)Ee * Cap * Dd * 2, stream);
    dispatch_kernel<<<Tt, 256, 0, stream>>>(x1f, idx1, p1, k1, idx2, p2, k2, ebuf);
    // 8-11: expert FFN — 256^2 double-buffered counted-vmcnt GEMMs
    tconv64_kernel<<<dim3(DFF / 64, Dd / 64, Ee), 256, 0, stream>>>(w1, wt, Dd, DFF);
    gemm_x2<1><<<dim3(DFF / 256, Cap / 256, Ee), 512, 0, stream>>>(
        ebuf, wt, hbuf, b1, Cap, DFF, Dd,
        (size_t)Cap * Dd, (size_t)DFF * Dd, (size_t)Cap * DFF, DFF);
    tconv64_kernel<<<dim3(Dd / 64, DFF / 64, Ee), 256, 0, stream>>>(w2, wt, DFF, Dd);
    gemm_x2<0><<<dim3(Dd / 256, Cap / 256, Ee), 512, 0, stream>>>(
        hbuf, wt, ybuf, b2, Cap, Dd, DFF,
        (size_t)Cap * DFF, (size_t)Dd * DFF, (size_t)Cap * Dd, Dd);
    // 12: combine + residual + LN2
    combine_ln2<<<Tt, 256, 0, stream>>>(x1f, ybuf, idx1, p1, w1c, idx2, p2, w2c, ln2g, ln2b, out);
}

// Round 8
// 1342.265 us; speedup vs baseline: 2.2071x; 1.0183x over previous
//
#include <hip/hip_runtime.h>
#include <cstdint>

#define DEVI __device__ __forceinline__

typedef short short8 __attribute__((ext_vector_type(8)));
typedef float f32x4 __attribute__((ext_vector_type(4)));
typedef unsigned short u16;
typedef u16 u16x4 __attribute__((ext_vector_type(4)));

static constexpr int Bz = 8, Ss = 1024, Dd = 1024, Hh = 16, HD = 64, DFF = 4096, Ee = 16;
static constexpr int Tt = Bz * Ss;           // 8192 tokens
static constexpr int Cap = (2 * Tt) / Ee;    // 1024 capacity
static constexpr int D3 = 3 * Dd;            // 3072
static constexpr float EPSc = 1.1920929e-07f;
static constexpr size_t PT = (size_t)Tt * Dd;   // plane elements (token-major)

DEVI u16 f2b(float f) {
    union { float f; uint32_t u; } v; v.f = f;
    return (u16)((v.u + 0x7FFFu + ((v.u >> 16) & 1u)) >> 16);
}
DEVI float b2f(u16 h) {
    union { uint32_t u; float f; } v; v.u = ((uint32_t)h) << 16; return v.f;
}
DEVI f32x4 zf4() { f32x4 v; v[0] = 0.f; v[1] = 0.f; v[2] = 0.f; v[3] = 0.f; return v; }

// async global->LDS, 16B per lane. LDS dest must be wave-uniform base + lane*16B.
DEVI void gl16(const u16* g, u16* l) {
    __builtin_amdgcn_global_load_lds(
        (const __attribute__((address_space(1))) void*)g,
        (__attribute__((address_space(3))) void*)l, 16, 0, 0);
}

// swizzled u16 index for [R][64] bf16 tiles (128B rows): byte ^= (row&7)<<4
DEVI int swzb(int row, int col) {
    int byte = (row * 64 + col) * 2;
    byte ^= (row & 7) << 4;
    return byte >> 1;
}

// ---------------------------------------------------------------------------
// split fp32 -> 3 bf16 planes (hi/mid/lo), plane stride = n. n % 1024 == 0.
// ---------------------------------------------------------------------------
__global__ __launch_bounds__(256)
void split3_kernel(const float* __restrict__ in, u16* __restrict__ out, long long n) {
    const long long i = ((long long)blockIdx.x * 256 + threadIdx.x) * 4;
    if (i >= n) return;
    const float4 v = *(const float4*)(in + i);
    const float f[4] = {v.x, v.y, v.z, v.w};
    u16x4 ph, pm, pl;
#pragma unroll
    for (int c = 0; c < 4; ++c) {
        const u16 hi = f2b(f[c]);
        const float r1 = f[c] - b2f(hi);     // exact
        const u16 mi = f2b(r1);
        const float r2 = r1 - b2f(mi);       // exact
        const u16 lo = f2b(r2);
        ph[c] = hi; pm[c] = mi; pl[c] = lo;
    }
    *(u16x4*)(out + i) = ph;
    *(u16x4*)(out + n + i) = pm;
    *(u16x4*)(out + 2 * n + i) = pl;
}

// ---------------------------------------------------------------------------
// transpose + convert, vectorized: in [Z][R][Cc] f32 -> out [Z][Cc][R] bf16
// ---------------------------------------------------------------------------
__global__ __launch_bounds__(256)
void tconv64_kernel(const float* __restrict__ in, u16* __restrict__ out, int R, int Cc) {
    __shared__ u16 tile[64][68];
    const int z = blockIdx.z;
    const int r0 = blockIdx.y * 64, c0 = blockIdx.x * 64;
    const int tr = threadIdx.x >> 4;          // 0..15
    const int tc4 = (threadIdx.x & 15) * 4;   // 0..60
    const float* ip = in + (size_t)z * R * Cc;
#pragma unroll
    for (int i = 0; i < 4; ++i) {
        const int row = tr + i * 16;
        const float4 v = *(const float4*)(ip + (size_t)(r0 + row) * Cc + c0 + tc4);
        u16x4 w;
        w[0] = f2b(v.x); w[1] = f2b(v.y); w[2] = f2b(v.z); w[3] = f2b(v.w);
        *(u16x4*)(&tile[row][tc4]) = w;
    }
    __syncthreads();
    u16* op = out + (size_t)z * R * Cc;
#pragma unroll
    for (int i = 0; i < 4; ++i) {
        const int orow = tr + i * 16;
        u16x4 w;
#pragma unroll
        for (int j = 0; j < 4; ++j) w[j] = tile[tc4 + j][orow];
        *(u16x4*)(op + (size_t)(c0 + orow) * R + r0 + tc4) = w;
    }
}

// ---------------------------------------------------------------------------
// V-plane transpose: vh/vl [Tt][Dd] (per bh: [s][64]) -> vth/vtl [bh][64][Ss]
// ---------------------------------------------------------------------------
__global__ __launch_bounds__(256)
void vtrans_kernel(const u16* __restrict__ vh, const u16* __restrict__ vl,
                   u16* __restrict__ vth, u16* __restrict__ vtl) {
    __shared__ u16 th[32][33], tl[32][33];
    const int bh = blockIdx.z, d0 = blockIdx.y * 32, s0 = blockIdx.x * 32;
    const int bb = bh >> 4, hh = bh & 15;
    const int tr = threadIdx.x >> 5, tc = threadIdx.x & 31;
#pragma unroll
    for (int i = 0; i < 4; ++i) {
        const size_t src = (size_t)(bb * Ss + s0 + tr + i * 8) * Dd + hh * HD + d0 + tc;
        th[tr + i * 8][tc] = vh[src];
        tl[tr + i * 8][tc] = vl[src];
    }
    __syncthreads();
#pragma unroll
    for (int i = 0; i < 4; ++i) {
        const size_t dst = ((size_t)bh * HD + d0 + tr + i * 8) * Ss + s0 + tc;
        vth[dst] = th[tc][tr + i * 8];
        vtl[dst] = tl[tc][tr + i * 8];
    }
}

// ---------------------------------------------------------------------------
// 3-split MFMA BT-GEMM v2 (routing path): 128x128 tile, BK=32, 8 waves,
// double-buffered 96KiB LDS, raw s_barrier + counted vmcnt(6).
// Per-element MFMA accumulation chain BIT-IDENTICAL to the validated gemm_gl:
// same kt order, same product order (bp-major), same epilogue arithmetic.
// MODE: 2 f32 out, 3 QKV split-plane out.
// ---------------------------------------------------------------------------
template <int MODE>
__global__ __launch_bounds__(512)
void gemm_x3(const u16* __restrict__ A, const u16* __restrict__ Bt, void* __restrict__ Cout,
             const float* __restrict__ bias, int M, int N, int K,
             size_t psA, size_t psB,
             u16* __restrict__ qh, u16* __restrict__ ql,
             u16* __restrict__ kh, u16* __restrict__ kl,
             u16* __restrict__ vh, u16* __restrict__ vl) {
    __shared__ u16 lds[2 * 3 * 2 * 128 * 32];   // [buf][plane][A/B][128*32] = 96 KiB
    const int tid = threadIdx.x, lane = tid & 63, wid = tid >> 6;
    const int wm = wid >> 1, wn = wid & 1;       // 4 x 2 waves -> 32x64 per wave
    const int lr = lane & 15, lg = lane >> 4;
    const int m0 = blockIdx.y * 128, n0 = blockIdx.x * 128;

    // 48 staging calls per K-step (3 planes x {A,B} x 8 segs), 6 per wave.
    const u16* gsrc[6];
    int ldof[6];
#pragma unroll
    for (int c = 0; c < 6; ++c) {
        const int g = wid * 6 + c;
        const int p = g >> 4, r = g & 15, mat = r >> 3, seg = r & 7;
        const int row = seg * 16 + (lane >> 2);
        const int col = (lane & 3) * 8;
        gsrc[c] = (mat ? Bt + p * psB + (size_t)(n0 + row) * K
                       : A + p * psA + (size_t)(m0 + row) * K) + col;
        ldof[c] = (p * 2 + mat) * 4096 + seg * 512 + lane * 8;
    }

    f32x4 acc[2][4];
#pragma unroll
    for (int i = 0; i < 2; ++i)
#pragma unroll
        for (int j = 0; j < 4; ++j) acc[i][j] = zf4();

#define STAGE_X3(b, kto)                                                       \
    {                                                                          \
        _Pragma("unroll")                                                      \
        for (int c = 0; c < 6; ++c)                                            \
            gl16(gsrc[c] + (kto), lds + (b) * 24576 + ldof[c]);                \
    }

#define COMPUTE_X3(b)                                                          \
    {                                                                          \
        const u16* L = lds + (b) * 24576;                                      \
        short8 af[3][2];                                                       \
        _Pragma("unroll")                                                      \
        for (int p = 0; p < 3; ++p)                                            \
            _Pragma("unroll")                                                  \
            for (int i = 0; i < 2; ++i)                                        \
                af[p][i] = *(const short8*)(L + (p * 2) * 4096 +               \
                                            (wm * 32 + i * 16 + lr) * 32 + lg * 8); \
        _Pragma("unroll")                                                      \
        for (int bp = 0; bp < 3; ++bp) {                                       \
            short8 bf[4];                                                      \
            _Pragma("unroll")                                                  \
            for (int j = 0; j < 4; ++j)                                        \
                bf[j] = *(const short8*)(L + (bp * 2 + 1) * 4096 +             \
                                         (wn * 64 + j * 16 + lr) * 32 + lg * 8); \
            _Pragma("unroll")                                                  \
            for (int ap = 0; ap + bp < 3; ++ap)                                \
                _Pragma("unroll")                                              \
                for (int i = 0; i < 2; ++i)                                    \
                    _Pragma("unroll")                                          \
                    for (int j = 0; j < 4; ++j)                                \
                        acc[i][j] = __builtin_amdgcn_mfma_f32_16x16x32_bf16(   \
                            af[ap][i], bf[j], acc[i][j], 0, 0, 0);             \
        }                                                                      \
    }

    const int nt = K >> 5;
    STAGE_X3(0, 0)
    for (int t = 0; t < nt - 1; ++t) {
        const int cur = t & 1;
        STAGE_X3(cur ^ 1, (t + 1) * 32)
        asm volatile("s_waitcnt vmcnt(6)" ::: "memory");
        __builtin_amdgcn_s_barrier();
        COMPUTE_X3(cur)
        asm volatile("s_waitcnt lgkmcnt(0)" ::: "memory");
        __builtin_amdgcn_s_barrier();
    }
    asm volatile("s_waitcnt vmcnt(0)" ::: "memory");
    __builtin_amdgcn_s_barrier();
    COMPUTE_X3((nt - 1) & 1)

#undef STAGE_X3
#undef COMPUTE_X3

    const int r4 = lg * 4;
    const int region = n0 >> 10;   // MODE 3: 0=Q,1=K,2=V (uniform per block)
#pragma unroll
    for (int j = 0; j < 4; ++j) {
        const int col = n0 + wn * 64 + j * 16 + lr;
        const float bv = bias[col];
#pragma unroll
        for (int i = 0; i < 2; ++i) {
#pragma unroll
            for (int r = 0; r < 4; ++r) {
                const int rowg = m0 + wm * 32 + i * 16 + r4 + r;
                float v = acc[i][j][r] + bv;
                if (MODE == 2) {
                    ((float*)Cout)[(size_t)rowg * N + col] = v;
                } else {
                    const size_t off = (size_t)rowg * Dd + (col & 1023);
                    if (region == 0) {
                        const float fs = v * 0.125f;
                        const u16 h = f2b(fs);
                        qh[off] = h; ql[off] = f2b(fs - b2f(h));
                    } else if (region == 1) {
                        const u16 h = f2b(v);
                        kh[off] = h; kl[off] = f2b(v - b2f(h));
                    } else {
                        const u16 h = f2b(v);
                        vh[off] = h; vl[off] = f2b(v - b2f(h));
                    }
                }
            }
        }
    }
}

// ---------------------------------------------------------------------------
// Expert GEMM, 256x256 tile, BK=64, 8 waves, double-buffered LDS,
// raw s_barrier + counted vmcnt(8). (validated round 7)
// ---------------------------------------------------------------------------
template <int RELU>
__global__ __launch_bounds__(512)
void gemm_x2(const u16* __restrict__ A, const u16* __restrict__ Bt, u16* __restrict__ Cout,
             const float* __restrict__ bias, int M, int N, int K,
             size_t sA, size_t sB, size_t sC, int sBias) {
    __shared__ u16 lds[2][2][256 * 64];   // 128 KiB
    const int tid = threadIdx.x, lane = tid & 63, wid = tid >> 6;
    const int wm = wid >> 2, wn = wid & 3;
    const int lr = lane & 15, lg = lane >> 4;
    const int m0 = blockIdx.y * 256, n0 = blockIdx.x * 256;
    const int e = blockIdx.z;
    const u16* Ab = A + (size_t)e * sA;
    const u16* Bb = Bt + (size_t)e * sB;

    const int srow = wid * 8 + (lane >> 3);
    const int scol = (lane & 7) * 8;

    f32x4 acc[8][4];
#pragma unroll
    for (int i = 0; i < 8; ++i)
#pragma unroll
        for (int j = 0; j < 4; ++j) acc[i][j] = zf4();

#define STAGE_X2(b, kt)                                                              \
    {                                                                                \
        _Pragma("unroll")                                                            \
        for (int c = 0; c < 4; ++c)                                                  \
            gl16(Ab + (size_t)(m0 + c * 64 + srow) * K + (kt) + scol,                \
                 &lds[b][0][(c * 64 + srow) * 64 + scol]);                           \
        _Pragma("unroll")                                                            \
        for (int c = 0; c < 4; ++c)                                                  \
            gl16(Bb + (size_t)(n0 + c * 64 + srow) * K + (kt) + scol,                \
                 &lds[b][1][(c * 64 + srow) * 64 + scol]);                           \
    }

#define COMPUTE_X2(b)                                                                \
    {                                                                                \
        _Pragma("unroll")                                                            \
        for (int ks = 0; ks < 2; ++ks) {                                             \
            short8 af[8], bf[4];                                                     \
            _Pragma("unroll")                                                        \
            for (int i = 0; i < 8; ++i)                                              \
                af[i] = *(const short8*)(&lds[b][0][(wm * 128 + i * 16 + lr) * 64 + ks * 32 + lg * 8]); \
            _Pragma("unroll")                                                        \
            for (int j = 0; j < 4; ++j)                                              \
                bf[j] = *(const short8*)(&lds[b][1][(wn * 64 + j * 16 + lr) * 64 + ks * 32 + lg * 8]);  \
            _Pragma("unroll")                                                        \
            for (int i = 0; i < 8; ++i)                                              \
                _Pragma("unroll")                                                    \
                for (int j = 0; j < 4; ++j)                                          \
                    acc[i][j] = __builtin_amdgcn_mfma_f32_16x16x32_bf16(af[i], bf[j], acc[i][j], 0, 0, 0); \
        }                                                                            \
    }

    const int nt = K >> 6;
    STAGE_X2(0, 0)
    for (int t = 0; t < nt - 1; ++t) {
        const int cur = t & 1;
        STAGE_X2(cur ^ 1, (t + 1) * 64)
        asm volatile("s_waitcnt vmcnt(8)" ::: "memory");
        __builtin_amdgcn_s_barrier();
        COMPUTE_X2(cur)
        asm volatile("s_waitcnt lgkmcnt(0)" ::: "memory");
        __builtin_amdgcn_s_barrier();
    }
    asm volatile("s_waitcnt vmcnt(0)" ::: "memory");
    __builtin_amdgcn_s_barrier();
    COMPUTE_X2((nt - 1) & 1)

#undef STAGE_X2
#undef COMPUTE_X2

    const int r4 = lg * 4;
#pragma unroll
    for (int j = 0; j < 4; ++j) {
        const int col = n0 + wn * 64 + j * 16 + lr;
        const float bv = bias[(size_t)e * sBias + col];
#pragma unroll
        for (int i = 0; i < 8; ++i) {
#pragma unroll
            for (int r = 0; r < 4; ++r) {
                const int rowg = m0 + wm * 128 + i * 16 + r4 + r;
                float v = acc[i][j][r] + bv;
                if (RELU) v = fmaxf(v, 0.f);
                Cout[(size_t)e * sC + (size_t)rowg * N + col] = f2b(v);
            }
        }
    }
}

// ---------------------------------------------------------------------------
// Split-bf16 MFMA flash attention (UNCHANGED — bit-stable routing path)
// ---------------------------------------------------------------------------
__global__ __launch_bounds__(256)
void attn_mfma(const u16* __restrict__ qhp, const u16* __restrict__ qlp,
               const u16* __restrict__ khp, const u16* __restrict__ klp,
               const u16* __restrict__ vthp, const u16* __restrict__ vtlp,
               u16* __restrict__ os) {
    __shared__ u16 Khi[64 * 64], Klo[64 * 64];
    __shared__ u16 Vhi[64 * 64], Vlo[64 * 64];   // [d][kk]
    __shared__ u16 Phi[4][16 * 64], Plo[4][16 * 64];

    const int qt = blockIdx.x, bh = blockIdx.y;
    const int bb = bh >> 4, hh = bh & 15;
    const int tid = threadIdx.x, lane = tid & 63, wid = tid >> 6;
    const int lr = lane & 15, lg = lane >> 4;

    short8 qhi[2], qlo[2];
    {
        const size_t qbase = (size_t)(bb * Ss + qt * 64 + wid * 16 + lr) * Dd + hh * HD;
#pragma unroll
        for (int ks = 0; ks < 2; ++ks) {
            qhi[ks] = *(const short8*)(qhp + qbase + ks * 32 + lg * 8);
            qlo[ks] = *(const short8*)(qlp + qbase + ks * 32 + lg * 8);
        }
    }

    float mrun[4], lrun[4];
    f32x4 oacc[4];
#pragma unroll
    for (int r = 0; r < 4; ++r) { mrun[r] = -1e30f; lrun[r] = 0.f; }
#pragma unroll
    for (int nf = 0; nf < 4; ++nf) oacc[nf] = zf4();

    const int srow = tid >> 2;        // 0..63
    const int sd = (tid & 3) * 16;    // 0,16,32,48

    u16* const PhiW = Phi[wid];
    u16* const PloW = Plo[wid];

    for (int kt = 0; kt < Ss / 64; ++kt) {
        const size_t krow = (size_t)(bb * Ss + kt * 64 + srow) * Dd + hh * HD + sd;
        const short8 k0 = *(const short8*)(khp + krow);
        const short8 k1 = *(const short8*)(khp + krow + 8);
        const short8 l0 = *(const short8*)(klp + krow);
        const short8 l1 = *(const short8*)(klp + krow + 8);
        const size_t vrow = ((size_t)bh * HD + srow) * Ss + kt * 64 + sd;
        const short8 v0 = *(const short8*)(vthp + vrow);
        const short8 v1 = *(const short8*)(vthp + vrow + 8);
        const short8 w0 = *(const short8*)(vtlp + vrow);
        const short8 w1 = *(const short8*)(vtlp + vrow + 8);
        __syncthreads();
        *(short8*)(Khi + swzb(srow, sd)) = k0;
        *(short8*)(Khi + swzb(srow, sd + 8)) = k1;
        *(short8*)(Klo + swzb(srow, sd)) = l0;
        *(short8*)(Klo + swzb(srow, sd + 8)) = l1;
        *(short8*)(Vhi + swzb(srow, sd)) = v0;
        *(short8*)(Vhi + swzb(srow, sd + 8)) = v1;
        *(short8*)(Vlo + swzb(srow, sd)) = w0;
        *(short8*)(Vlo + swzb(srow, sd + 8)) = w1;
        __syncthreads();

        f32x4 sc[4];
#pragma unroll
        for (int nf = 0; nf < 4; ++nf) sc[nf] = zf4();
#pragma unroll
        for (int nf = 0; nf < 4; ++nf)
#pragma unroll
            for (int ks = 0; ks < 2; ++ks) {
                const short8 kh = *(const short8*)(Khi + swzb(nf * 16 + lr, ks * 32 + lg * 8));
                const short8 kl = *(const short8*)(Klo + swzb(nf * 16 + lr, ks * 32 + lg * 8));
                sc[nf] = __builtin_amdgcn_mfma_f32_16x16x32_bf16(qhi[ks], kh, sc[nf], 0, 0, 0);
                sc[nf] = __builtin_amdgcn_mfma_f32_16x16x32_bf16(qhi[ks], kl, sc[nf], 0, 0, 0);
                sc[nf] = __builtin_amdgcn_mfma_f32_16x16x32_bf16(qlo[ks], kh, sc[nf], 0, 0, 0);
                sc[nf] = __builtin_amdgcn_mfma_f32_16x16x32_bf16(qlo[ks], kl, sc[nf], 0, 0, 0);
            }

        float scl[4];
#pragma unroll
        for (int r = 0; r < 4; ++r) {
            float m = fmaxf(fmaxf(sc[0][r], sc[1][r]), fmaxf(sc[2][r], sc[3][r]));
            m = fmaxf(m, __shfl_xor(m, 1));
            m = fmaxf(m, __shfl_xor(m, 2));
            m = fmaxf(m, __shfl_xor(m, 4));
            m = fmaxf(m, __shfl_xor(m, 8));
            const float mn = fmaxf(mrun[r], m);
            scl[r] = __expf(mrun[r] - mn);
            mrun[r] = mn;
            float s = 0.f;
#pragma unroll
            for (int nf = 0; nf < 4; ++nf) {
                const float p = __expf(sc[nf][r] - mn);
                sc[nf][r] = p;
                s += p;
            }
            s += __shfl_xor(s, 1);
            s += __shfl_xor(s, 2);
            s += __shfl_xor(s, 4);
            s += __shfl_xor(s, 8);
            lrun[r] = lrun[r] * scl[r] + s;
        }

#pragma unroll
        for (int nf = 0; nf < 4; ++nf)
#pragma unroll
            for (int r = 0; r < 4; ++r) {
                const float p = sc[nf][r];
                const u16 h = f2b(p);
                const int idx = swzb(lg * 4 + r, nf * 16 + lr);
                PhiW[idx] = h;
                PloW[idx] = f2b(p - b2f(h));
            }

#pragma unroll
        for (int nf = 0; nf < 4; ++nf)
#pragma unroll
            for (int r = 0; r < 4; ++r) oacc[nf][r] *= scl[r];

#pragma unroll
        for (int ks = 0; ks < 2; ++ks) {
            const short8 ph = *(const short8*)(PhiW + swzb(lr, ks * 32 + lg * 8));
            const short8 pl = *(const short8*)(PloW + swzb(lr, ks * 32 + lg * 8));
#pragma unroll
            for (int nf = 0; nf < 4; ++nf) {
                const short8 vh = *(const short8*)(Vhi + swzb(nf * 16 + lr, ks * 32 + lg * 8));
                const short8 vl = *(const short8*)(Vlo + swzb(nf * 16 + lr, ks * 32 + lg * 8));
                oacc[nf] = __builtin_amdgcn_mfma_f32_16x16x32_bf16(ph, vh, oacc[nf], 0, 0, 0);
                oacc[nf] = __builtin_amdgcn_mfma_f32_16x16x32_bf16(ph, vl, oacc[nf], 0, 0, 0);
                oacc[nf] = __builtin_amdgcn_mfma_f32_16x16x32_bf16(pl, vh, oacc[nf], 0, 0, 0);
                oacc[nf] = __builtin_amdgcn_mfma_f32_16x16x32_bf16(pl, vl, oacc[nf], 0, 0, 0);
            }
        }
    }

#pragma unroll
    for (int r = 0; r < 4; ++r) {
        const float inv = 1.f / lrun[r];
        const size_t base = (size_t)(bb * Ss + qt * 64 + wid * 16 + lg * 4 + r) * Dd + hh * HD;
#pragma unroll
        for (int nf = 0; nf < 4; ++nf) {
            const float o = oacc[nf][r] * inv;
            const u16 h = f2b(o);
            const float r1 = o - b2f(h);
            const u16 m = f2b(r1);
            const u16 l = f2b(r1 - b2f(m));
            const size_t off = base + nf * 16 + lr;
            os[off] = h;
            os[PT + off] = m;
            os[2 * PT + off] = l;
        }
    }
}

// ---------------------------------------------------------------------------
DEVI double block_reduce_d(double v, double* sred, int tid) {
#pragma unroll
    for (int off = 32; off > 0; off >>= 1) v += __shfl_down(v, off);
    __syncthreads();
    if ((tid & 63) == 0) sred[tid >> 6] = v;
    __syncthreads();
    return sred[0] + sred[1] + sred[2] + sred[3];
}

// ---------------------------------------------------------------------------
// LN1: x1f = LN(x + aproj)
// ---------------------------------------------------------------------------
__global__ __launch_bounds__(256)
void ln1_kernel(const float* __restrict__ x, const float* __restrict__ ap,
                const float* __restrict__ g, const float* __restrict__ b,
                float* __restrict__ x1f) {
    __shared__ double sred[4];
    const int t = blockIdx.x, tid = threadIdx.x;
    const float4 xv = ((const float4*)(x + (size_t)t * Dd))[tid];
    const float4 av = ((const float4*)(ap + (size_t)t * Dd))[tid];
    const double v0 = (double)xv.x + (double)av.x;
    const double v1 = (double)xv.y + (double)av.y;
    const double v2 = (double)xv.z + (double)av.z;
    const double v3 = (double)xv.w + (double)av.w;
    const double s = block_reduce_d(v0 + v1 + v2 + v3, sred, tid);
    const double mean = s * (1.0 / Dd);
    const double c0 = v0 - mean, c1 = v1 - mean, c2 = v2 - mean, c3 = v3 - mean;
    const double s2 = block_reduce_d(c0 * c0 + c1 * c1 + c2 * c2 + c3 * c3, sred, tid);
    const double rstd = 1.0 / sqrt(s2 * (1.0 / Dd) + 1e-5);
    const float4 gv = ((const float4*)g)[tid];
    const float4 bv = ((const float4*)b)[tid];
    float4 ov;
    ov.x = (float)(c0 * rstd * (double)gv.x + (double)bv.x);
    ov.y = (float)(c1 * rstd * (double)gv.y + (double)bv.y);
    ov.z = (float)(c2 * rstd * (double)gv.z + (double)bv.z);
    ov.w = (float)(c3 * rstd * (double)gv.w + (double)bv.w);
    ((float4*)(x1f + (size_t)t * Dd))[tid] = ov;
}

// ---------------------------------------------------------------------------
// gating stage 1 (fp64)
// ---------------------------------------------------------------------------
__global__ __launch_bounds__(256)
void gate1_kernel(const float* __restrict__ x1f, const float* __restrict__ wg,
                  int* __restrict__ idx1, int* __restrict__ idx2,
                  float* __restrict__ gate1, float* __restrict__ gate2) {
    const int tid = threadIdx.x, lane = tid & 63, wid = tid >> 6;
    const int t = blockIdx.x * 4 + wid;
    double acc[16];
#pragma unroll
    for (int e = 0; e < 16; ++e) acc[e] = 0.0;
    for (int i = 0; i < 16; ++i) {
        const int d = i * 64 + lane;
        const double xv = (double)x1f[(size_t)t * Dd + d];
        const float4* wr = (const float4*)(wg + (size_t)d * 16);
        const float4 w0 = wr[0], w1 = wr[1], w2 = wr[2], w3 = wr[3];
        acc[0] += xv * (double)w0.x;  acc[1] += xv * (double)w0.y;
        acc[2] += xv * (double)w0.z;  acc[3] += xv * (double)w0.w;
        acc[4] += xv * (double)w1.x;  acc[5] += xv * (double)w1.y;
        acc[6] += xv * (double)w1.z;  acc[7] += xv * (double)w1.w;
        acc[8] += xv * (double)w2.x;  acc[9] += xv * (double)w2.y;
        acc[10] += xv * (double)w2.z; acc[11] += xv * (double)w2.w;
        acc[12] += xv * (double)w3.x; acc[13] += xv * (double)w3.y;
        acc[14] += xv * (double)w3.z; acc[15] += xv * (double)w3.w;
    }
#pragma unroll
    for (int e = 0; e < 16; ++e) {
        acc[e] += __shfl_xor(acc[e], 1);
        acc[e] += __shfl_xor(acc[e], 2);
        acc[e] += __shfl_xor(acc[e], 4);
        acc[e] += __shfl_xor(acc[e], 8);
        acc[e] += __shfl_xor(acc[e], 16);
        acc[e] += __shfl_xor(acc[e], 32);
    }
    if (lane == 0) {
        double mx = acc[0];
#pragma unroll
        for (int e = 1; e < 16; ++e) mx = fmax(mx, acc[e]);
        double z = 0.0, ex[16];
#pragma unroll
        for (int e = 0; e < 16; ++e) { ex[e] = exp(acc[e] - mx); z += ex[e]; }
        int b1 = 0; double v1 = acc[0];
#pragma unroll
        for (int e = 1; e < 16; ++e) if (acc[e] > v1) { v1 = acc[e]; b1 = e; }
        int b2 = (b1 == 0) ? 1 : 0; double v2 = acc[b2];
#pragma unroll
        for (int e = 0; e < 16; ++e) if (e != b1 && acc[e] > v2) { v2 = acc[e]; b2 = e; }
        const double rz = 1.0 / z;
        idx1[t] = b1; idx2[t] = b2;
        gate1[t] = (float)(ex[b1] * rz); gate2[t] = (float)(ex[b2] * rz);
    }
}

// ---------------------------------------------------------------------------
// gating stage 2 (single block)
// ---------------------------------------------------------------------------
__global__ __launch_bounds__(256)
void gate2_kernel(const int* __restrict__ idx1, const int* __restrict__ idx2,
                  const float* __restrict__ gate1, const float* __restrict__ gate2,
                  int* __restrict__ p1, int* __restrict__ p2,
                  int* __restrict__ k1, int* __restrict__ k2,
                  float* __restrict__ w1, float* __restrict__ w2) {
    __shared__ int hist[16];
    __shared__ unsigned long long sb1[4][16], sb2[4][16];
    __shared__ int sbase1[16], sbase2[16];
    const int tid = threadIdx.x, lane = tid & 63, wid = tid >> 6;
    if (tid < 16) hist[tid] = 0;
    __syncthreads();
    for (int t = tid; t < Tt; t += 256) atomicAdd(&hist[idx1[t]], 1);
    __syncthreads();
    if (tid < 16) { sbase1[tid] = 0; sbase2[tid] = hist[tid]; }
    __syncthreads();
    const unsigned long long below = (1ULL << lane) - 1ULL;
    for (int ch = 0; ch < Tt / 256; ++ch) {
        const int t = ch * 256 + tid;
        const int a = idx1[t], b = idx2[t];
#pragma unroll
        for (int e = 0; e < 16; ++e) {
            const unsigned long long m1 = __ballot(a == e);
            const unsigned long long m2 = __ballot(b == e);
            if (lane == 0) { sb1[wid][e] = m1; sb2[wid][e] = m2; }
        }
        __syncthreads();
        int r1 = __popcll(sb1[wid][a] & below);
        int r2 = __popcll(sb2[wid][b] & below);
#pragma unroll
        for (int w = 0; w < 4; ++w)
            if (w < wid) { r1 += __popcll(sb1[w][a]); r2 += __popcll(sb2[w][b]); }
        const int loc1 = sbase1[a] + r1, loc2 = sbase2[b] + r2;
        const int kk1 = loc1 < Cap, kk2 = loc2 < Cap;
        const float g1 = kk1 ? gate1[t] : 0.f;
        const float g2 = kk2 ? gate2[t] : 0.f;
        const float dn = fmaxf(g1 + g2, EPSc);
        p1[t] = kk1 ? loc1 : 0;
        p2[t] = kk2 ? loc2 : 0;
        k1[t] = kk1; k2[t] = kk2;
        w1[t] = g1 / dn; w2[t] = g2 / dn;
        __syncthreads();
        if (tid == 0) {
#pragma unroll
            for (int e = 0; e < 16; ++e) {
                int c1 = 0, c2 = 0;
#pragma unroll
                for (int w = 0; w < 4; ++w) { c1 += __popcll(sb1[w][e]); c2 += __popcll(sb2[w][e]); }
                sbase1[e] += c1; sbase2[e] += c2;
            }
        }
        __syncthreads();
    }
}

// ---------------------------------------------------------------------------
// dispatch: scatter kept tokens (f32 -> bf16) into [E,C,D] buffers (pre-zeroed)
// ---------------------------------------------------------------------------
__global__ __launch_bounds__(256)
void dispatch_kernel(const float* __restrict__ x1f,
                     const int* __restrict__ i1, const int* __restrict__ p1, const int* __restrict__ k1,
                     const int* __restrict__ i2, const int* __restrict__ p2, const int* __restrict__ k2,
                     u16* __restrict__ buf) {
    const int t = blockIdx.x, tid = threadIdx.x;
    const float4 v = ((const float4*)(x1f + (size_t)t * Dd))[tid];
    u16x4 pw;
    pw[0] = f2b(v.x); pw[1] = f2b(v.y); pw[2] = f2b(v.z); pw[3] = f2b(v.w);
    if (k1[t]) *(u16x4*)(buf + ((size_t)i1[t] * Cap + p1[t]) * Dd + tid * 4) = pw;
    if (k2[t]) *(u16x4*)(buf + ((size_t)i2[t] * Cap + p2[t]) * Dd + tid * 4) = pw;
}

// ---------------------------------------------------------------------------
// combine + residual + LN2 -> d_out (f32)
// ---------------------------------------------------------------------------
__global__ __launch_bounds__(256)
void combine_ln2(const float* __restrict__ x1f, const u16* __restrict__ y,
                 const int* __restrict__ i1, const int* __restrict__ p1, const float* __restrict__ w1,
                 const int* __restrict__ i2, const int* __restrict__ p2, const float* __restrict__ w2,
                 const float* __restrict__ g, const float* __restrict__ b,
                 float* __restrict__ out) {
    __shared__ double sred[4];
    const int t = blockIdx.x, tid = threadIdx.x;
    const size_t r1 = ((size_t)i1[t] * Cap + p1[t]) * Dd;
    const size_t r2 = ((size_t)i2[t] * Cap + p2[t]) * Dd;
    const double a1 = (double)w1[t], a2 = (double)w2[t];
    const u16x4 y1 = *(const u16x4*)(y + r1 + tid * 4);
    const u16x4 y2 = *(const u16x4*)(y + r2 + tid * 4);
    const float4 xv = ((const float4*)(x1f + (size_t)t * Dd))[tid];
    const double v0 = (double)xv.x + a1 * (double)b2f(y1[0]) + a2 * (double)b2f(y2[0]);
    const double v1 = (double)xv.y + a1 * (double)b2f(y1[1]) + a2 * (double)b2f(y2[1]);
    const double v2 = (double)xv.z + a1 * (double)b2f(y1[2]) + a2 * (double)b2f(y2[2]);
    const double v3 = (double)xv.w + a1 * (double)b2f(y1[3]) + a2 * (double)b2f(y2[3]);
    const double s = block_reduce_d(v0 + v1 + v2 + v3, sred, tid);
    const double mean = s * (1.0 / Dd);
    const double c0 = v0 - mean, c1 = v1 - mean, c2 = v2 - mean, c3 = v3 - mean;
    const double s2 = block_reduce_d(c0 * c0 + c1 * c1 + c2 * c2 + c3 * c3, sred, tid);
    const double rstd = 1.0 / sqrt(s2 * (1.0 / Dd) + 1e-5);
    const float4 gv = ((const float4*)g)[tid];
    const float4 bv = ((const float4*)b)[tid];
    float4 ov;
    ov.x = (float)(c0 * rstd * (double)gv.x + (double)bv.x);
    ov.y = (float)(c1 * rstd * (double)gv.y + (double)bv.y);
    ov.z = (float)(c2 * rstd * (double)gv.z + (double)bv.z);
    ov.w = (float)(c3 * rstd * (double)gv.w + (double)bv.w);
    ((float4*)(out + (size_t)t * Dd))[tid] = ov;
}

// ---------------------------------------------------------------------------
extern "C" void kernel_launch(void* const* d_in, const int* in_sizes, int n_in,
                              void* d_out, int out_size, void* d_ws, size_t ws_size,
                              hipStream_t stream) {
    (void)in_sizes; (void)n_in; (void)out_size; (void)ws_size;
    const float* x    = (const float*)d_in[0];
    const float* inW  = (const float*)d_in[1];
    const float* inB  = (const float*)d_in[2];
    const float* outW = (const float*)d_in[3];
    const float* outB = (const float*)d_in[4];
    const float* ln1g = (const float*)d_in[5];
    const float* ln1b = (const float*)d_in[6];
    const float* ln2g = (const float*)d_in[7];
    const float* ln2b = (const float*)d_in[8];
    const float* wg   = (const float*)d_in[9];
    const float* w1   = (const float*)d_in[10];
    const float* b1   = (const float*)d_in[11];
    const float* w2   = (const float*)d_in[12];
    const float* b2   = (const float*)d_in[13];
    float* out = (float*)d_out;

    char* ws = (char*)d_ws;
    const size_t MB = 1024 * 1024;
    // ---- phase-overlapped arena (verified layout, peak 352.4 MiB) ----
    u16*   xs3   = (u16*)(ws + 0);          // [0,48)    dead after QKV gemm
    u16*   inW3  = (u16*)(ws + 48 * MB);    // [48,66)   dead after QKV gemm
    u16*   qh    = (u16*)(ws + 66 * MB);    // [66,82)   dead after attn
    u16*   ql    = (u16*)(ws + 82 * MB);    // [82,98)   dead after attn
    u16*   kh    = (u16*)(ws + 98 * MB);    // [98,114)  dead after attn
    u16*   kl    = (u16*)(ws + 114 * MB);   // [114,130) dead after attn
    u16*   vh    = (u16*)(ws + 130 * MB);   // [130,146) dead after vtrans
    u16*   vl    = (u16*)(ws + 146 * MB);   // [146,162) dead after vtrans
    u16*   vth   = (u16*)(ws + 162 * MB);   // [162,178) dead after attn
    u16*   vtl   = (u16*)(ws + 178 * MB);   // [178,194) dead after attn
    u16*   os3   = (u16*)(ws + 194 * MB);   // [194,242) attn out, dead after OP
    u16*   outW3 = (u16*)(ws + 0);          // [0,6)     over dead xs3, dead after OP
    float* aproj = (float*)(ws + 6 * MB);   // [6,38)    over dead xs3, dead after LN1
    u16*   wt    = (u16*)(ws + 0);          // [0,128)   written post-LN1 (all dead)
    u16*   hbuf  = (u16*)(ws + 128 * MB);   // [128,256) over dead kl-tail/v*/os3
    u16*   ybuf  = (u16*)(ws + 256 * MB);   // [256,288) fresh
    u16*   ebuf  = (u16*)(ws + 288 * MB);   // [288,320) fresh
    float* x1f   = (float*)(ws + 320 * MB); // [320,352) fresh, live till end
    char*  gbase = ws + 352 * MB;           // [352,~352.4) gating arrays
    int*   idx1 = (int*)(gbase + 0 * Tt * 4);
    int*   idx2 = (int*)(gbase + 1 * Tt * 4);
    float* gt1  = (float*)(gbase + 2 * Tt * 4);
    float* gt2  = (float*)(gbase + 3 * Tt * 4);
    int*   p1   = (int*)(gbase + 4 * Tt * 4);
    int*   p2   = (int*)(gbase + 5 * Tt * 4);
    int*   k1   = (int*)(gbase + 6 * Tt * 4);
    int*   k2   = (int*)(gbase + 7 * Tt * 4);
    float* w1c  = (float*)(gbase + 8 * Tt * 4);
    float* w2c  = (float*)(gbase + 9 * Tt * 4);

    const long long nTD = (long long)Tt * Dd;
    const long long nW1 = (long long)D3 * Dd;
    const long long nW2 = (long long)Dd * Dd;

    // 1: split inputs; QKV GEMM (gemm_x3, bit-identical chain) writes split planes
    split3_kernel<<<(int)(nTD / 1024), 256, 0, stream>>>(x, xs3, nTD);
    split3_kernel<<<(int)(nW1 / 1024), 256, 0, stream>>>(inW, inW3, nW1);
    gemm_x3<3><<<dim3(D3 / 128, Tt / 128, 1), 512, 0, stream>>>(
        xs3, inW3, nullptr, inB, Tt, D3, Dd, (size_t)nTD, (size_t)nW1,
        qh, ql, kh, kl, vh, vl);
    // 2: V transpose; attention (bit-identical), writes os3 planes
    vtrans_kernel<<<dim3(Ss / 32, HD / 32, Bz * Hh), 256, 0, stream>>>(vh, vl, vth, vtl);
    attn_mfma<<<dim3(Ss / 64, Bz * Hh), 256, 0, stream>>>(qh, ql, kh, kl, vth, vtl, os3);
    // 3: out-proj (gemm_x3, f32 out)
    split3_kernel<<<(int)(nW2 / 1024), 256, 0, stream>>>(outW, outW3, nW2);
    gemm_x3<2><<<dim3(Dd / 128, Tt / 128, 1), 512, 0, stream>>>(
        os3, outW3, aproj, outB, Tt, Dd, Dd, (size_t)nTD, (size_t)nW2,
        nullptr, nullptr, nullptr, nullptr, nullptr, nullptr);
    // 4: LN1
    ln1_kernel<<<Tt, 256, 0, stream>>>(x, aproj, ln1g, ln1b, x1f);
    // 5-6: gating
    gate1_kernel<<<Tt / 4, 256, 0, stream>>>(x1f, wg, idx1, idx2, gt1, gt2);
    gate2_kernel<<<1, 256, 0, stream>>>(idx1, idx2, gt1, gt2, p1, p2, k1, k2, w1c, w2c);
    // 7: dispatch
    hipMemsetAsync(ebuf, 0, (size_t)Ee * Cap * Dd * 2, stream);
    dispatch_kernel<<<Tt, 256, 0, stream>>>(x1f, idx1, p1, k1, idx2, p2, k2, ebuf);
    // 8-11: expert FFN — 256^2 double-buffered counted-vmcnt GEMMs
    tconv64_kernel<<<dim3(DFF / 64, Dd / 64, Ee), 256, 0, stream>>>(w1, wt, Dd, DFF);
    gemm_x2<1><<<dim3(DFF / 256, Cap / 256, Ee), 512, 0, stream>>>(
        ebuf, wt, hbuf, b1, Cap, DFF, Dd,
        (size_t)Cap * Dd, (size_t)DFF * Dd, (size_t)Cap * DFF, DFF);
    tconv64_kernel<<<dim3(Dd / 64, DFF / 64, Ee), 256, 0, stream>>>(w2, wt, DFF, Dd);
    gemm_x2<0><<<dim3(Dd / 256, Cap / 256, Ee), 512, 0, stream>>>(
        hbuf, wt, ybuf, b2, Cap, Dd, DFF,
        (size_t)Cap * DFF, (size_t)Dd * DFF, (size_t)Cap * Dd, Dd);
    // 12: combine + residual + LN2
    combine_ln2<<<Tt, 256, 0, stream>>>(x1f, ybuf, idx1, p1, w1c, idx2, p2, w2c, ln2g, ln2b, out);
}

// Round 9
// 1320.495 us; speedup vs baseline: 2.2435x; 1.0165x over previous
//
#include <hip/hip_runtime.h>
#include <cstdint>

#define DEVI __device__ __forceinline__

typedef short short8 __attribute__((ext_vector_type(8)));
typedef float f32x4 __attribute__((ext_vector_type(4)));
typedef unsigned short u16;
typedef u16 u16x4 __attribute__((ext_vector_type(4)));

static constexpr int Bz = 8, Ss = 1024, Dd = 1024, Hh = 16, HD = 64, DFF = 4096, Ee = 16;
static constexpr int Tt = Bz * Ss;           // 8192 tokens
static constexpr int Cap = (2 * Tt) / Ee;    // 1024 capacity
static constexpr int D3 = 3 * Dd;            // 3072
static constexpr float EPSc = 1.1920929e-07f;
static constexpr size_t PT = (size_t)Tt * Dd;   // plane elements (token-major)

DEVI u16 f2b(float f) {
    union { float f; uint32_t u; } v; v.f = f;
    return (u16)((v.u + 0x7FFFu + ((v.u >> 16) & 1u)) >> 16);
}
DEVI float b2f(u16 h) {
    union { uint32_t u; float f; } v; v.u = ((uint32_t)h) << 16; return v.f;
}
DEVI f32x4 zf4() { f32x4 v; v[0] = 0.f; v[1] = 0.f; v[2] = 0.f; v[3] = 0.f; return v; }

// async global->LDS, 16B per lane. LDS dest must be wave-uniform base + lane*16B.
DEVI void gl16(const u16* g, u16* l) {
    __builtin_amdgcn_global_load_lds(
        (const __attribute__((address_space(1))) void*)g,
        (__attribute__((address_space(3))) void*)l, 16, 0, 0);
}

// swizzled u16 index for [R][64] bf16 tiles (128B rows): byte ^= (row&7)<<4
DEVI int swzb(int row, int col) {
    int byte = (row * 64 + col) * 2;
    byte ^= (row & 7) << 4;
    return byte >> 1;
}

// ---------------------------------------------------------------------------
// split fp32 -> 3 bf16 planes (hi/mid/lo), plane stride = n. n % 1024 == 0.
// ---------------------------------------------------------------------------
__global__ __launch_bounds__(256)
void split3_kernel(const float* __restrict__ in, u16* __restrict__ out, long long n) {
    const long long i = ((long long)blockIdx.x * 256 + threadIdx.x) * 4;
    if (i >= n) return;
    const float4 v = *(const float4*)(in + i);
    const float f[4] = {v.x, v.y, v.z, v.w};
    u16x4 ph, pm, pl;
#pragma unroll
    for (int c = 0; c < 4; ++c) {
        const u16 hi = f2b(f[c]);
        const float r1 = f[c] - b2f(hi);     // exact
        const u16 mi = f2b(r1);
        const float r2 = r1 - b2f(mi);       // exact
        const u16 lo = f2b(r2);
        ph[c] = hi; pm[c] = mi; pl[c] = lo;
    }
    *(u16x4*)(out + i) = ph;
    *(u16x4*)(out + n + i) = pm;
    *(u16x4*)(out + 2 * n + i) = pl;
}

// ---------------------------------------------------------------------------
// transpose + convert, vectorized: in [Z][R][Cc] f32 -> out [Z][Cc][R] bf16
// ---------------------------------------------------------------------------
__global__ __launch_bounds__(256)
void tconv64_kernel(const float* __restrict__ in, u16* __restrict__ out, int R, int Cc) {
    __shared__ u16 tile[64][68];
    const int z = blockIdx.z;
    const int r0 = blockIdx.y * 64, c0 = blockIdx.x * 64;
    const int tr = threadIdx.x >> 4;          // 0..15
    const int tc4 = (threadIdx.x & 15) * 4;   // 0..60
    const float* ip = in + (size_t)z * R * Cc;
#pragma unroll
    for (int i = 0; i < 4; ++i) {
        const int row = tr + i * 16;
        const float4 v = *(const float4*)(ip + (size_t)(r0 + row) * Cc + c0 + tc4);
        u16x4 w;
        w[0] = f2b(v.x); w[1] = f2b(v.y); w[2] = f2b(v.z); w[3] = f2b(v.w);
        *(u16x4*)(&tile[row][tc4]) = w;
    }
    __syncthreads();
    u16* op = out + (size_t)z * R * Cc;
#pragma unroll
    for (int i = 0; i < 4; ++i) {
        const int orow = tr + i * 16;
        u16x4 w;
#pragma unroll
        for (int j = 0; j < 4; ++j) w[j] = tile[tc4 + j][orow];
        *(u16x4*)(op + (size_t)(c0 + orow) * R + r0 + tc4) = w;
    }
}

// ---------------------------------------------------------------------------
// V-plane transpose: vh/vl [Tt][Dd] (per bh: [s][64]) -> vth/vtl [bh][64][Ss]
// ---------------------------------------------------------------------------
__global__ __launch_bounds__(256)
void vtrans_kernel(const u16* __restrict__ vh, const u16* __restrict__ vl,
                   u16* __restrict__ vth, u16* __restrict__ vtl) {
    __shared__ u16 th[32][33], tl[32][33];
    const int bh = blockIdx.z, d0 = blockIdx.y * 32, s0 = blockIdx.x * 32;
    const int bb = bh >> 4, hh = bh & 15;
    const int tr = threadIdx.x >> 5, tc = threadIdx.x & 31;
#pragma unroll
    for (int i = 0; i < 4; ++i) {
        const size_t src = (size_t)(bb * Ss + s0 + tr + i * 8) * Dd + hh * HD + d0 + tc;
        th[tr + i * 8][tc] = vh[src];
        tl[tr + i * 8][tc] = vl[src];
    }
    __syncthreads();
#pragma unroll
    for (int i = 0; i < 4; ++i) {
        const size_t dst = ((size_t)bh * HD + d0 + tr + i * 8) * Ss + s0 + tc;
        vth[dst] = th[tc][tr + i * 8];
        vtl[dst] = tl[tc][tr + i * 8];
    }
}

// ---------------------------------------------------------------------------
// 3-split MFMA BT-GEMM v3 (routing path): 128x256 tile, BK=32, 8 waves (2x4),
// acc[4][4]/wave (m93 ratio), double-buffered 144KiB LDS, counted vmcnt(9).
// Per-acc MFMA chain BIT-IDENTICAL to validated gemm_gl (kt asc, bp-major).
// MODE: 2 f32 out, 3 QKV split-plane out.
// ---------------------------------------------------------------------------
template <int MODE>
__global__ __launch_bounds__(512)
void gemm_x3b(const u16* __restrict__ A, const u16* __restrict__ Bt, void* __restrict__ Cout,
              const float* __restrict__ bias, int M, int N, int K,
              size_t psA, size_t psB,
              u16* __restrict__ qh, u16* __restrict__ ql,
              u16* __restrict__ kh, u16* __restrict__ kl,
              u16* __restrict__ vh, u16* __restrict__ vl) {
    // per buf: A 3 planes x 128x32 (4096 u16) + B 3 planes x 256x32 (8192 u16)
    __shared__ u16 lds[2 * 36864];   // 144 KiB
    const int tid = threadIdx.x, lane = tid & 63, wid = tid >> 6;
    const int wm = wid >> 2, wn = wid & 3;   // 2 x 4 waves: 64-row x 64-col each
    const int lr = lane & 15, lg = lane >> 4;
    const int m0 = blockIdx.y * 128, n0 = blockIdx.x * 256;

    // 72 staging segs per K-step (A: 3x8, B: 3x16), 9 per wave.
    const u16* gsrc[9];
    int ldof[9];
#pragma unroll
    for (int c = 0; c < 9; ++c) {
        const int g = wid * 9 + c;
        int p, seg, base;
        const u16* mat;
        size_t rowb;
        if (g < 24) { p = g >> 3; seg = g & 7;  mat = A;  rowb = (size_t)(m0 + seg * 16 + (lane >> 2)) * K; base = p * 4096;          mat += p * psA; }
        else { const int gb = g - 24; p = gb >> 4; seg = gb & 15; mat = Bt; rowb = (size_t)(n0 + seg * 16 + (lane >> 2)) * K; base = 12288 + p * 8192; mat += p * psB; }
        gsrc[c] = mat + rowb + (lane & 3) * 8;
        ldof[c] = base + seg * 512 + lane * 8;
    }

    f32x4 acc[4][4];
#pragma unroll
    for (int i = 0; i < 4; ++i)
#pragma unroll
        for (int j = 0; j < 4; ++j) acc[i][j] = zf4();

#define STAGE_X3B(b, kto)                                                      \
    {                                                                          \
        _Pragma("unroll")                                                      \
        for (int c = 0; c < 9; ++c)                                            \
            gl16(gsrc[c] + (kto), lds + (b) * 36864 + ldof[c]);                \
    }

#define COMPUTE_X3B(b)                                                         \
    {                                                                          \
        const u16* L = lds + (b) * 36864;                                      \
        short8 af[3][4];                                                       \
        _Pragma("unroll")                                                      \
        for (int p = 0; p < 3; ++p)                                            \
            _Pragma("unroll")                                                  \
            for (int i = 0; i < 4; ++i)                                        \
                af[p][i] = *(const short8*)(L + p * 4096 +                     \
                                            (wm * 64 + i * 16 + lr) * 32 + lg * 8); \
        _Pragma("unroll")                                                      \
        for (int bp = 0; bp < 3; ++bp) {                                       \
            short8 bf[4];                                                      \
            _Pragma("unroll")                                                  \
            for (int j = 0; j < 4; ++j)                                        \
                bf[j] = *(const short8*)(L + 12288 + bp * 8192 +               \
                                         (wn * 64 + j * 16 + lr) * 32 + lg * 8); \
            _Pragma("unroll")                                                  \
            for (int ap = 0; ap + bp < 3; ++ap)                                \
                _Pragma("unroll")                                              \
                for (int i = 0; i < 4; ++i)                                    \
                    _Pragma("unroll")                                          \
                    for (int j = 0; j < 4; ++j)                                \
                        acc[i][j] = __builtin_amdgcn_mfma_f32_16x16x32_bf16(   \
                            af[ap][i], bf[j], acc[i][j], 0, 0, 0);             \
        }                                                                      \
    }

    const int nt = K >> 5;
    STAGE_X3B(0, 0)
    for (int t = 0; t < nt - 1; ++t) {
        const int cur = t & 1;
        STAGE_X3B(cur ^ 1, (t + 1) * 32)
        asm volatile("s_waitcnt vmcnt(9)" ::: "memory");
        __builtin_amdgcn_s_barrier();
        COMPUTE_X3B(cur)
        asm volatile("s_waitcnt lgkmcnt(0)" ::: "memory");
        __builtin_amdgcn_s_barrier();
    }
    asm volatile("s_waitcnt vmcnt(0)" ::: "memory");
    __builtin_amdgcn_s_barrier();
    COMPUTE_X3B((nt - 1) & 1)

#undef STAGE_X3B
#undef COMPUTE_X3B

    const int r4 = lg * 4;
#pragma unroll
    for (int j = 0; j < 4; ++j) {
        const int col = n0 + wn * 64 + j * 16 + lr;
        const float bv = bias[col];
        const int region = col >> 10;   // MODE 3: 0=Q,1=K,2=V (uniform per wn)
#pragma unroll
        for (int i = 0; i < 4; ++i) {
#pragma unroll
            for (int r = 0; r < 4; ++r) {
                const int rowg = m0 + wm * 64 + i * 16 + r4 + r;
                float v = acc[i][j][r] + bv;
                if (MODE == 2) {
                    ((float*)Cout)[(size_t)rowg * N + col] = v;
                } else {
                    const size_t off = (size_t)rowg * Dd + (col & 1023);
                    if (region == 0) {
                        const float fs = v * 0.125f;
                        const u16 h = f2b(fs);
                        qh[off] = h; ql[off] = f2b(fs - b2f(h));
                    } else if (region == 1) {
                        const u16 h = f2b(v);
                        kh[off] = h; kl[off] = f2b(v - b2f(h));
                    } else {
                        const u16 h = f2b(v);
                        vh[off] = h; vl[off] = f2b(v - b2f(h));
                    }
                }
            }
        }
    }
}

// ---------------------------------------------------------------------------
// Expert GEMM, 256x256 tile, BK=64, 8 waves, double-buffered LDS,
// counted vmcnt(8) + XOR bank swizzle (128B rows were 16-way conflicted):
// linear LDS dest, inverse-swizzled per-lane SOURCE col, same XOR on reads.
// ---------------------------------------------------------------------------
template <int RELU>
__global__ __launch_bounds__(512)
void gemm_x2(const u16* __restrict__ A, const u16* __restrict__ Bt, u16* __restrict__ Cout,
             const float* __restrict__ bias, int M, int N, int K,
             size_t sA, size_t sB, size_t sC, int sBias) {
    __shared__ u16 lds[2][2][256 * 64];   // 128 KiB
    const int tid = threadIdx.x, lane = tid & 63, wid = tid >> 6;
    const int wm = wid >> 2, wn = wid & 3;
    const int lr = lane & 15, lg = lane >> 4;
    const int m0 = blockIdx.y * 256, n0 = blockIdx.x * 256;
    const int e = blockIdx.z;
    const u16* Ab = A + (size_t)e * sA;
    const u16* Bb = Bt + (size_t)e * sB;

    const int srow = wid * 8 + (lane >> 3);
    // swizzled source chunk: lane stages LDS chunk (lane&7) at row (..+lane>>3);
    // it must FETCH global chunk (lane&7) ^ ((lane>>3)&7).
    const int sscol = (((lane & 7) ^ ((lane >> 3) & 7))) * 8;

    f32x4 acc[8][4];
#pragma unroll
    for (int i = 0; i < 8; ++i)
#pragma unroll
        for (int j = 0; j < 4; ++j) acc[i][j] = zf4();

#define STAGE_X2(b, kt)                                                              \
    {                                                                                \
        _Pragma("unroll")                                                            \
        for (int c = 0; c < 4; ++c)                                                  \
            gl16(Ab + (size_t)(m0 + c * 64 + srow) * K + (kt) + sscol,               \
                 &lds[b][0][(c * 64 + srow) * 64 + (lane & 7) * 8]);                 \
        _Pragma("unroll")                                                            \
        for (int c = 0; c < 4; ++c)                                                  \
            gl16(Bb + (size_t)(n0 + c * 64 + srow) * K + (kt) + sscol,               \
                 &lds[b][1][(c * 64 + srow) * 64 + (lane & 7) * 8]);                 \
    }

#define COMPUTE_X2(b)                                                                \
    {                                                                                \
        _Pragma("unroll")                                                            \
        for (int ks = 0; ks < 2; ++ks) {                                             \
            short8 af[8], bf[4];                                                     \
            _Pragma("unroll")                                                        \
            for (int i = 0; i < 8; ++i)                                              \
                af[i] = *(const short8*)(&lds[b][0][(wm * 128 + i * 16 + lr) * 64 +  \
                                                    (((ks * 4 + lg) ^ (lr & 7)) * 8)]); \
            _Pragma("unroll")                                                        \
            for (int j = 0; j < 4; ++j)                                              \
                bf[j] = *(const short8*)(&lds[b][1][(wn * 64 + j * 16 + lr) * 64 +   \
                                                    (((ks * 4 + lg) ^ (lr & 7)) * 8)]); \
            _Pragma("unroll")                                                        \
            for (int i = 0; i < 8; ++i)                                              \
                _Pragma("unroll")                                                    \
                for (int j = 0; j < 4; ++j)                                          \
                    acc[i][j] = __builtin_amdgcn_mfma_f32_16x16x32_bf16(af[i], bf[j], acc[i][j], 0, 0, 0); \
        }                                                                            \
    }

    const int nt = K >> 6;
    STAGE_X2(0, 0)
    for (int t = 0; t < nt - 1; ++t) {
        const int cur = t & 1;
        STAGE_X2(cur ^ 1, (t + 1) * 64)
        asm volatile("s_waitcnt vmcnt(8)" ::: "memory");
        __builtin_amdgcn_s_barrier();
        COMPUTE_X2(cur)
        asm volatile("s_waitcnt lgkmcnt(0)" ::: "memory");
        __builtin_amdgcn_s_barrier();
    }
    asm volatile("s_waitcnt vmcnt(0)" ::: "memory");
    __builtin_amdgcn_s_barrier();
    COMPUTE_X2((nt - 1) & 1)

#undef STAGE_X2
#undef COMPUTE_X2

    const int r4 = lg * 4;
#pragma unroll
    for (int j = 0; j < 4; ++j) {
        const int col = n0 + wn * 64 + j * 16 + lr;
        const float bv = bias[(size_t)e * sBias + col];
#pragma unroll
        for (int i = 0; i < 8; ++i) {
#pragma unroll
            for (int r = 0; r < 4; ++r) {
                const int rowg = m0 + wm * 128 + i * 16 + r4 + r;
                float v = acc[i][j][r] + bv;
                if (RELU) v = fmaxf(v, 0.f);
                Cout[(size_t)e * sC + (size_t)rowg * N + col] = f2b(v);
            }
        }
    }
}

// ---------------------------------------------------------------------------
// Split-bf16 MFMA flash attention (UNCHANGED — bit-stable routing path)
// ---------------------------------------------------------------------------
__global__ __launch_bounds__(256)
void attn_mfma(const u16* __restrict__ qhp, const u16* __restrict__ qlp,
               const u16* __restrict__ khp, const u16* __restrict__ klp,
               const u16* __restrict__ vthp, const u16* __restrict__ vtlp,
               u16* __restrict__ os) {
    __shared__ u16 Khi[64 * 64], Klo[64 * 64];
    __shared__ u16 Vhi[64 * 64], Vlo[64 * 64];   // [d][kk]
    __shared__ u16 Phi[4][16 * 64], Plo[4][16 * 64];

    const int qt = blockIdx.x, bh = blockIdx.y;
    const int bb = bh >> 4, hh = bh & 15;
    const int tid = threadIdx.x, lane = tid & 63, wid = tid >> 6;
    const int lr = lane & 15, lg = lane >> 4;

    short8 qhi[2], qlo[2];
    {
        const size_t qbase = (size_t)(bb * Ss + qt * 64 + wid * 16 + lr) * Dd + hh * HD;
#pragma unroll
        for (int ks = 0; ks < 2; ++ks) {
            qhi[ks] = *(const short8*)(qhp + qbase + ks * 32 + lg * 8);
            qlo[ks] = *(const short8*)(qlp + qbase + ks * 32 + lg * 8);
        }
    }

    float mrun[4], lrun[4];
    f32x4 oacc[4];
#pragma unroll
    for (int r = 0; r < 4; ++r) { mrun[r] = -1e30f; lrun[r] = 0.f; }
#pragma unroll
    for (int nf = 0; nf < 4; ++nf) oacc[nf] = zf4();

    const int srow = tid >> 2;        // 0..63
    const int sd = (tid & 3) * 16;    // 0,16,32,48

    u16* const PhiW = Phi[wid];
    u16* const PloW = Plo[wid];

    for (int kt = 0; kt < Ss / 64; ++kt) {
        const size_t krow = (size_t)(bb * Ss + kt * 64 + srow) * Dd + hh * HD + sd;
        const short8 k0 = *(const short8*)(khp + krow);
        const short8 k1 = *(const short8*)(khp + krow + 8);
        const short8 l0 = *(const short8*)(klp + krow);
        const short8 l1 = *(const short8*)(klp + krow + 8);
        const size_t vrow = ((size_t)bh * HD + srow) * Ss + kt * 64 + sd;
        const short8 v0 = *(const short8*)(vthp + vrow);
        const short8 v1 = *(const short8*)(vthp + vrow + 8);
        const short8 w0 = *(const short8*)(vtlp + vrow);
        const short8 w1 = *(const short8*)(vtlp + vrow + 8);
        __syncthreads();
        *(short8*)(Khi + swzb(srow, sd)) = k0;
        *(short8*)(Khi + swzb(srow, sd + 8)) = k1;
        *(short8*)(Klo + swzb(srow, sd)) = l0;
        *(short8*)(Klo + swzb(srow, sd + 8)) = l1;
        *(short8*)(Vhi + swzb(srow, sd)) = v0;
        *(short8*)(Vhi + swzb(srow, sd + 8)) = v1;
        *(short8*)(Vlo + swzb(srow, sd)) = w0;
        *(short8*)(Vlo + swzb(srow, sd + 8)) = w1;
        __syncthreads();

        f32x4 sc[4];
#pragma unroll
        for (int nf = 0; nf < 4; ++nf) sc[nf] = zf4();
#pragma unroll
        for (int nf = 0; nf < 4; ++nf)
#pragma unroll
            for (int ks = 0; ks < 2; ++ks) {
                const short8 kh = *(const short8*)(Khi + swzb(nf * 16 + lr, ks * 32 + lg * 8));
                const short8 kl = *(const short8*)(Klo + swzb(nf * 16 + lr, ks * 32 + lg * 8));
                sc[nf] = __builtin_amdgcn_mfma_f32_16x16x32_bf16(qhi[ks], kh, sc[nf], 0, 0, 0);
                sc[nf] = __builtin_amdgcn_mfma_f32_16x16x32_bf16(qhi[ks], kl, sc[nf], 0, 0, 0);
                sc[nf] = __builtin_amdgcn_mfma_f32_16x16x32_bf16(qlo[ks], kh, sc[nf], 0, 0, 0);
                sc[nf] = __builtin_amdgcn_mfma_f32_16x16x32_bf16(qlo[ks], kl, sc[nf], 0, 0, 0);
            }

        float scl[4];
#pragma unroll
        for (int r = 0; r < 4; ++r) {
            float m = fmaxf(fmaxf(sc[0][r], sc[1][r]), fmaxf(sc[2][r], sc[3][r]));
            m = fmaxf(m, __shfl_xor(m, 1));
            m = fmaxf(m, __shfl_xor(m, 2));
            m = fmaxf(m, __shfl_xor(m, 4));
            m = fmaxf(m, __shfl_xor(m, 8));
            const float mn = fmaxf(mrun[r], m);
            scl[r] = __expf(mrun[r] - mn);
            mrun[r] = mn;
            float s = 0.f;
#pragma unroll
            for (int nf = 0; nf < 4; ++nf) {
                const float p = __expf(sc[nf][r] - mn);
                sc[nf][r] = p;
                s += p;
            }
            s += __shfl_xor(s, 1);
            s += __shfl_xor(s, 2);
            s += __shfl_xor(s, 4);
            s += __shfl_xor(s, 8);
            lrun[r] = lrun[r] * scl[r] + s;
        }

#pragma unroll
        for (int nf = 0; nf < 4; ++nf)
#pragma unroll
            for (int r = 0; r < 4; ++r) {
                const float p = sc[nf][r];
                const u16 h = f2b(p);
                const int idx = swzb(lg * 4 + r, nf * 16 + lr);
                PhiW[idx] = h;
                PloW[idx] = f2b(p - b2f(h));
            }

#pragma unroll
        for (int nf = 0; nf < 4; ++nf)
#pragma unroll
            for (int r = 0; r < 4; ++r) oacc[nf][r] *= scl[r];

#pragma unroll
        for (int ks = 0; ks < 2; ++ks) {
            const short8 ph = *(const short8*)(PhiW + swzb(lr, ks * 32 + lg * 8));
            const short8 pl = *(const short8*)(PloW + swzb(lr, ks * 32 + lg * 8));
#pragma unroll
            for (int nf = 0; nf < 4; ++nf) {
                const short8 vh = *(const short8*)(Vhi + swzb(nf * 16 + lr, ks * 32 + lg * 8));
                const short8 vl = *(const short8*)(Vlo + swzb(nf * 16 + lr, ks * 32 + lg * 8));
                oacc[nf] = __builtin_amdgcn_mfma_f32_16x16x32_bf16(ph, vh, oacc[nf], 0, 0, 0);
                oacc[nf] = __builtin_amdgcn_mfma_f32_16x16x32_bf16(ph, vl, oacc[nf], 0, 0, 0);
                oacc[nf] = __builtin_amdgcn_mfma_f32_16x16x32_bf16(pl, vh, oacc[nf], 0, 0, 0);
                oacc[nf] = __builtin_amdgcn_mfma_f32_16x16x32_bf16(pl, vl, oacc[nf], 0, 0, 0);
            }
        }
    }

#pragma unroll
    for (int r = 0; r < 4; ++r) {
        const float inv = 1.f / lrun[r];
        const size_t base = (size_t)(bb * Ss + qt * 64 + wid * 16 + lg * 4 + r) * Dd + hh * HD;
#pragma unroll
        for (int nf = 0; nf < 4; ++nf) {
            const float o = oacc[nf][r] * inv;
            const u16 h = f2b(o);
            const float r1 = o - b2f(h);
            const u16 m = f2b(r1);
            const u16 l = f2b(r1 - b2f(m));
            const size_t off = base + nf * 16 + lr;
            os[off] = h;
            os[PT + off] = m;
            os[2 * PT + off] = l;
        }
    }
}

// ---------------------------------------------------------------------------
DEVI double block_reduce_d(double v, double* sred, int tid) {
#pragma unroll
    for (int off = 32; off > 0; off >>= 1) v += __shfl_down(v, off);
    __syncthreads();
    if ((tid & 63) == 0) sred[tid >> 6] = v;
    __syncthreads();
    return sred[0] + sred[1] + sred[2] + sred[3];
}

// ---------------------------------------------------------------------------
// LN1: x1f = LN(x + aproj)
// ---------------------------------------------------------------------------
__global__ __launch_bounds__(256)
void ln1_kernel(const float* __restrict__ x, const float* __restrict__ ap,
                const float* __restrict__ g, const float* __restrict__ b,
                float* __restrict__ x1f) {
    __shared__ double sred[4];
    const int t = blockIdx.x, tid = threadIdx.x;
    const float4 xv = ((const float4*)(x + (size_t)t * Dd))[tid];
    const float4 av = ((const float4*)(ap + (size_t)t * Dd))[tid];
    const double v0 = (double)xv.x + (double)av.x;
    const double v1 = (double)xv.y + (double)av.y;
    const double v2 = (double)xv.z + (double)av.z;
    const double v3 = (double)xv.w + (double)av.w;
    const double s = block_reduce_d(v0 + v1 + v2 + v3, sred, tid);
    const double mean = s * (1.0 / Dd);
    const double c0 = v0 - mean, c1 = v1 - mean, c2 = v2 - mean, c3 = v3 - mean;
    const double s2 = block_reduce_d(c0 * c0 + c1 * c1 + c2 * c2 + c3 * c3, sred, tid);
    const double rstd = 1.0 / sqrt(s2 * (1.0 / Dd) + 1e-5);
    const float4 gv = ((const float4*)g)[tid];
    const float4 bv = ((const float4*)b)[tid];
    float4 ov;
    ov.x = (float)(c0 * rstd * (double)gv.x + (double)bv.x);
    ov.y = (float)(c1 * rstd * (double)gv.y + (double)bv.y);
    ov.z = (float)(c2 * rstd * (double)gv.z + (double)bv.z);
    ov.w = (float)(c3 * rstd * (double)gv.w + (double)bv.w);
    ((float4*)(x1f + (size_t)t * Dd))[tid] = ov;
}

// ---------------------------------------------------------------------------
// gating stage 1 (fp64)
// ---------------------------------------------------------------------------
__global__ __launch_bounds__(256)
void gate1_kernel(const float* __restrict__ x1f, const float* __restrict__ wg,
                  int* __restrict__ idx1, int* __restrict__ idx2,
                  float* __restrict__ gate1, float* __restrict__ gate2) {
    const int tid = threadIdx.x, lane = tid & 63, wid = tid >> 6;
    const int t = blockIdx.x * 4 + wid;
    double acc[16];
#pragma unroll
    for (int e = 0; e < 16; ++e) acc[e] = 0.0;
    for (int i = 0; i < 16; ++i) {
        const int d = i * 64 + lane;
        const double xv = (double)x1f[(size_t)t * Dd + d];
        const float4* wr = (const float4*)(wg + (size_t)d * 16);
        const float4 w0 = wr[0], w1 = wr[1], w2 = wr[2], w3 = wr[3];
        acc[0] += xv * (double)w0.x;  acc[1] += xv * (double)w0.y;
        acc[2] += xv * (double)w0.z;  acc[3] += xv * (double)w0.w;
        acc[4] += xv * (double)w1.x;  acc[5] += xv * (double)w1.y;
        acc[6] += xv * (double)w1.z;  acc[7] += xv * (double)w1.w;
        acc[8] += xv * (double)w2.x;  acc[9] += xv * (double)w2.y;
        acc[10] += xv * (double)w2.z; acc[11] += xv * (double)w2.w;
        acc[12] += xv * (double)w3.x; acc[13] += xv * (double)w3.y;
        acc[14] += xv * (double)w3.z; acc[15] += xv * (double)w3.w;
    }
#pragma unroll
    for (int e = 0; e < 16; ++e) {
        acc[e] += __shfl_xor(acc[e], 1);
        acc[e] += __shfl_xor(acc[e], 2);
        acc[e] += __shfl_xor(acc[e], 4);
        acc[e] += __shfl_xor(acc[e], 8);
        acc[e] += __shfl_xor(acc[e], 16);
        acc[e] += __shfl_xor(acc[e], 32);
    }
    if (lane == 0) {
        double mx = acc[0];
#pragma unroll
        for (int e = 1; e < 16; ++e) mx = fmax(mx, acc[e]);
        double z = 0.0, ex[16];
#pragma unroll
        for (int e = 0; e < 16; ++e) { ex[e] = exp(acc[e] - mx); z += ex[e]; }
        int b1 = 0; double v1 = acc[0];
#pragma unroll
        for (int e = 1; e < 16; ++e) if (acc[e] > v1) { v1 = acc[e]; b1 = e; }
        int b2 = (b1 == 0) ? 1 : 0; double v2 = acc[b2];
#pragma unroll
        for (int e = 0; e < 16; ++e) if (e != b1 && acc[e] > v2) { v2 = acc[e]; b2 = e; }
        const double rz = 1.0 / z;
        idx1[t] = b1; idx2[t] = b2;
        gate1[t] = (float)(ex[b1] * rz); gate2[t] = (float)(ex[b2] * rz);
    }
}

// ---------------------------------------------------------------------------
// gating stage 2 (single block)
// ---------------------------------------------------------------------------
__global__ __launch_bounds__(256)
void gate2_kernel(const int* __restrict__ idx1, const int* __restrict__ idx2,
                  const float* __restrict__ gate1, const float* __restrict__ gate2,
                  int* __restrict__ p1, int* __restrict__ p2,
                  int* __restrict__ k1, int* __restrict__ k2,
                  float* __restrict__ w1, float* __restrict__ w2) {
    __shared__ int hist[16];
    __shared__ unsigned long long sb1[4][16], sb2[4][16];
    __shared__ int sbase1[16], sbase2[16];
    const int tid = threadIdx.x, lane = tid & 63, wid = tid >> 6;
    if (tid < 16) hist[tid] = 0;
    __syncthreads();
    for (int t = tid; t < Tt; t += 256) atomicAdd(&hist[idx1[t]], 1);
    __syncthreads();
    if (tid < 16) { sbase1[tid] = 0; sbase2[tid] = hist[tid]; }
    __syncthreads();
    const unsigned long long below = (1ULL << lane) - 1ULL;
    for (int ch = 0; ch < Tt / 256; ++ch) {
        const int t = ch * 256 + tid;
        const int a = idx1[t], b = idx2[t];
#pragma unroll
        for (int e = 0; e < 16; ++e) {
            const unsigned long long m1 = __ballot(a == e);
            const unsigned long long m2 = __ballot(b == e);
            if (lane == 0) { sb1[wid][e] = m1; sb2[wid][e] = m2; }
        }
        __syncthreads();
        int r1 = __popcll(sb1[wid][a] & below);
        int r2 = __popcll(sb2[wid][b] & below);
#pragma unroll
        for (int w = 0; w < 4; ++w)
            if (w < wid) { r1 += __popcll(sb1[w][a]); r2 += __popcll(sb2[w][b]); }
        const int loc1 = sbase1[a] + r1, loc2 = sbase2[b] + r2;
        const int kk1 = loc1 < Cap, kk2 = loc2 < Cap;
        const float g1 = kk1 ? gate1[t] : 0.f;
        const float g2 = kk2 ? gate2[t] : 0.f;
        const float dn = fmaxf(g1 + g2, EPSc);
        p1[t] = kk1 ? loc1 : 0;
        p2[t] = kk2 ? loc2 : 0;
        k1[t] = kk1; k2[t] = kk2;
        w1[t] = g1 / dn; w2[t] = g2 / dn;
        __syncthreads();
        if (tid == 0) {
#pragma unroll
            for (int e = 0; e < 16; ++e) {
                int c1 = 0, c2 = 0;
#pragma unroll
                for (int w = 0; w < 4; ++w) { c1 += __popcll(sb1[w][e]); c2 += __popcll(sb2[w][e]); }
                sbase1[e] += c1; sbase2[e] += c2;
            }
        }
        __syncthreads();
    }
}

// ---------------------------------------------------------------------------
// dispatch: scatter kept tokens (f32 -> bf16) into [E,C,D] buffers (pre-zeroed)
// ---------------------------------------------------------------------------
__global__ __launch_bounds__(256)
void dispatch_kernel(const float* __restrict__ x1f,
                     const int* __restrict__ i1, const int* __restrict__ p1, const int* __restrict__ k1,
                     const int* __restrict__ i2, const int* __restrict__ p2, const int* __restrict__ k2,
                     u16* __restrict__ buf) {
    const int t = blockIdx.x, tid = threadIdx.x;
    const float4 v = ((const float4*)(x1f + (size_t)t * Dd))[tid];
    u16x4 pw;
    pw[0] = f2b(v.x); pw[1] = f2b(v.y); pw[2] = f2b(v.z); pw[3] = f2b(v.w);
    if (k1[t]) *(u16x4*)(buf + ((size_t)i1[t] * Cap + p1[t]) * Dd + tid * 4) = pw;
    if (k2[t]) *(u16x4*)(buf + ((size_t)i2[t] * Cap + p2[t]) * Dd + tid * 4) = pw;
}

// ---------------------------------------------------------------------------
// combine + residual + LN2 -> d_out (f32)
// ---------------------------------------------------------------------------
__global__ __launch_bounds__(256)
void combine_ln2(const float* __restrict__ x1f, const u16* __restrict__ y,
                 const int* __restrict__ i1, const int* __restrict__ p1, const float* __restrict__ w1,
                 const int* __restrict__ i2, const int* __restrict__ p2, const float* __restrict__ w2,
                 const float* __restrict__ g, const float* __restrict__ b,
                 float* __restrict__ out) {
    __shared__ double sred[4];
    const int t = blockIdx.x, tid = threadIdx.x;
    const size_t r1 = ((size_t)i1[t] * Cap + p1[t]) * Dd;
    const size_t r2 = ((size_t)i2[t] * Cap + p2[t]) * Dd;
    const double a1 = (double)w1[t], a2 = (double)w2[t];
    const u16x4 y1 = *(const u16x4*)(y + r1 + tid * 4);
    const u16x4 y2 = *(const u16x4*)(y + r2 + tid * 4);
    const float4 xv = ((const float4*)(x1f + (size_t)t * Dd))[tid];
    const double v0 = (double)xv.x + a1 * (double)b2f(y1[0]) + a2 * (double)b2f(y2[0]);
    const double v1 = (double)xv.y + a1 * (double)b2f(y1[1]) + a2 * (double)b2f(y2[1]);
    const double v2 = (double)xv.z + a1 * (double)b2f(y1[2]) + a2 * (double)b2f(y2[2]);
    const double v3 = (double)xv.w + a1 * (double)b2f(y1[3]) + a2 * (double)b2f(y2[3]);
    const double s = block_reduce_d(v0 + v1 + v2 + v3, sred, tid);
    const double mean = s * (1.0 / Dd);
    const double c0 = v0 - mean, c1 = v1 - mean, c2 = v2 - mean, c3 = v3 - mean;
    const double s2 = block_reduce_d(c0 * c0 + c1 * c1 + c2 * c2 + c3 * c3, sred, tid);
    const double rstd = 1.0 / sqrt(s2 * (1.0 / Dd) + 1e-5);
    const float4 gv = ((const float4*)g)[tid];
    const float4 bv = ((const float4*)b)[tid];
    float4 ov;
    ov.x = (float)(c0 * rstd * (double)gv.x + (double)bv.x);
    ov.y = (float)(c1 * rstd * (double)gv.y + (double)bv.y);
    ov.z = (float)(c2 * rstd * (double)gv.z + (double)bv.z);
    ov.w = (float)(c3 * rstd * (double)gv.w + (double)bv.w);
    ((float4*)(out + (size_t)t * Dd))[tid] = ov;
}

// ---------------------------------------------------------------------------
extern "C" void kernel_launch(void* const* d_in, const int* in_sizes, int n_in,
                              void* d_out, int out_size, void* d_ws, size_t ws_size,
                              hipStream_t stream) {
    (void)in_sizes; (void)n_in; (void)out_size; (void)ws_size;
    const float* x    = (const float*)d_in[0];
    const float* inW  = (const float*)d_in[1];
    const float* inB  = (const float*)d_in[2];
    const float* outW = (const float*)d_in[3];
    const float* outB = (const float*)d_in[4];
    const float* ln1g = (const float*)d_in[5];
    const float* ln1b = (const float*)d_in[6];
    const float* ln2g = (const float*)d_in[7];
    const float* ln2b = (const float*)d_in[8];
    const float* wg   = (const float*)d_in[9];
    const float* w1   = (const float*)d_in[10];
    const float* b1   = (const float*)d_in[11];
    const float* w2   = (const float*)d_in[12];
    const float* b2   = (const float*)d_in[13];
    float* out = (float*)d_out;

    char* ws = (char*)d_ws;
    const size_t MB = 1024 * 1024;
    // ---- phase-overlapped arena (verified layout, peak 352.4 MiB) ----
    u16*   xs3   = (u16*)(ws + 0);          // [0,48)    dead after QKV gemm
    u16*   inW3  = (u16*)(ws + 48 * MB);    // [48,66)   dead after QKV gemm
    u16*   qh    = (u16*)(ws + 66 * MB);    // [66,82)   dead after attn
    u16*   ql    = (u16*)(ws + 82 * MB);    // [82,98)   dead after attn
    u16*   kh    = (u16*)(ws + 98 * MB);    // [98,114)  dead after attn
    u16*   kl    = (u16*)(ws + 114 * MB);   // [114,130) dead after attn
    u16*   vh    = (u16*)(ws + 130 * MB);   // [130,146) dead after vtrans
    u16*   vl    = (u16*)(ws + 146 * MB);   // [146,162) dead after vtrans
    u16*   vth   = (u16*)(ws + 162 * MB);   // [162,178) dead after attn
    u16*   vtl   = (u16*)(ws + 178 * MB);   // [178,194) dead after attn
    u16*   os3   = (u16*)(ws + 194 * MB);   // [194,242) attn out, dead after OP
    u16*   outW3 = (u16*)(ws + 0);          // [0,6)     over dead xs3, dead after OP
    float* aproj = (float*)(ws + 6 * MB);   // [6,38)    over dead xs3, dead after LN1
    u16*   wt    = (u16*)(ws + 0);          // [0,128)   written post-LN1 (all dead)
    u16*   hbuf  = (u16*)(ws + 128 * MB);   // [128,256) over dead kl-tail/v*/os3
    u16*   ybuf  = (u16*)(ws + 256 * MB);   // [256,288) fresh
    u16*   ebuf  = (u16*)(ws + 288 * MB);   // [288,320) fresh
    float* x1f   = (float*)(ws + 320 * MB); // [320,352) fresh, live till end
    char*  gbase = ws + 352 * MB;           // [352,~352.4) gating arrays
    int*   idx1 = (int*)(gbase + 0 * Tt * 4);
    int*   idx2 = (int*)(gbase + 1 * Tt * 4);
    float* gt1  = (float*)(gbase + 2 * Tt * 4);
    float* gt2  = (float*)(gbase + 3 * Tt * 4);
    int*   p1   = (int*)(gbase + 4 * Tt * 4);
    int*   p2   = (int*)(gbase + 5 * Tt * 4);
    int*   k1   = (int*)(gbase + 6 * Tt * 4);
    int*   k2   = (int*)(gbase + 7 * Tt * 4);
    float* w1c  = (float*)(gbase + 8 * Tt * 4);
    float* w2c  = (float*)(gbase + 9 * Tt * 4);

    const long long nTD = (long long)Tt * Dd;
    const long long nW1 = (long long)D3 * Dd;
    const long long nW2 = (long long)Dd * Dd;

    // 1: split inputs; QKV GEMM (gemm_x3b, bit-identical chain) writes split planes
    split3_kernel<<<(int)(nTD / 1024), 256, 0, stream>>>(x, xs3, nTD);
    split3_kernel<<<(int)(nW1 / 1024), 256, 0, stream>>>(inW, inW3, nW1);
    gemm_x3b<3><<<dim3(D3 / 256, Tt / 128, 1), 512, 0, stream>>>(
        xs3, inW3, nullptr, inB, Tt, D3, Dd, (size_t)nTD, (size_t)nW1,
        qh, ql, kh, kl, vh, vl);
    // 2: V transpose; attention (bit-identical), writes os3 planes
    vtrans_kernel<<<dim3(Ss / 32, HD / 32, Bz * Hh), 256, 0, stream>>>(vh, vl, vth, vtl);
    attn_mfma<<<dim3(Ss / 64, Bz * Hh), 256, 0, stream>>>(qh, ql, kh, kl, vth, vtl, os3);
    // 3: out-proj (gemm_x3b, f32 out)
    split3_kernel<<<(int)(nW2 / 1024), 256, 0, stream>>>(outW, outW3, nW2);
    gemm_x3b<2><<<dim3(Dd / 256, Tt / 128, 1), 512, 0, stream>>>(
        os3, outW3, aproj, outB, Tt, Dd, Dd, (size_t)nTD, (size_t)nW2,
        nullptr, nullptr, nullptr, nullptr, nullptr, nullptr);
    // 4: LN1
    ln1_kernel<<<Tt, 256, 0, stream>>>(x, aproj, ln1g, ln1b, x1f);
    // 5-6: gating
    gate1_kernel<<<Tt / 4, 256, 0, stream>>>(x1f, wg, idx1, idx2, gt1, gt2);
    gate2_kernel<<<1, 256, 0, stream>>>(idx1, idx2, gt1, gt2, p1, p2, k1, k2, w1c, w2c);
    // 7: dispatch
    hipMemsetAsync(ebuf, 0, (size_t)Ee * Cap * Dd * 2, stream);
    dispatch_kernel<<<Tt, 256, 0, stream>>>(x1f, idx1, p1, k1, idx2, p2, k2, ebuf);
    // 8-11: expert FFN — 256^2 dbuf counted-vmcnt GEMMs + bank swizzle
    tconv64_kernel<<<dim3(DFF / 64, Dd / 64, Ee), 256, 0, stream>>>(w1, wt, Dd, DFF);
    gemm_x2<1><<<dim3(DFF / 256, Cap / 256, Ee), 512, 0, stream>>>(
        ebuf, wt, hbuf, b1, Cap, DFF, Dd,
        (size_t)Cap * Dd, (size_t)DFF * Dd, (size_t)Cap * DFF, DFF);
    tconv64_kernel<<<dim3(Dd / 64, DFF / 64, Ee), 256, 0, stream>>>(w2, wt, DFF, Dd);
    gemm_x2<0><<<dim3(Dd / 256, Cap / 256, Ee), 512, 0, stream>>>(
        hbuf, wt, ybuf, b2, Cap, Dd, DFF,
        (size_t)Cap * DFF, (size_t)Dd * DFF, (size_t)Cap * Dd, Dd);
    // 12: combine + residual + LN2
    combine_ln2<<<Tt, 256, 0, stream>>>(x1f, ybuf, idx1, p1, w1c, idx2, p2, w2c, ln2g, ln2b, out);
}

// Round 10
// 1272.937 us; speedup vs baseline: 2.3273x; 1.0374x over previous
//
#include <hip/hip_runtime.h>
#include <cstdint>

#define DEVI __device__ __forceinline__

typedef short short8 __attribute__((ext_vector_type(8)));
typedef float f32x4 __attribute__((ext_vector_type(4)));
typedef unsigned short u16;
typedef u16 u16x4 __attribute__((ext_vector_type(4)));

static constexpr int Bz = 8, Ss = 1024, Dd = 1024, Hh = 16, HD = 64, DFF = 4096, Ee = 16;
static constexpr int Tt = Bz * Ss;           // 8192 tokens
static constexpr int Cap = (2 * Tt) / Ee;    // 1024 capacity
static constexpr int D3 = 3 * Dd;            // 3072
static constexpr float EPSc = 1.1920929e-07f;
static constexpr size_t PT = (size_t)Tt * Dd;   // plane elements (token-major)

DEVI u16 f2b(float f) {
    union { float f; uint32_t u; } v; v.f = f;
    return (u16)((v.u + 0x7FFFu + ((v.u >> 16) & 1u)) >> 16);
}
DEVI float b2f(u16 h) {
    union { uint32_t u; float f; } v; v.u = ((uint32_t)h) << 16; return v.f;
}
DEVI f32x4 zf4() { f32x4 v; v[0] = 0.f; v[1] = 0.f; v[2] = 0.f; v[3] = 0.f; return v; }

// async global->LDS, 16B per lane. LDS dest must be wave-uniform base + lane*16B.
DEVI void gl16(const u16* g, u16* l) {
    __builtin_amdgcn_global_load_lds(
        (const __attribute__((address_space(1))) void*)g,
        (__attribute__((address_space(3))) void*)l, 16, 0, 0);
}

// swizzled u16 index for [R][64] bf16 tiles (128B rows): byte ^= (row&7)<<4
DEVI int swzb(int row, int col) {
    int byte = (row * 64 + col) * 2;
    byte ^= (row & 7) << 4;
    return byte >> 1;
}

// ---------------------------------------------------------------------------
// split fp32 -> 3 bf16 planes (hi/mid/lo), plane stride = n. n % 1024 == 0.
// ---------------------------------------------------------------------------
__global__ __launch_bounds__(256)
void split3_kernel(const float* __restrict__ in, u16* __restrict__ out, long long n) {
    const long long i = ((long long)blockIdx.x * 256 + threadIdx.x) * 4;
    if (i >= n) return;
    const float4 v = *(const float4*)(in + i);
    const float f[4] = {v.x, v.y, v.z, v.w};
    u16x4 ph, pm, pl;
#pragma unroll
    for (int c = 0; c < 4; ++c) {
        const u16 hi = f2b(f[c]);
        const float r1 = f[c] - b2f(hi);     // exact
        const u16 mi = f2b(r1);
        const float r2 = r1 - b2f(mi);       // exact
        const u16 lo = f2b(r2);
        ph[c] = hi; pm[c] = mi; pl[c] = lo;
    }
    *(u16x4*)(out + i) = ph;
    *(u16x4*)(out + n + i) = pm;
    *(u16x4*)(out + 2 * n + i) = pl;
}

// ---------------------------------------------------------------------------
// transpose + convert, vectorized: in [Z][R][Cc] f32 -> out [Z][Cc][R] bf16
// ---------------------------------------------------------------------------
__global__ __launch_bounds__(256)
void tconv64_kernel(const float* __restrict__ in, u16* __restrict__ out, int R, int Cc) {
    __shared__ u16 tile[64][68];
    const int z = blockIdx.z;
    const int r0 = blockIdx.y * 64, c0 = blockIdx.x * 64;
    const int tr = threadIdx.x >> 4;          // 0..15
    const int tc4 = (threadIdx.x & 15) * 4;   // 0..60
    const float* ip = in + (size_t)z * R * Cc;
#pragma unroll
    for (int i = 0; i < 4; ++i) {
        const int row = tr + i * 16;
        const float4 v = *(const float4*)(ip + (size_t)(r0 + row) * Cc + c0 + tc4);
        u16x4 w;
        w[0] = f2b(v.x); w[1] = f2b(v.y); w[2] = f2b(v.z); w[3] = f2b(v.w);
        *(u16x4*)(&tile[row][tc4]) = w;
    }
    __syncthreads();
    u16* op = out + (size_t)z * R * Cc;
#pragma unroll
    for (int i = 0; i < 4; ++i) {
        const int orow = tr + i * 16;
        u16x4 w;
#pragma unroll
        for (int j = 0; j < 4; ++j) w[j] = tile[tc4 + j][orow];
        *(u16x4*)(op + (size_t)(c0 + orow) * R + r0 + tc4) = w;
    }
}

// ---------------------------------------------------------------------------
// V-plane transpose: vh/vl [Tt][Dd] (per bh: [s][64]) -> vth/vtl [bh][64][Ss]
// ---------------------------------------------------------------------------
__global__ __launch_bounds__(256)
void vtrans_kernel(const u16* __restrict__ vh, const u16* __restrict__ vl,
                   u16* __restrict__ vth, u16* __restrict__ vtl) {
    __shared__ u16 th[32][33], tl[32][33];
    const int bh = blockIdx.z, d0 = blockIdx.y * 32, s0 = blockIdx.x * 32;
    const int bb = bh >> 4, hh = bh & 15;
    const int tr = threadIdx.x >> 5, tc = threadIdx.x & 31;
#pragma unroll
    for (int i = 0; i < 4; ++i) {
        const size_t src = (size_t)(bb * Ss + s0 + tr + i * 8) * Dd + hh * HD + d0 + tc;
        th[tr + i * 8][tc] = vh[src];
        tl[tr + i * 8][tc] = vl[src];
    }
    __syncthreads();
#pragma unroll
    for (int i = 0; i < 4; ++i) {
        const size_t dst = ((size_t)bh * HD + d0 + tr + i * 8) * Ss + s0 + tc;
        vth[dst] = th[tc][tr + i * 8];
        vtl[dst] = tl[tc][tr + i * 8];
    }
}

// ---------------------------------------------------------------------------
// 3-split MFMA BT-GEMM, PHASED (routing path): 128x256 tile, BK=32, 8 waves,
// dbuf 144KiB. Per K-step: stages front-loaded, then 3 phases (one per B-plane)
// each {ds_read, barrier, lgkm(0), setprio MFMA cluster, barrier}; boundary
// vmcnt(0)+barrier. Per-acc MFMA chain BIT-IDENTICAL to validated gemm_gl
// (kt ascending, bp-major, ap ascending). MODE: 2 f32 out, 3 QKV planes out.
// ---------------------------------------------------------------------------
template <int MODE>
__global__ __launch_bounds__(512)
void gemm_x3p(const u16* __restrict__ A, const u16* __restrict__ Bt, void* __restrict__ Cout,
              const float* __restrict__ bias, int M, int N, int K,
              size_t psA, size_t psB,
              u16* __restrict__ qh, u16* __restrict__ ql,
              u16* __restrict__ kh, u16* __restrict__ kl,
              u16* __restrict__ vh, u16* __restrict__ vl) {
    // per buf: A 3 planes x 128x32 (4096 u16 each) + B 3 planes x 256x32 (8192 u16)
    __shared__ u16 lds[2 * 36864];   // 144 KiB
    const int tid = threadIdx.x, lane = tid & 63, wid = tid >> 6;
    const int wm = wid >> 2, wn = wid & 3;   // 2 x 4 waves: 64-row x 64-col each
    const int lr = lane & 15, lg = lane >> 4;
    const int m0 = blockIdx.y * 128, n0 = blockIdx.x * 256;

    // 72 staging segs per K-step (A: 3x8, B: 3x16), 9 per wave.
    const u16* gsrc[9];
    int ldof[9];
#pragma unroll
    for (int c = 0; c < 9; ++c) {
        const int g = wid * 9 + c;
        int p, seg, base;
        const u16* mat;
        size_t rowb;
        if (g < 24) { p = g >> 3; seg = g & 7;  mat = A;  rowb = (size_t)(m0 + seg * 16 + (lane >> 2)) * K; base = p * 4096;          mat += p * psA; }
        else { const int gb = g - 24; p = gb >> 4; seg = gb & 15; mat = Bt; rowb = (size_t)(n0 + seg * 16 + (lane >> 2)) * K; base = 12288 + p * 8192; mat += p * psB; }
        gsrc[c] = mat + rowb + (lane & 3) * 8;
        ldof[c] = base + seg * 512 + lane * 8;
    }

    f32x4 acc[4][4];
#pragma unroll
    for (int i = 0; i < 4; ++i)
#pragma unroll
        for (int j = 0; j < 4; ++j) acc[i][j] = zf4();

#define STAGE_P(b, kto)                                                        \
    {                                                                          \
        _Pragma("unroll")                                                      \
        for (int c = 0; c < 9; ++c)                                            \
            gl16(gsrc[c] + (kto), lds + (b) * 36864 + ldof[c]);                \
    }

    const int nt = K >> 5;
    STAGE_P(0, 0)
    asm volatile("s_waitcnt vmcnt(0)" ::: "memory");
    __builtin_amdgcn_s_barrier();

    for (int t = 0; t < nt; ++t) {
        const int cur = t & 1;
        const u16* L = lds + cur * 36864;
        if (t < nt - 1) STAGE_P(cur ^ 1, (t + 1) * 32)

        short8 af[3][4], bf[4];
        // ---- Phase 0: all A planes + B plane 0; MFMA bp=0 (ap 0,1,2) ----
#pragma unroll
        for (int p = 0; p < 3; ++p)
#pragma unroll
            for (int i = 0; i < 4; ++i)
                af[p][i] = *(const short8*)(L + p * 4096 + (wm * 64 + i * 16 + lr) * 32 + lg * 8);
#pragma unroll
        for (int j = 0; j < 4; ++j)
            bf[j] = *(const short8*)(L + 12288 + (wn * 64 + j * 16 + lr) * 32 + lg * 8);
        __builtin_amdgcn_s_barrier();
        asm volatile("s_waitcnt lgkmcnt(0)" ::: "memory");
        __builtin_amdgcn_s_setprio(1);
#pragma unroll
        for (int ap = 0; ap < 3; ++ap)
#pragma unroll
            for (int i = 0; i < 4; ++i)
#pragma unroll
                for (int j = 0; j < 4; ++j)
                    acc[i][j] = __builtin_amdgcn_mfma_f32_16x16x32_bf16(af[ap][i], bf[j], acc[i][j], 0, 0, 0);
        __builtin_amdgcn_s_setprio(0);
        __builtin_amdgcn_s_barrier();

        // ---- Phase 1: B plane 1; MFMA bp=1 (ap 0,1) ----
#pragma unroll
        for (int j = 0; j < 4; ++j)
            bf[j] = *(const short8*)(L + 12288 + 8192 + (wn * 64 + j * 16 + lr) * 32 + lg * 8);
        __builtin_amdgcn_s_barrier();
        asm volatile("s_waitcnt lgkmcnt(0)" ::: "memory");
        __builtin_amdgcn_s_setprio(1);
#pragma unroll
        for (int ap = 0; ap < 2; ++ap)
#pragma unroll
            for (int i = 0; i < 4; ++i)
#pragma unroll
                for (int j = 0; j < 4; ++j)
                    acc[i][j] = __builtin_amdgcn_mfma_f32_16x16x32_bf16(af[ap][i], bf[j], acc[i][j], 0, 0, 0);
        __builtin_amdgcn_s_setprio(0);
        __builtin_amdgcn_s_barrier();

        // ---- Phase 2: B plane 2; MFMA bp=2 (ap 0) ----
#pragma unroll
        for (int j = 0; j < 4; ++j)
            bf[j] = *(const short8*)(L + 12288 + 16384 + (wn * 64 + j * 16 + lr) * 32 + lg * 8);
        __builtin_amdgcn_s_barrier();
        asm volatile("s_waitcnt lgkmcnt(0)" ::: "memory");
        __builtin_amdgcn_s_setprio(1);
#pragma unroll
        for (int i = 0; i < 4; ++i)
#pragma unroll
            for (int j = 0; j < 4; ++j)
                acc[i][j] = __builtin_amdgcn_mfma_f32_16x16x32_bf16(af[0][i], bf[j], acc[i][j], 0, 0, 0);
        __builtin_amdgcn_s_setprio(0);
        __builtin_amdgcn_s_barrier();

        // ---- boundary: next buffer staged & visible ----
        if (t < nt - 1) asm volatile("s_waitcnt vmcnt(0)" ::: "memory");
        __builtin_amdgcn_s_barrier();
    }
#undef STAGE_P

    const int r4 = lg * 4;
#pragma unroll
    for (int j = 0; j < 4; ++j) {
        const int col = n0 + wn * 64 + j * 16 + lr;
        const float bv = bias[col];
        const int region = col >> 10;   // MODE 3: 0=Q,1=K,2=V (uniform per wn)
#pragma unroll
        for (int i = 0; i < 4; ++i) {
#pragma unroll
            for (int r = 0; r < 4; ++r) {
                const int rowg = m0 + wm * 64 + i * 16 + r4 + r;
                float v = acc[i][j][r] + bv;
                if (MODE == 2) {
                    ((float*)Cout)[(size_t)rowg * N + col] = v;
                } else {
                    const size_t off = (size_t)rowg * Dd + (col & 1023);
                    if (region == 0) {
                        const float fs = v * 0.125f;
                        const u16 h = f2b(fs);
                        qh[off] = h; ql[off] = f2b(fs - b2f(h));
                    } else if (region == 1) {
                        const u16 h = f2b(v);
                        kh[off] = h; kl[off] = f2b(v - b2f(h));
                    } else {
                        const u16 h = f2b(v);
                        vh[off] = h; vl[off] = f2b(v - b2f(h));
                    }
                }
            }
        }
    }
}

// ---------------------------------------------------------------------------
// Expert GEMM, 256x256 tile, BK=64, 8 waves, double-buffered LDS,
// counted vmcnt(8) + XOR bank swizzle (validated round 9).
// ---------------------------------------------------------------------------
template <int RELU>
__global__ __launch_bounds__(512)
void gemm_x2(const u16* __restrict__ A, const u16* __restrict__ Bt, u16* __restrict__ Cout,
             const float* __restrict__ bias, int M, int N, int K,
             size_t sA, size_t sB, size_t sC, int sBias) {
    __shared__ u16 lds[2][2][256 * 64];   // 128 KiB
    const int tid = threadIdx.x, lane = tid & 63, wid = tid >> 6;
    const int wm = wid >> 2, wn = wid & 3;
    const int lr = lane & 15, lg = lane >> 4;
    const int m0 = blockIdx.y * 256, n0 = blockIdx.x * 256;
    const int e = blockIdx.z;
    const u16* Ab = A + (size_t)e * sA;
    const u16* Bb = Bt + (size_t)e * sB;

    const int srow = wid * 8 + (lane >> 3);
    const int sscol = (((lane & 7) ^ ((lane >> 3) & 7))) * 8;

    f32x4 acc[8][4];
#pragma unroll
    for (int i = 0; i < 8; ++i)
#pragma unroll
        for (int j = 0; j < 4; ++j) acc[i][j] = zf4();

#define STAGE_X2(b, kt)                                                              \
    {                                                                                \
        _Pragma("unroll")                                                            \
        for (int c = 0; c < 4; ++c)                                                  \
            gl16(Ab + (size_t)(m0 + c * 64 + srow) * K + (kt) + sscol,               \
                 &lds[b][0][(c * 64 + srow) * 64 + (lane & 7) * 8]);                 \
        _Pragma("unroll")                                                            \
        for (int c = 0; c < 4; ++c)                                                  \
            gl16(Bb + (size_t)(n0 + c * 64 + srow) * K + (kt) + sscol,               \
                 &lds[b][1][(c * 64 + srow) * 64 + (lane & 7) * 8]);                 \
    }

#define COMPUTE_X2(b)                                                                \
    {                                                                                \
        _Pragma("unroll")                                                            \
        for (int ks = 0; ks < 2; ++ks) {                                             \
            short8 af[8], bf[4];                                                     \
            _Pragma("unroll")                                                        \
            for (int i = 0; i < 8; ++i)                                              \
                af[i] = *(const short8*)(&lds[b][0][(wm * 128 + i * 16 + lr) * 64 +  \
                                                    (((ks * 4 + lg) ^ (lr & 7)) * 8)]); \
            _Pragma("unroll")                                                        \
            for (int j = 0; j < 4; ++j)                                              \
                bf[j] = *(const short8*)(&lds[b][1][(wn * 64 + j * 16 + lr) * 64 +   \
                                                    (((ks * 4 + lg) ^ (lr & 7)) * 8)]); \
            _Pragma("unroll")                                                        \
            for (int i = 0; i < 8; ++i)                                              \
                _Pragma("unroll")                                                    \
                for (int j = 0; j < 4; ++j)                                          \
                    acc[i][j] = __builtin_amdgcn_mfma_f32_16x16x32_bf16(af[i], bf[j], acc[i][j], 0, 0, 0); \
        }                                                                            \
    }

    const int nt = K >> 6;
    STAGE_X2(0, 0)
    for (int t = 0; t < nt - 1; ++t) {
        const int cur = t & 1;
        STAGE_X2(cur ^ 1, (t + 1) * 64)
        asm volatile("s_waitcnt vmcnt(8)" ::: "memory");
        __builtin_amdgcn_s_barrier();
        COMPUTE_X2(cur)
        asm volatile("s_waitcnt lgkmcnt(0)" ::: "memory");
        __builtin_amdgcn_s_barrier();
    }
    asm volatile("s_waitcnt vmcnt(0)" ::: "memory");
    __builtin_amdgcn_s_barrier();
    COMPUTE_X2((nt - 1) & 1)

#undef STAGE_X2
#undef COMPUTE_X2

    const int r4 = lg * 4;
#pragma unroll
    for (int j = 0; j < 4; ++j) {
        const int col = n0 + wn * 64 + j * 16 + lr;
        const float bv = bias[(size_t)e * sBias + col];
#pragma unroll
        for (int i = 0; i < 8; ++i) {
#pragma unroll
            for (int r = 0; r < 4; ++r) {
                const int rowg = m0 + wm * 128 + i * 16 + r4 + r;
                float v = acc[i][j][r] + bv;
                if (RELU) v = fmaxf(v, 0.f);
                Cout[(size_t)e * sC + (size_t)rowg * N + col] = f2b(v);
            }
        }
    }
}

// ---------------------------------------------------------------------------
// Split-bf16 MFMA flash attention (UNCHANGED — bit-stable routing path)
// ---------------------------------------------------------------------------
__global__ __launch_bounds__(256)
void attn_mfma(const u16* __restrict__ qhp, const u16* __restrict__ qlp,
               const u16* __restrict__ khp, const u16* __restrict__ klp,
               const u16* __restrict__ vthp, const u16* __restrict__ vtlp,
               u16* __restrict__ os) {
    __shared__ u16 Khi[64 * 64], Klo[64 * 64];
    __shared__ u16 Vhi[64 * 64], Vlo[64 * 64];   // [d][kk]
    __shared__ u16 Phi[4][16 * 64], Plo[4][16 * 64];

    const int qt = blockIdx.x, bh = blockIdx.y;
    const int bb = bh >> 4, hh = bh & 15;
    const int tid = threadIdx.x, lane = tid & 63, wid = tid >> 6;
    const int lr = lane & 15, lg = lane >> 4;

    short8 qhi[2], qlo[2];
    {
        const size_t qbase = (size_t)(bb * Ss + qt * 64 + wid * 16 + lr) * Dd + hh * HD;
#pragma unroll
        for (int ks = 0; ks < 2; ++ks) {
            qhi[ks] = *(const short8*)(qhp + qbase + ks * 32 + lg * 8);
            qlo[ks] = *(const short8*)(qlp + qbase + ks * 32 + lg * 8);
        }
    }

    float mrun[4], lrun[4];
    f32x4 oacc[4];
#pragma unroll
    for (int r = 0; r < 4; ++r) { mrun[r] = -1e30f; lrun[r] = 0.f; }
#pragma unroll
    for (int nf = 0; nf < 4; ++nf) oacc[nf] = zf4();

    const int srow = tid >> 2;        // 0..63
    const int sd = (tid & 3) * 16;    // 0,16,32,48

    u16* const PhiW = Phi[wid];
    u16* const PloW = Plo[wid];

    for (int kt = 0; kt < Ss / 64; ++kt) {
        const size_t krow = (size_t)(bb * Ss + kt * 64 + srow) * Dd + hh * HD + sd;
        const short8 k0 = *(const short8*)(khp + krow);
        const short8 k1 = *(const short8*)(khp + krow + 8);
        const short8 l0 = *(const short8*)(klp + krow);
        const short8 l1 = *(const short8*)(klp + krow + 8);
        const size_t vrow = ((size_t)bh * HD + srow) * Ss + kt * 64 + sd;
        const short8 v0 = *(const short8*)(vthp + vrow);
        const short8 v1 = *(const short8*)(vthp + vrow + 8);
        const short8 w0 = *(const short8*)(vtlp + vrow);
        const short8 w1 = *(const short8*)(vtlp + vrow + 8);
        __syncthreads();
        *(short8*)(Khi + swzb(srow, sd)) = k0;
        *(short8*)(Khi + swzb(srow, sd + 8)) = k1;
        *(short8*)(Klo + swzb(srow, sd)) = l0;
        *(short8*)(Klo + swzb(srow, sd + 8)) = l1;
        *(short8*)(Vhi + swzb(srow, sd)) = v0;
        *(short8*)(Vhi + swzb(srow, sd + 8)) = v1;
        *(short8*)(Vlo + swzb(srow, sd)) = w0;
        *(short8*)(Vlo + swzb(srow, sd + 8)) = w1;
        __syncthreads();

        f32x4 sc[4];
#pragma unroll
        for (int nf = 0; nf < 4; ++nf) sc[nf] = zf4();
#pragma unroll
        for (int nf = 0; nf < 4; ++nf)
#pragma unroll
            for (int ks = 0; ks < 2; ++ks) {
                const short8 kh = *(const short8*)(Khi + swzb(nf * 16 + lr, ks * 32 + lg * 8));
                const short8 kl = *(const short8*)(Klo + swzb(nf * 16 + lr, ks * 32 + lg * 8));
                sc[nf] = __builtin_amdgcn_mfma_f32_16x16x32_bf16(qhi[ks], kh, sc[nf], 0, 0, 0);
                sc[nf] = __builtin_amdgcn_mfma_f32_16x16x32_bf16(qhi[ks], kl, sc[nf], 0, 0, 0);
                sc[nf] = __builtin_amdgcn_mfma_f32_16x16x32_bf16(qlo[ks], kh, sc[nf], 0, 0, 0);
                sc[nf] = __builtin_amdgcn_mfma_f32_16x16x32_bf16(qlo[ks], kl, sc[nf], 0, 0, 0);
            }

        float scl[4];
#pragma unroll
        for (int r = 0; r < 4; ++r) {
            float m = fmaxf(fmaxf(sc[0][r], sc[1][r]), fmaxf(sc[2][r], sc[3][r]));
            m = fmaxf(m, __shfl_xor(m, 1));
            m = fmaxf(m, __shfl_xor(m, 2));
            m = fmaxf(m, __shfl_xor(m, 4));
            m = fmaxf(m, __shfl_xor(m, 8));
            const float mn = fmaxf(mrun[r], m);
            scl[r] = __expf(mrun[r] - mn);
            mrun[r] = mn;
            float s = 0.f;
#pragma unroll
            for (int nf = 0; nf < 4; ++nf) {
                const float p = __expf(sc[nf][r] - mn);
                sc[nf][r] = p;
                s += p;
            }
            s += __shfl_xor(s, 1);
            s += __shfl_xor(s, 2);
            s += __shfl_xor(s, 4);
            s += __shfl_xor(s, 8);
            lrun[r] = lrun[r] * scl[r] + s;
        }

#pragma unroll
        for (int nf = 0; nf < 4; ++nf)
#pragma unroll
            for (int r = 0; r < 4; ++r) {
                const float p = sc[nf][r];
                const u16 h = f2b(p);
                const int idx = swzb(lg * 4 + r, nf * 16 + lr);
                PhiW[idx] = h;
                PloW[idx] = f2b(p - b2f(h));
            }

#pragma unroll
        for (int nf = 0; nf < 4; ++nf)
#pragma unroll
            for (int r = 0; r < 4; ++r) oacc[nf][r] *= scl[r];

#pragma unroll
        for (int ks = 0; ks < 2; ++ks) {
            const short8 ph = *(const short8*)(PhiW + swzb(lr, ks * 32 + lg * 8));
            const short8 pl = *(const short8*)(PloW + swzb(lr, ks * 32 + lg * 8));
#pragma unroll
            for (int nf = 0; nf < 4; ++nf) {
                const short8 vh = *(const short8*)(Vhi + swzb(nf * 16 + lr, ks * 32 + lg * 8));
                const short8 vl = *(const short8*)(Vlo + swzb(nf * 16 + lr, ks * 32 + lg * 8));
                oacc[nf] = __builtin_amdgcn_mfma_f32_16x16x32_bf16(ph, vh, oacc[nf], 0, 0, 0);
                oacc[nf] = __builtin_amdgcn_mfma_f32_16x16x32_bf16(ph, vl, oacc[nf], 0, 0, 0);
                oacc[nf] = __builtin_amdgcn_mfma_f32_16x16x32_bf16(pl, vh, oacc[nf], 0, 0, 0);
                oacc[nf] = __builtin_amdgcn_mfma_f32_16x16x32_bf16(pl, vl, oacc[nf], 0, 0, 0);
            }
        }
    }

#pragma unroll
    for (int r = 0; r < 4; ++r) {
        const float inv = 1.f / lrun[r];
        const size_t base = (size_t)(bb * Ss + qt * 64 + wid * 16 + lg * 4 + r) * Dd + hh * HD;
#pragma unroll
        for (int nf = 0; nf < 4; ++nf) {
            const float o = oacc[nf][r] * inv;
            const u16 h = f2b(o);
            const float r1 = o - b2f(h);
            const u16 m = f2b(r1);
            const u16 l = f2b(r1 - b2f(m));
            const size_t off = base + nf * 16 + lr;
            os[off] = h;
            os[PT + off] = m;
            os[2 * PT + off] = l;
        }
    }
}

// ---------------------------------------------------------------------------
DEVI double block_reduce_d(double v, double* sred, int tid) {
#pragma unroll
    for (int off = 32; off > 0; off >>= 1) v += __shfl_down(v, off);
    __syncthreads();
    if ((tid & 63) == 0) sred[tid >> 6] = v;
    __syncthreads();
    return sred[0] + sred[1] + sred[2] + sred[3];
}

// ---------------------------------------------------------------------------
// LN1: x1f = LN(x + aproj)
// ---------------------------------------------------------------------------
__global__ __launch_bounds__(256)
void ln1_kernel(const float* __restrict__ x, const float* __restrict__ ap,
                const float* __restrict__ g, const float* __restrict__ b,
                float* __restrict__ x1f) {
    __shared__ double sred[4];
    const int t = blockIdx.x, tid = threadIdx.x;
    const float4 xv = ((const float4*)(x + (size_t)t * Dd))[tid];
    const float4 av = ((const float4*)(ap + (size_t)t * Dd))[tid];
    const double v0 = (double)xv.x + (double)av.x;
    const double v1 = (double)xv.y + (double)av.y;
    const double v2 = (double)xv.z + (double)av.z;
    const double v3 = (double)xv.w + (double)av.w;
    const double s = block_reduce_d(v0 + v1 + v2 + v3, sred, tid);
    const double mean = s * (1.0 / Dd);
    const double c0 = v0 - mean, c1 = v1 - mean, c2 = v2 - mean, c3 = v3 - mean;
    const double s2 = block_reduce_d(c0 * c0 + c1 * c1 + c2 * c2 + c3 * c3, sred, tid);
    const double rstd = 1.0 / sqrt(s2 * (1.0 / Dd) + 1e-5);
    const float4 gv = ((const float4*)g)[tid];
    const float4 bv = ((const float4*)b)[tid];
    float4 ov;
    ov.x = (float)(c0 * rstd * (double)gv.x + (double)bv.x);
    ov.y = (float)(c1 * rstd * (double)gv.y + (double)bv.y);
    ov.z = (float)(c2 * rstd * (double)gv.z + (double)bv.z);
    ov.w = (float)(c3 * rstd * (double)gv.w + (double)bv.w);
    ((float4*)(x1f + (size_t)t * Dd))[tid] = ov;
}

// ---------------------------------------------------------------------------
// gating stage 1 (fp64)
// ---------------------------------------------------------------------------
__global__ __launch_bounds__(256)
void gate1_kernel(const float* __restrict__ x1f, const float* __restrict__ wg,
                  int* __restrict__ idx1, int* __restrict__ idx2,
                  float* __restrict__ gate1, float* __restrict__ gate2) {
    const int tid = threadIdx.x, lane = tid & 63, wid = tid >> 6;
    const int t = blockIdx.x * 4 + wid;
    double acc[16];
#pragma unroll
    for (int e = 0; e < 16; ++e) acc[e] = 0.0;
    for (int i = 0; i < 16; ++i) {
        const int d = i * 64 + lane;
        const double xv = (double)x1f[(size_t)t * Dd + d];
        const float4* wr = (const float4*)(wg + (size_t)d * 16);
        const float4 w0 = wr[0], w1 = wr[1], w2 = wr[2], w3 = wr[3];
        acc[0] += xv * (double)w0.x;  acc[1] += xv * (double)w0.y;
        acc[2] += xv * (double)w0.z;  acc[3] += xv * (double)w0.w;
        acc[4] += xv * (double)w1.x;  acc[5] += xv * (double)w1.y;
        acc[6] += xv * (double)w1.z;  acc[7] += xv * (double)w1.w;
        acc[8] += xv * (double)w2.x;  acc[9] += xv * (double)w2.y;
        acc[10] += xv * (double)w2.z; acc[11] += xv * (double)w2.w;
        acc[12] += xv * (double)w3.x; acc[13] += xv * (double)w3.y;
        acc[14] += xv * (double)w3.z; acc[15] += xv * (double)w3.w;
    }
#pragma unroll
    for (int e = 0; e < 16; ++e) {
        acc[e] += __shfl_xor(acc[e], 1);
        acc[e] += __shfl_xor(acc[e], 2);
        acc[e] += __shfl_xor(acc[e], 4);
        acc[e] += __shfl_xor(acc[e], 8);
        acc[e] += __shfl_xor(acc[e], 16);
        acc[e] += __shfl_xor(acc[e], 32);
    }
    if (lane == 0) {
        double mx = acc[0];
#pragma unroll
        for (int e = 1; e < 16; ++e) mx = fmax(mx, acc[e]);
        double z = 0.0, ex[16];
#pragma unroll
        for (int e = 0; e < 16; ++e) { ex[e] = exp(acc[e] - mx); z += ex[e]; }
        int b1 = 0; double v1 = acc[0];
#pragma unroll
        for (int e = 1; e < 16; ++e) if (acc[e] > v1) { v1 = acc[e]; b1 = e; }
        int b2 = (b1 == 0) ? 1 : 0; double v2 = acc[b2];
#pragma unroll
        for (int e = 0; e < 16; ++e) if (e != b1 && acc[e] > v2) { v2 = acc[e]; b2 = e; }
        const double rz = 1.0 / z;
        idx1[t] = b1; idx2[t] = b2;
        gate1[t] = (float)(ex[b1] * rz); gate2[t] = (float)(ex[b2] * rz);
    }
}

// ---------------------------------------------------------------------------
// gating stage 2 (single block; per-expert base update parallelized tid<16)
// ---------------------------------------------------------------------------
__global__ __launch_bounds__(256)
void gate2_kernel(const int* __restrict__ idx1, const int* __restrict__ idx2,
                  const float* __restrict__ gate1, const float* __restrict__ gate2,
                  int* __restrict__ p1, int* __restrict__ p2,
                  int* __restrict__ k1, int* __restrict__ k2,
                  float* __restrict__ w1, float* __restrict__ w2) {
    __shared__ int hist[16];
    __shared__ unsigned long long sb1[4][16], sb2[4][16];
    __shared__ int sbase1[16], sbase2[16];
    const int tid = threadIdx.x, lane = tid & 63, wid = tid >> 6;
    if (tid < 16) hist[tid] = 0;
    __syncthreads();
    for (int t = tid; t < Tt; t += 256) atomicAdd(&hist[idx1[t]], 1);
    __syncthreads();
    if (tid < 16) { sbase1[tid] = 0; sbase2[tid] = hist[tid]; }
    __syncthreads();
    const unsigned long long below = (1ULL << lane) - 1ULL;
    for (int ch = 0; ch < Tt / 256; ++ch) {
        const int t = ch * 256 + tid;
        const int a = idx1[t], b = idx2[t];
#pragma unroll
        for (int e = 0; e < 16; ++e) {
            const unsigned long long m1 = __ballot(a == e);
            const unsigned long long m2 = __ballot(b == e);
            if (lane == 0) { sb1[wid][e] = m1; sb2[wid][e] = m2; }
        }
        __syncthreads();
        int r1 = __popcll(sb1[wid][a] & below);
        int r2 = __popcll(sb2[wid][b] & below);
#pragma unroll
        for (int w = 0; w < 4; ++w)
            if (w < wid) { r1 += __popcll(sb1[w][a]); r2 += __popcll(sb2[w][b]); }
        const int loc1 = sbase1[a] + r1, loc2 = sbase2[b] + r2;
        const int kk1 = loc1 < Cap, kk2 = loc2 < Cap;
        const float g1 = kk1 ? gate1[t] : 0.f;
        const float g2 = kk2 ? gate2[t] : 0.f;
        const float dn = fmaxf(g1 + g2, EPSc);
        p1[t] = kk1 ? loc1 : 0;
        p2[t] = kk2 ? loc2 : 0;
        k1[t] = kk1; k2[t] = kk2;
        w1[t] = g1 / dn; w2[t] = g2 / dn;
        __syncthreads();
        if (tid < 16) {
            const int e = tid;
            int c1 = 0, c2 = 0;
#pragma unroll
            for (int w = 0; w < 4; ++w) { c1 += __popcll(sb1[w][e]); c2 += __popcll(sb2[w][e]); }
            sbase1[e] += c1; sbase2[e] += c2;
        }
        __syncthreads();
    }
}

// ---------------------------------------------------------------------------
// dispatch: scatter kept tokens (f32 -> bf16) into [E,C,D] buffers (pre-zeroed)
// ---------------------------------------------------------------------------
__global__ __launch_bounds__(256)
void dispatch_kernel(const float* __restrict__ x1f,
                     const int* __restrict__ i1, const int* __restrict__ p1, const int* __restrict__ k1,
                     const int* __restrict__ i2, const int* __restrict__ p2, const int* __restrict__ k2,
                     u16* __restrict__ buf) {
    const int t = blockIdx.x, tid = threadIdx.x;
    const float4 v = ((const float4*)(x1f + (size_t)t * Dd))[tid];
    u16x4 pw;
    pw[0] = f2b(v.x); pw[1] = f2b(v.y); pw[2] = f2b(v.z); pw[3] = f2b(v.w);
    if (k1[t]) *(u16x4*)(buf + ((size_t)i1[t] * Cap + p1[t]) * Dd + tid * 4) = pw;
    if (k2[t]) *(u16x4*)(buf + ((size_t)i2[t] * Cap + p2[t]) * Dd + tid * 4) = pw;
}

// ---------------------------------------------------------------------------
// combine + residual + LN2 -> d_out (f32)
// ---------------------------------------------------------------------------
__global__ __launch_bounds__(256)
void combine_ln2(const float* __restrict__ x1f, const u16* __restrict__ y,
                 const int* __restrict__ i1, const int* __restrict__ p1, const float* __restrict__ w1,
                 const int* __restrict__ i2, const int* __restrict__ p2, const float* __restrict__ w2,
                 const float* __restrict__ g, const float* __restrict__ b,
                 float* __restrict__ out) {
    __shared__ double sred[4];
    const int t = blockIdx.x, tid = threadIdx.x;
    const size_t r1 = ((size_t)i1[t] * Cap + p1[t]) * Dd;
    const size_t r2 = ((size_t)i2[t] * Cap + p2[t]) * Dd;
    const double a1 = (double)w1[t], a2 = (double)w2[t];
    const u16x4 y1 = *(const u16x4*)(y + r1 + tid * 4);
    const u16x4 y2 = *(const u16x4*)(y + r2 + tid * 4);
    const float4 xv = ((const float4*)(x1f + (size_t)t * Dd))[tid];
    const double v0 = (double)xv.x + a1 * (double)b2f(y1[0]) + a2 * (double)b2f(y2[0]);
    const double v1 = (double)xv.y + a1 * (double)b2f(y1[1]) + a2 * (double)b2f(y2[1]);
    const double v2 = (double)xv.z + a1 * (double)b2f(y1[2]) + a2 * (double)b2f(y2[2]);
    const double v3 = (double)xv.w + a1 * (double)b2f(y1[3]) + a2 * (double)b2f(y2[3]);
    const double s = block_reduce_d(v0 + v1 + v2 + v3, sred, tid);
    const double mean = s * (1.0 / Dd);
    const double c0 = v0 - mean, c1 = v1 - mean, c2 = v2 - mean, c3 = v3 - mean;
    const double s2 = block_reduce_d(c0 * c0 + c1 * c1 + c2 * c2 + c3 * c3, sred, tid);
    const double rstd = 1.0 / sqrt(s2 * (1.0 / Dd) + 1e-5);
    const float4 gv = ((const float4*)g)[tid];
    const float4 bv = ((const float4*)b)[tid];
    float4 ov;
    ov.x = (float)(c0 * rstd * (double)gv.x + (double)bv.x);
    ov.y = (float)(c1 * rstd * (double)gv.y + (double)bv.y);
    ov.z = (float)(c2 * rstd * (double)gv.z + (double)bv.z);
    ov.w = (float)(c3 * rstd * (double)gv.w + (double)bv.w);
    ((float4*)(out + (size_t)t * Dd))[tid] = ov;
}

// ---------------------------------------------------------------------------
extern "C" void kernel_launch(void* const* d_in, const int* in_sizes, int n_in,
                              void* d_out, int out_size, void* d_ws, size_t ws_size,
                              hipStream_t stream) {
    (void)in_sizes; (void)n_in; (void)out_size; (void)ws_size;
    const float* x    = (const float*)d_in[0];
    const float* inW  = (const float*)d_in[1];
    const float* inB  = (const float*)d_in[2];
    const float* outW = (const float*)d_in[3];
    const float* outB = (const float*)d_in[4];
    const float* ln1g = (const float*)d_in[5];
    const float* ln1b = (const float*)d_in[6];
    const float* ln2g = (const float*)d_in[7];
    const float* ln2b = (const float*)d_in[8];
    const float* wg   = (const float*)d_in[9];
    const float* w1   = (const float*)d_in[10];
    const float* b1   = (const float*)d_in[11];
    const float* w2   = (const float*)d_in[12];
    const float* b2   = (const float*)d_in[13];
    float* out = (float*)d_out;

    char* ws = (char*)d_ws;
    const size_t MB = 1024 * 1024;
    // ---- phase-overlapped arena (verified layout, peak 352.4 MiB) ----
    u16*   xs3   = (u16*)(ws + 0);          // [0,48)    dead after QKV gemm
    u16*   inW3  = (u16*)(ws + 48 * MB);    // [48,66)   dead after QKV gemm
    u16*   qh    = (u16*)(ws + 66 * MB);    // [66,82)   dead after attn
    u16*   ql    = (u16*)(ws + 82 * MB);    // [82,98)   dead after attn
    u16*   kh    = (u16*)(ws + 98 * MB);    // [98,114)  dead after attn
    u16*   kl    = (u16*)(ws + 114 * MB);   // [114,130) dead after attn
    u16*   vh    = (u16*)(ws + 130 * MB);   // [130,146) dead after vtrans
    u16*   vl    = (u16*)(ws + 146 * MB);   // [146,162) dead after vtrans
    u16*   vth   = (u16*)(ws + 162 * MB);   // [162,178) dead after attn
    u16*   vtl   = (u16*)(ws + 178 * MB);   // [178,194) dead after attn
    u16*   os3   = (u16*)(ws + 194 * MB);   // [194,242) attn out, dead after OP
    u16*   outW3 = (u16*)(ws + 0);          // [0,6)     over dead xs3, dead after OP
    float* aproj = (float*)(ws + 6 * MB);   // [6,38)    over dead xs3, dead after LN1
    u16*   wt    = (u16*)(ws + 0);          // [0,128)   written post-LN1 (all dead)
    u16*   hbuf  = (u16*)(ws + 128 * MB);   // [128,256) over dead kl-tail/v*/os3
    u16*   ybuf  = (u16*)(ws + 256 * MB);   // [256,288) fresh
    u16*   ebuf  = (u16*)(ws + 288 * MB);   // [288,320) fresh
    float* x1f   = (float*)(ws + 320 * MB); // [320,352) fresh, live till end
    char*  gbase = ws + 352 * MB;           // [352,~352.4) gating arrays
    int*   idx1 = (int*)(gbase + 0 * Tt * 4);
    int*   idx2 = (int*)(gbase + 1 * Tt * 4);
    float* gt1  = (float*)(gbase + 2 * Tt * 4);
    float* gt2  = (float*)(gbase + 3 * Tt * 4);
    int*   p1   = (int*)(gbase + 4 * Tt * 4);
    int*   p2   = (int*)(gbase + 5 * Tt * 4);
    int*   k1   = (int*)(gbase + 6 * Tt * 4);
    int*   k2   = (int*)(gbase + 7 * Tt * 4);
    float* w1c  = (float*)(gbase + 8 * Tt * 4);
    float* w2c  = (float*)(gbase + 9 * Tt * 4);

    const long long nTD = (long long)Tt * Dd;
    const long long nW1 = (long long)D3 * Dd;
    const long long nW2 = (long long)Dd * Dd;

    // 1: split inputs; QKV GEMM (phased, bit-identical chain) writes split planes
    split3_kernel<<<(int)(nTD / 1024), 256, 0, stream>>>(x, xs3, nTD);
    split3_kernel<<<(int)(nW1 / 1024), 256, 0, stream>>>(inW, inW3, nW1);
    gemm_x3p<3><<<dim3(D3 / 256, Tt / 128, 1), 512, 0, stream>>>(
        xs3, inW3, nullptr, inB, Tt, D3, Dd, (size_t)nTD, (size_t)nW1,
        qh, ql, kh, kl, vh, vl);
    // 2: V transpose; attention (bit-identical), writes os3 planes
    vtrans_kernel<<<dim3(Ss / 32, HD / 32, Bz * Hh), 256, 0, stream>>>(vh, vl, vth, vtl);
    attn_mfma<<<dim3(Ss / 64, Bz * Hh), 256, 0, stream>>>(qh, ql, kh, kl, vth, vtl, os3);
    // 3: out-proj (phased, f32 out)
    split3_kernel<<<(int)(nW2 / 1024), 256, 0, stream>>>(outW, outW3, nW2);
    gemm_x3p<2><<<dim3(Dd / 256, Tt / 128, 1), 512, 0, stream>>>(
        os3, outW3, aproj, outB, Tt, Dd, Dd, (size_t)nTD, (size_t)nW2,
        nullptr, nullptr, nullptr, nullptr, nullptr, nullptr);
    // 4: LN1
    ln1_kernel<<<Tt, 256, 0, stream>>>(x, aproj, ln1g, ln1b, x1f);
    // 5-6: gating
    gate1_kernel<<<Tt / 4, 256, 0, stream>>>(x1f, wg, idx1, idx2, gt1, gt2);
    gate2_kernel<<<1, 256, 0, stream>>>(idx1, idx2, gt1, gt2, p1, p2, k1, k2, w1c, w2c);
    // 7: dispatch
    hipMemsetAsync(ebuf, 0, (size_t)Ee * Cap * Dd * 2, stream);
    dispatch_kernel<<<Tt, 256, 0, stream>>>(x1f, idx1, p1, k1, idx2, p2, k2, ebuf);
    // 8-11: expert FFN — 256^2 dbuf counted-vmcnt GEMMs + bank swizzle
    tconv64_kernel<<<dim3(DFF / 64, Dd / 64, Ee), 256, 0, stream>>>(w1, wt, Dd, DFF);
    gemm_x2<1><<<dim3(DFF / 256, Cap / 256, Ee), 512, 0, stream>>>(
        ebuf, wt, hbuf, b1, Cap, DFF, Dd,
        (size_t)Cap * Dd, (size_t)DFF * Dd, (size_t)Cap * DFF, DFF);
    tconv64_kernel<<<dim3(Dd / 64, DFF / 64, Ee), 256, 0, stream>>>(w2, wt, DFF, Dd);
    gemm_x2<0><<<dim3(Dd / 256, Cap / 256, Ee), 512, 0, stream>>>(
        hbuf, wt, ybuf, b2, Cap, Dd, DFF,
        (size_t)Cap * DFF, (size_t)Dd * DFF, (size_t)Cap * Dd, Dd);
    // 12: combine + residual + LN2
    combine_ln2<<<Tt, 256, 0, stream>>>(x1f, ybuf, idx1, p1, w1c, idx2, p2, w2c, ln2g, ln2b, out);
}